// Round 14
// baseline (5003.919 us; speedup 1.0000x reference)
//
#include <hip/hip_runtime.h>
#include <math.h>
#include <float.h>

#define BATCH   8
#define SEQ     1025
#define GTOK    1024
#define CDIM    768
#define NHEAD   12
#define DHEAD   64
#define NVIEW   6
#define NCLUST  512
#define NGRID   1568
#define NROWS   8200
#define NFEAT   8192
#define SEGCAP  2048
#define LDT     1032   // main-attn T1 row stride (bf16, 16B-aligned rows)

typedef unsigned short bf16;
typedef __attribute__((ext_vector_type(8))) short bf16x8;
typedef __attribute__((ext_vector_type(4))) float f32x4;

__device__ __forceinline__ float b2f(bf16 u) {
    union { unsigned int i; float f; } v; v.i = ((unsigned int)u) << 16; return v.f;
}
__device__ __forceinline__ bf16 f2b(float f) {
    union { float f; unsigned int i; } v; v.f = f;
    unsigned int x = v.i;
    return (bf16)((x + 0x7fffu + ((x >> 16) & 1u)) >> 16);
}

__device__ __forceinline__ float block_reduce_sum(float v, float* red) {
    int tid = threadIdx.x;
    red[tid] = v; __syncthreads();
    for (int s = blockDim.x >> 1; s > 0; s >>= 1) {
        if (tid < s) red[tid] += red[tid + s];
        __syncthreads();
    }
    float r = red[0]; __syncthreads();
    return r;
}

__device__ __forceinline__ float gelu_exact(float v) {
    return 0.5f * v * (1.f + erff(v * 0.70710678118654752f));
}
__device__ __forceinline__ float quick_gelu(float v) {
    return v / (1.f + expf(-1.702f * v));
}

// ---------------------------------------------------------------------------
// LayerNorm: one block per row (f32 input, f32 gamma/beta, bf16 out)
// ---------------------------------------------------------------------------
__global__ __launch_bounds__(256)
void ln_kernel(const float* __restrict__ x, const float* __restrict__ g,
               const float* __restrict__ b, long long goff, bf16* __restrict__ out)
{
    __shared__ float red[256];
    long long row = blockIdx.x;
    int tid = threadIdx.x;
    long long base = row * CDIM;
    float v0 = x[base + tid], v1 = x[base + tid + 256], v2 = x[base + tid + 512];
    float mean = block_reduce_sum(v0 + v1 + v2, red) * (1.f / CDIM);
    float d0 = v0 - mean, d1 = v1 - mean, d2 = v2 - mean;
    float var = block_reduce_sum(d0 * d0 + d1 * d1 + d2 * d2, red) * (1.f / CDIM);
    float rstd = rsqrtf(var + 1e-5f);
    bf16* orow = out + base;
    orow[tid]       = f2b(d0 * rstd * g[goff + tid]       + b[goff + tid]);
    orow[tid + 256] = f2b(d1 * rstd * g[goff + tid + 256] + b[goff + tid + 256]);
    orow[tid + 512] = f2b(d2 * rstd * g[goff + tid + 512] + b[goff + tid + 512]);
}

// ---------------------------------------------------------------------------
// gemm_k: 64x64-tile MFMA GEMM (narrow-N / odd-K cases; AV only now)
// Non-trans B staging: coalesced k-major loads + scattered LDS writes.
// ---------------------------------------------------------------------------
#define LDSK 40

template<int TRANSB, int ATY, int BSRC, int OTY, int RES>
__global__ __launch_bounds__(256)
void gemm_k(const void* __restrict__ Av, const void* __restrict__ B,
            const void* __restrict__ bias, const float* __restrict__ Res,
            void* __restrict__ Cv,
            int M, int N, int K, int lda, int ldb, int ldc, int ldres,
            float alpha, int act, long long boff, long long biasoff,
            long long sA, long long sB, long long sC)
{
    __shared__ short As[64][LDSK];
    __shared__ short Bs[64][LDSK];
    int bz = blockIdx.z;
    int tid = threadIdx.x;
    int m0 = blockIdx.y * 64, n0 = blockIdx.x * 64;
    long long Aoff = (long long)bz * sA;
    long long Boff = boff + (long long)bz * sB;

    int lane = tid & 63;
    int w = tid >> 6;
    int wr = w >> 1, wc = w & 1;
    int fr = lane & 15;
    int kg = lane >> 4;

    f32x4 acc[2][2] = {};

    for (int k0 = 0; k0 < K; k0 += 32) {
        // A tile: As[r][k], thread: row tid>>2, 8 k at (tid&3)*8
        {
            int r = tid >> 2, kb = (tid & 3) * 8;
            int gm = m0 + r;
            short tmp[8] = {};
            if (gm < M) {
                long long base = Aoff + (long long)gm * lda + k0 + kb;
                if (k0 + kb + 8 <= K) {
                    if (ATY == 0) {
                        *reinterpret_cast<uint4*>(tmp) =
                            *reinterpret_cast<const uint4*>((const bf16*)Av + base);
                    } else {
                        float4 f0 = *reinterpret_cast<const float4*>((const float*)Av + base);
                        float4 f1 = *reinterpret_cast<const float4*>((const float*)Av + base + 4);
                        tmp[0]=(short)f2b(f0.x); tmp[1]=(short)f2b(f0.y);
                        tmp[2]=(short)f2b(f0.z); tmp[3]=(short)f2b(f0.w);
                        tmp[4]=(short)f2b(f1.x); tmp[5]=(short)f2b(f1.y);
                        tmp[6]=(short)f2b(f1.z); tmp[7]=(short)f2b(f1.w);
                    }
                } else {
                    #pragma unroll
                    for (int j = 0; j < 8; ++j) {
                        if (k0 + kb + j < K)
                            tmp[j] = ATY ? (short)f2b(((const float*)Av)[base + j])
                                         : (short)((const bf16*)Av)[base + j];
                    }
                }
            }
            *reinterpret_cast<uint4*>(&As[r][kb]) = *reinterpret_cast<uint4*>(tmp);
        }
        // B tile
        if (TRANSB) {
            int col = tid >> 2, kb = (tid & 3) * 8;
            int gn = n0 + col;
            short tmp[8] = {};
            if (gn < N) {
                long long base = Boff + (long long)gn * ldb + k0 + kb;
                if (k0 + kb + 8 <= K) {
                    if (BSRC == 0) {
                        *reinterpret_cast<uint4*>(tmp) =
                            *reinterpret_cast<const uint4*>((const bf16*)B + base);
                    } else {
                        float4 f0 = *reinterpret_cast<const float4*>((const float*)B + base);
                        float4 f1 = *reinterpret_cast<const float4*>((const float*)B + base + 4);
                        tmp[0]=(short)f2b(f0.x); tmp[1]=(short)f2b(f0.y);
                        tmp[2]=(short)f2b(f0.z); tmp[3]=(short)f2b(f0.w);
                        tmp[4]=(short)f2b(f1.x); tmp[5]=(short)f2b(f1.y);
                        tmp[6]=(short)f2b(f1.z); tmp[7]=(short)f2b(f1.w);
                    }
                } else {
                    #pragma unroll
                    for (int j = 0; j < 8; ++j) {
                        if (k0 + kb + j < K)
                            tmp[j] = BSRC ? (short)f2b(((const float*)B)[base + j])
                                          : (short)((const bf16*)B)[base + j];
                    }
                }
            }
            *reinterpret_cast<uint4*>(&Bs[col][kb]) = *reinterpret_cast<uint4*>(tmp);
        } else {
            // k-major coalesced: thread -> k = tid>>3 (0..31), 8 cols at (tid&7)*8
            int kk = tid >> 3, cb = (tid & 7) * 8;
            int gk = k0 + kk;
            short tmp[8] = {};
            if (gk < K && n0 + cb < N) {
                long long base = Boff + (long long)gk * ldb + n0 + cb;
                if (n0 + cb + 8 <= N) {
                    if (BSRC == 0) {
                        *reinterpret_cast<uint4*>(tmp) =
                            *reinterpret_cast<const uint4*>((const bf16*)B + base);
                    } else {
                        float4 f0 = *reinterpret_cast<const float4*>((const float*)B + base);
                        float4 f1 = *reinterpret_cast<const float4*>((const float*)B + base + 4);
                        tmp[0]=(short)f2b(f0.x); tmp[1]=(short)f2b(f0.y);
                        tmp[2]=(short)f2b(f0.z); tmp[3]=(short)f2b(f0.w);
                        tmp[4]=(short)f2b(f1.x); tmp[5]=(short)f2b(f1.y);
                        tmp[6]=(short)f2b(f1.z); tmp[7]=(short)f2b(f1.w);
                    }
                } else {
                    #pragma unroll
                    for (int j = 0; j < 8; ++j)
                        if (n0 + cb + j < N)
                            tmp[j] = BSRC ? (short)f2b(((const float*)B)[base + j])
                                          : (short)((const bf16*)B)[base + j];
                }
            }
            #pragma unroll
            for (int j = 0; j < 8; ++j) Bs[cb + j][kk] = tmp[j];
        }
        __syncthreads();

        bf16x8 a0 = *reinterpret_cast<const bf16x8*>(&As[wr * 32 + fr][kg * 8]);
        bf16x8 a1 = *reinterpret_cast<const bf16x8*>(&As[wr * 32 + 16 + fr][kg * 8]);
        bf16x8 b0 = *reinterpret_cast<const bf16x8*>(&Bs[wc * 32 + fr][kg * 8]);
        bf16x8 b1 = *reinterpret_cast<const bf16x8*>(&Bs[wc * 32 + 16 + fr][kg * 8]);
        acc[0][0] = __builtin_amdgcn_mfma_f32_16x16x32_bf16(a0, b0, acc[0][0], 0, 0, 0);
        acc[0][1] = __builtin_amdgcn_mfma_f32_16x16x32_bf16(a0, b1, acc[0][1], 0, 0, 0);
        acc[1][0] = __builtin_amdgcn_mfma_f32_16x16x32_bf16(a1, b0, acc[1][0], 0, 0, 0);
        acc[1][1] = __builtin_amdgcn_mfma_f32_16x16x32_bf16(a1, b1, acc[1][1], 0, 0, 0);
        __syncthreads();
    }

    #pragma unroll
    for (int m = 0; m < 2; ++m) {
        #pragma unroll
        for (int n = 0; n < 2; ++n) {
            #pragma unroll
            for (int i = 0; i < 4; ++i) {
                int gm = m0 + wr * 32 + m * 16 + kg * 4 + i;
                int gn = n0 + wc * 32 + n * 16 + fr;
                if (gm >= M || gn >= N) continue;
                float v = acc[m][n][i] * alpha;
                if (bias) v += BSRC ? ((const float*)bias)[biasoff + gn]
                                    : b2f(((const bf16*)bias)[biasoff + gn]);
                if (act == 1) v = quick_gelu(v);
                if (RES) v += Res[(long long)gm * ldres + gn];
                long long ci = sC * bz + (long long)gm * ldc + gn;
                if (OTY) ((float*)Cv)[ci] = v;
                else     ((bf16*)Cv)[ci] = f2b(v);
            }
        }
    }
}

// ---------------------------------------------------------------------------
// gemm2: 128x128-tile MFMA GEMM, BK=32, 8 waves, register-prefetch pipeline.
// Non-trans B staging: coalesced k-major loads + scattered LDS writes.
// Requires K % 32 == 0.
// ---------------------------------------------------------------------------
template<int TRANSB, int ATY, int BSRC, int OTY, int RES>
__global__ __launch_bounds__(512)
void gemm2(const void* __restrict__ Av, const void* __restrict__ B,
           const void* __restrict__ bias, const float* __restrict__ Res,
           void* __restrict__ Cv,
           int M, int N, int K, int lda, int ldb, int ldc, int ldres,
           float alpha, int act, long long boff, long long biasoff,
           long long sA, long long sB, long long sC)
{
    __shared__ short As[128][LDSK];
    __shared__ short Bs[128][LDSK];
    int bz = blockIdx.z;
    int tid = threadIdx.x;               // 0..511
    int m0 = blockIdx.y * 128, n0 = blockIdx.x * 128;
    long long Aoff = (long long)bz * sA;
    long long Boff = boff + (long long)bz * sB;

    int lane = tid & 63;
    int w = tid >> 6;
    int wr = w >> 2, wc = w & 3;         // 2 x 4 wave grid
    int fr = lane & 15;
    int kg = lane >> 4;

    int srA = tid >> 2;                  // A: row 0..127
    int skA = (tid & 3) * 8;             // A: k sub-offset
    int kkB = tid >> 4;                  // B nontrans: k 0..31
    int cbB = (tid & 15) * 8;            // B nontrans: col chunk

    short ra[8], rb[8];

    auto loadA = [&](int kk) {
        int gm = m0 + srA;
        if (gm < M) {
            long long base = Aoff + (long long)gm * lda + kk + skA;
            if (ATY == 0) {
                *reinterpret_cast<uint4*>(ra) =
                    *reinterpret_cast<const uint4*>((const bf16*)Av + base);
            } else {
                float4 f0 = *reinterpret_cast<const float4*>((const float*)Av + base);
                float4 f1 = *reinterpret_cast<const float4*>((const float*)Av + base + 4);
                ra[0]=(short)f2b(f0.x); ra[1]=(short)f2b(f0.y);
                ra[2]=(short)f2b(f0.z); ra[3]=(short)f2b(f0.w);
                ra[4]=(short)f2b(f1.x); ra[5]=(short)f2b(f1.y);
                ra[6]=(short)f2b(f1.z); ra[7]=(short)f2b(f1.w);
            }
        } else {
            #pragma unroll
            for (int j = 0; j < 8; ++j) ra[j] = 0;
        }
    };
    auto loadB = [&](int kk) {
        if (TRANSB) {
            int gn = n0 + srA;
            if (gn < N) {
                long long base = Boff + (long long)gn * ldb + kk + skA;
                if (BSRC == 0) {
                    *reinterpret_cast<uint4*>(rb) =
                        *reinterpret_cast<const uint4*>((const bf16*)B + base);
                } else {
                    float4 f0 = *reinterpret_cast<const float4*>((const float*)B + base);
                    float4 f1 = *reinterpret_cast<const float4*>((const float*)B + base + 4);
                    rb[0]=(short)f2b(f0.x); rb[1]=(short)f2b(f0.y);
                    rb[2]=(short)f2b(f0.z); rb[3]=(short)f2b(f0.w);
                    rb[4]=(short)f2b(f1.x); rb[5]=(short)f2b(f1.y);
                    rb[6]=(short)f2b(f1.z); rb[7]=(short)f2b(f1.w);
                }
            } else {
                #pragma unroll
                for (int j = 0; j < 8; ++j) rb[j] = 0;
            }
        } else {
            int gn = n0 + cbB;
            if (gn < N) {
                long long base = Boff + (long long)(kk + kkB) * ldb + gn;
                if (gn + 8 <= N) {
                    if (BSRC == 0) {
                        *reinterpret_cast<uint4*>(rb) =
                            *reinterpret_cast<const uint4*>((const bf16*)B + base);
                    } else {
                        float4 f0 = *reinterpret_cast<const float4*>((const float*)B + base);
                        float4 f1 = *reinterpret_cast<const float4*>((const float*)B + base + 4);
                        rb[0]=(short)f2b(f0.x); rb[1]=(short)f2b(f0.y);
                        rb[2]=(short)f2b(f0.z); rb[3]=(short)f2b(f0.w);
                        rb[4]=(short)f2b(f1.x); rb[5]=(short)f2b(f1.y);
                        rb[6]=(short)f2b(f1.z); rb[7]=(short)f2b(f1.w);
                    }
                } else {
                    #pragma unroll
                    for (int j = 0; j < 8; ++j)
                        rb[j] = (gn + j < N)
                              ? (BSRC ? (short)f2b(((const float*)B)[base + j])
                                      : (short)((const bf16*)B)[base + j])
                              : (short)0;
                }
            } else {
                #pragma unroll
                for (int j = 0; j < 8; ++j) rb[j] = 0;
            }
        }
    };

    f32x4 acc[4][2] = {};

    loadA(0); loadB(0);
    for (int k0 = 0; k0 < K; k0 += 32) {
        *reinterpret_cast<uint4*>(&As[srA][skA]) = *reinterpret_cast<uint4*>(ra);
        if (TRANSB) {
            *reinterpret_cast<uint4*>(&Bs[srA][skA]) = *reinterpret_cast<uint4*>(rb);
        } else {
            #pragma unroll
            for (int j = 0; j < 8; ++j) Bs[cbB + j][kkB] = rb[j];
        }
        __syncthreads();
        if (k0 + 32 < K) { loadA(k0 + 32); loadB(k0 + 32); }

        bf16x8 a[4], bq[2];
        #pragma unroll
        for (int m = 0; m < 4; ++m)
            a[m] = *reinterpret_cast<const bf16x8*>(&As[wr * 64 + m * 16 + fr][kg * 8]);
        #pragma unroll
        for (int n = 0; n < 2; ++n)
            bq[n] = *reinterpret_cast<const bf16x8*>(&Bs[wc * 32 + n * 16 + fr][kg * 8]);
        #pragma unroll
        for (int m = 0; m < 4; ++m)
            #pragma unroll
            for (int n = 0; n < 2; ++n)
                acc[m][n] = __builtin_amdgcn_mfma_f32_16x16x32_bf16(a[m], bq[n], acc[m][n], 0, 0, 0);
        __syncthreads();
    }

    #pragma unroll
    for (int m = 0; m < 4; ++m) {
        #pragma unroll
        for (int n = 0; n < 2; ++n) {
            #pragma unroll
            for (int i = 0; i < 4; ++i) {
                int gm = m0 + wr * 64 + m * 16 + kg * 4 + i;
                int gn = n0 + wc * 32 + n * 16 + fr;
                if (gm >= M || gn >= N) continue;
                float v = acc[m][n][i] * alpha;
                if (bias) v += BSRC ? ((const float*)bias)[biasoff + gn]
                                    : b2f(((const bf16*)bias)[biasoff + gn]);
                if (act == 1) v = quick_gelu(v);
                if (RES) v += Res[(long long)gm * ldres + gn];
                long long ci = sC * bz + (long long)gm * ldc + gn;
                if (OTY) ((float*)Cv)[ci] = v;
                else     ((bf16*)Cv)[ci] = f2b(v);
            }
        }
    }
}

// ---------------------------------------------------------------------------
// Fused softmax + attn_weight accumulate. T1 rows are bf16 with stride LDT.
// aw output stays f32 (full precision from f32 exp).
// ---------------------------------------------------------------------------
__global__ __launch_bounds__(256)
void softmax_aw_kernel(bf16* __restrict__ T1, float* __restrict__ out, int first)
{
    __shared__ float red[256];
    __shared__ float srow[SEQ];
    long long r = blockIdx.x;
    bf16* sr = T1 + r * LDT;
    float* aw = out + (long long)NROWS * CDIM + r * SEQ;
    int tid = threadIdx.x;

    float lmax = -FLT_MAX;
    for (int k = tid; k < SEQ; k += 256) {
        float v = b2f(sr[k]);
        srow[k] = v;
        lmax = fmaxf(lmax, v);
    }
    red[tid] = lmax; __syncthreads();
    for (int st = 128; st > 0; st >>= 1) {
        if (tid < st) red[tid] = fmaxf(red[tid], red[tid + st]);
        __syncthreads();
    }
    float m = red[0]; __syncthreads();

    float ls = 0.f;
    for (int k = tid; k < SEQ; k += 256) {
        float p = expf(srow[k] - m);
        srow[k] = p; ls += p;
    }
    float Z = block_reduce_sum(ls, red);
    float inv = 1.f / fmaxf(Z, 1e-30f);
    const float hscale = 1.f / (float)NHEAD;
    for (int k = tid; k < SEQ; k += 256) {
        float p = srow[k] * inv;
        sr[k] = f2b(p);
        aw[k] = (first ? 0.f : aw[k]) + p * hscale;
    }
}

// ---------------------------------------------------------------------------
// Row softmax (view attention), f32 rows of width 1024, LDS-staged
// ---------------------------------------------------------------------------
__global__ __launch_bounds__(256)
void softmax_rows(float* __restrict__ s)
{
    __shared__ float red[256];
    __shared__ float srow[GTOK];
    long long row = blockIdx.x;
    float* sr = s + row * GTOK;
    int tid = threadIdx.x;
    float lmax = -FLT_MAX;
    #pragma unroll
    for (int i = 0; i < 4; ++i) {
        float v = sr[tid + i * 256];
        srow[tid + i * 256] = v;
        lmax = fmaxf(lmax, v);
    }
    red[tid] = lmax; __syncthreads();
    for (int st = 128; st > 0; st >>= 1) {
        if (tid < st) red[tid] = fmaxf(red[tid], red[tid + st]);
        __syncthreads();
    }
    float m = red[0]; __syncthreads();
    float ls = 0.f;
    #pragma unroll
    for (int i = 0; i < 4; ++i) {
        float p = expf(srow[tid + i * 256] - m);
        srow[tid + i * 256] = p; ls += p;
    }
    float Z = block_reduce_sum(ls, red);
    float inv = 1.f / fmaxf(Z, 1e-30f);
    #pragma unroll
    for (int i = 0; i < 4; ++i) sr[tid + i * 256] = srow[tid + i * 256] * inv;
}

// ---------------------------------------------------------------------------
// Fused adapter + final residual: one block per row.
// adp = gelu(ffn @ w_down + b_down); v = x2 + ffn + 0.5*(adp @ w_up + b_up)
// writes d_out (f32, all rows) and f32 feat (non-cls rows)
// ---------------------------------------------------------------------------
__global__ __launch_bounds__(256)
void adp_final_kernel(const float* __restrict__ ffn, const float* __restrict__ w_down,
                      const float* __restrict__ b_down, const float* __restrict__ w_up,
                      const float* __restrict__ b_up, const float* __restrict__ x2,
                      float* __restrict__ out, float* __restrict__ feat)
{
    __shared__ float rowsh[CDIM];
    __shared__ float red[256];
    __shared__ float a[16];
    long long row = blockIdx.x;
    int tid = threadIdx.x;
    for (int c = tid; c < CDIM; c += 256) rowsh[c] = ffn[row * CDIM + c];
    __syncthreads();
    int n = tid >> 4;
    int part = tid & 15;
    float s = 0.f;
    for (int i = part; i < CDIM; i += 16) s += rowsh[i] * w_down[i * 16 + n];
    red[tid] = s; __syncthreads();
    if (part == 0) {
        float t = 0.f;
        #pragma unroll
        for (int p = 0; p < 16; ++p) t += red[n * 16 + p];
        a[n] = gelu_exact(t + b_down[n]);
    }
    __syncthreads();

    int b = (int)(row / SEQ);
    int sidx = (int)(row % SEQ);
    #pragma unroll
    for (int i = 0; i < 3; ++i) {
        int c = tid + i * 256;
        float acc = b_up[c];
        #pragma unroll
        for (int k = 0; k < 16; ++k) acc += a[k] * w_up[k * CDIM + c];
        float v = x2[row * CDIM + c] + rowsh[c] + 0.5f * acc;
        out[row * CDIM + c] = v;
        if (sidx > 0)
            feat[((long long)b * GTOK + (sidx - 1)) * CDIM + c] = v;
    }
}

// ---------------------------------------------------------------------------
// Deterministic segment max+mean, compacted (round 11, proven)
// ---------------------------------------------------------------------------
__global__ __launch_bounds__(256)
void seg_kernel(const float* __restrict__ feat, const int* __restrict__ idx,
                float* __restrict__ y)
{
    __shared__ int sidx[NFEAT];
    __shared__ int list[SEGCAP];
    __shared__ int offs[256];
    int seg = blockIdx.x;
    int tid = threadIdx.x;
    for (int j = tid; j < NFEAT; j += 256) sidx[j] = idx[j];
    __syncthreads();

    int base = tid * 32;
    int cnt = 0;
    #pragma unroll
    for (int i = 0; i < 32; ++i) cnt += (sidx[base + i] == seg) ? 1 : 0;
    offs[tid] = cnt;
    __syncthreads();
    for (int st = 1; st < 256; st <<= 1) {
        int v = (tid >= st) ? offs[tid - st] : 0;
        __syncthreads();
        offs[tid] += v;
        __syncthreads();
    }
    int total = offs[255];
    int pos = offs[tid] - cnt;
    __syncthreads();

    float mx0 = -FLT_MAX, mx1 = -FLT_MAX, mx2 = -FLT_MAX;
    float s0 = 0.f, s1 = 0.f, s2 = 0.f;

    if (total <= SEGCAP) {
        #pragma unroll
        for (int i = 0; i < 32; ++i) {
            int j = base + i;
            if (sidx[j] == seg) list[pos++] = j;
        }
        __syncthreads();
        for (int i = 0; i < total; ++i) {
            const float* fr = feat + (long long)list[i] * CDIM;
            float v0 = fr[tid], v1 = fr[tid + 256], v2 = fr[tid + 512];
            s0 += v0; s1 += v1; s2 += v2;
            mx0 = fmaxf(mx0, v0); mx1 = fmaxf(mx1, v1); mx2 = fmaxf(mx2, v2);
        }
    } else {
        for (int j = 0; j < NFEAT; ++j) {
            if (sidx[j] == seg) {
                const float* fr = feat + (long long)j * CDIM;
                float v0 = fr[tid], v1 = fr[tid + 256], v2 = fr[tid + 512];
                s0 += v0; s1 += v1; s2 += v2;
                mx0 = fmaxf(mx0, v0); mx1 = fmaxf(mx1, v1); mx2 = fmaxf(mx2, v2);
            }
        }
    }

    if (total == 0) { mx0 = mx1 = mx2 = 0.f; }
    float inv = 1.f / (float)(total > 0 ? total : 1);
    float* yr = y + (long long)seg * CDIM;
    yr[tid]       = mx0 + s0 * inv;
    yr[tid + 256] = mx1 + s1 * inv;
    yr[tid + 512] = mx2 + s2 * inv;
}

// ---------------------------------------------------------------------------
// BatchNorm over rows (two-pass) + exact GELU -> bf16
// ---------------------------------------------------------------------------
__global__ __launch_bounds__(128)
void bn_gelu_kernel(const float* __restrict__ y, const float* __restrict__ g,
                    const float* __restrict__ b, long long goff,
                    bf16* __restrict__ out, int R)
{
    __shared__ float red[128];
    int c = blockIdx.x;
    int tid = threadIdx.x;
    float s = 0.f;
    for (int r = tid; r < R; r += 128) s += y[(long long)r * CDIM + c];
    float mean = block_reduce_sum(s, red) / (float)R;
    float ss = 0.f;
    for (int r = tid; r < R; r += 128) {
        float d = y[(long long)r * CDIM + c] - mean;
        ss += d * d;
    }
    float var = fmaxf(block_reduce_sum(ss, red) / (float)R, 0.f);
    float rstd = rsqrtf(var + 1e-5f);
    float gc = g[goff + c], bc = b[goff + c];
    for (int r = tid; r < R; r += 128) {
        float v = (y[(long long)r * CDIM + c] - mean) * rstd * gc + bc;
        out[(long long)r * CDIM + c] = f2b(gelu_exact(v));
    }
}

// ---------------------------------------------------------------------------
// Final fusion: cosine sims over 6 views, weighted sum, write f32 out rows
// ---------------------------------------------------------------------------
__global__ __launch_bounds__(256)
void fuse_final_kernel(const float* __restrict__ feat, const bf16* __restrict__ bn3d,
                       const bf16* __restrict__ bn1d, const int* __restrict__ cluster,
                       const int* __restrict__ fgi, float* __restrict__ out)
{
    __shared__ float red[256];
    __shared__ float simsh[NVIEW];
    int j = blockIdx.x;
    int tid = threadIdx.x;
    int b = j >> 10, g = j & 1023;
    const bf16* x3 = bn3d + (long long)cluster[j] * CDIM;
    float s = 0.f;
    for (int c = tid; c < CDIM; c += 256) { float v = b2f(x3[c]); s += v * v; }
    float nx3 = fmaxf(sqrtf(block_reduce_sum(s, red)), 1e-8f);

    for (int i = 0; i < NVIEW; ++i) {
        const bf16* p = bn1d + ((long long)i * NGRID + fgi[i * NFEAT + j]) * CDIM;
        float d = 0.f, nn = 0.f;
        for (int c = tid; c < CDIM; c += 256) {
            float pv = b2f(p[c]);
            d += pv * b2f(x3[c]); nn += pv * pv;
        }
        float D = block_reduce_sum(d, red);
        float Np = sqrtf(block_reduce_sum(nn, red));
        if (tid == 0) {
            float cosv = D / (fmaxf(Np, 1e-8f) * nx3);
            simsh[i] = (cosv + 1.f) * 0.5f;
        }
        __syncthreads();
    }
    float ssum = 0.f;
    #pragma unroll
    for (int i = 0; i < NVIEW; ++i) ssum += simsh[i];
    float invs = 1.f / fmaxf(ssum, 1e-20f);
    long long orow = ((long long)b * SEQ + 1 + g) * CDIM;
    for (int c = tid; c < CDIM; c += 256) {
        float acc = 0.f;
        #pragma unroll
        for (int i = 0; i < NVIEW; ++i) {
            const bf16* p = bn1d + ((long long)i * NGRID + fgi[i * NFEAT + j]) * CDIM;
            acc += simsh[i] * invs * b2f(p[c]);
        }
        out[orow + c] = feat[(long long)j * CDIM + c] + 0.3f * acc;
    }
}

// ---------------------------------------------------------------------------
// Host side
// ---------------------------------------------------------------------------
extern "C" void kernel_launch(void* const* d_in, const int* in_sizes, int n_in,
                              void* d_out, int out_size, void* d_ws, size_t ws_size,
                              hipStream_t stream)
{
    const float* x      = (const float*)d_in[0];
    const int*  cluster = (const int*)d_in[2];
    const int*  fgi     = (const int*)d_in[3];
    const float* ln1_g = (const float*)d_in[6];
    const float* ln1_b = (const float*)d_in[7];
    const float* w_qkv = (const float*)d_in[8];
    const float* b_qkv = (const float*)d_in[9];
    const float* w_o   = (const float*)d_in[10];
    const float* b_o   = (const float*)d_in[11];
    const float* ln2_g = (const float*)d_in[12];
    const float* ln2_b = (const float*)d_in[13];
    const float* w_fc  = (const float*)d_in[14];
    const float* b_fc  = (const float*)d_in[15];
    const float* w_proj= (const float*)d_in[16];
    const float* b_proj= (const float*)d_in[17];
    const float* w_down= (const float*)d_in[18];
    const float* b_down= (const float*)d_in[19];
    const float* w_up  = (const float*)d_in[20];
    const float* b_up  = (const float*)d_in[21];
    const float* bn3d_g= (const float*)d_in[22];
    const float* bn3d_b= (const float*)d_in[23];
    const float* n3_g  = (const float*)d_in[24];
    const float* n3_b  = (const float*)d_in[25];
    const float* vw_qkv= (const float*)d_in[26];
    const float* vb_qkv= (const float*)d_in[27];
    const float* vw_o  = (const float*)d_in[28];
    const float* vb_o  = (const float*)d_in[29];
    const float* bn1d_g= (const float*)d_in[30];
    const float* bn1d_b= (const float*)d_in[31];
    (void)in_sizes; (void)n_in; (void)out_size; (void)ws_size;

    float* out = (float*)d_out;

    // workspace layout (bytes), total ~185.1 MB
    char* w = (char*)d_ws;
    bf16*  QKV  = (bf16*)w;  w += (long long)NROWS * 3 * CDIM * 2;
    bf16*  H    = (bf16*)w;  w += (long long)NROWS * CDIM * 2;
    float* X2   = (float*)w; w += (long long)NROWS * CDIM * 4;
    bf16*  AO   = (bf16*)w;  w += (long long)NROWS * CDIM * 2;
    float* FFN  = (float*)w; w += (long long)NROWS * CDIM * 4;
    float* T1   = (float*)w; w += (long long)BATCH * SEQ * SEQ * 4;  // also bf16 scores / bf16 MID
    float* ADP  = (float*)w; w += (long long)NROWS * 16 * 4;         // (unused now, kept for layout)
    float* FEAT = (float*)w; w += (long long)NFEAT * CDIM * 4;
    float* Y512 = (float*)w; w += (long long)NCLUST * CDIM * 4;
    bf16*  BN3D = (bf16*)w;  w += (long long)NCLUST * CDIM * 2;
    float* YG   = (float*)w; w += (long long)NGRID * CDIM * 4;
    bf16*  BN1D = (bf16*)w;  w += (long long)NVIEW * NGRID * CDIM * 2;
    bf16*  T1b  = (bf16*)T1;   // main-attn bf16 scores, stride LDT
    (void)ADP;

    dim3 blk(256), blk512(512);

    // ---- stage A: transformer block ----
    ln_kernel<<<NROWS, blk, 0, stream>>>(x, ln1_g, ln1_b, 0LL, H);

    gemm2<0,0,1,0,0><<<dim3(18, 65, 1), blk512, 0, stream>>>(
        H, w_qkv, b_qkv, nullptr, QKV,
        NROWS, 3*CDIM, CDIM, CDIM, 3*CDIM, 3*CDIM, 0, 1.f, 0, 0LL, 0LL, 0, 0, 0);

    // ---- main attention via per-head MFMA GEMMs (bf16 scores, stride LDT) ----
    for (int h = 0; h < NHEAD; ++h) {
        gemm2<1,0,0,0,0><<<dim3(9, 9, BATCH), blk512, 0, stream>>>(
            QKV + h * DHEAD, QKV + CDIM + h * DHEAD, nullptr, nullptr, T1b,
            SEQ, SEQ, DHEAD, 3*CDIM, 3*CDIM, LDT, 0, 0.125f, 0, 0LL, 0LL,
            (long long)SEQ * 3*CDIM, (long long)SEQ * 3*CDIM, (long long)SEQ * LDT);

        softmax_aw_kernel<<<NROWS, blk, 0, stream>>>(T1b, out, h == 0 ? 1 : 0);

        gemm_k<0,0,0,0,0><<<dim3(1, 17, BATCH), blk, 0, stream>>>(
            T1b, QKV + 2*CDIM + h * DHEAD, nullptr, nullptr, AO + h * DHEAD,
            SEQ, DHEAD, SEQ, LDT, 3*CDIM, CDIM, 0, 1.f, 0, 0LL, 0LL,
            (long long)SEQ * LDT, (long long)SEQ * 3*CDIM, (long long)SEQ * CDIM);
    }

    // x2 = AO @ w_o + b_o + x   -> f32
    gemm2<0,0,1,1,1><<<dim3(6, 65, 1), blk512, 0, stream>>>(
        AO, w_o, b_o, x, X2,
        NROWS, CDIM, CDIM, CDIM, CDIM, CDIM, CDIM, 1.f, 0, 0LL, 0LL, 0, 0, 0);

    ln_kernel<<<NROWS, blk, 0, stream>>>(X2, ln2_g, ln2_b, 0LL, H);

    // FC + proj in 2 row-chunks of 4100; bf16 MID shares T1 region
    {
        bf16* MID = (bf16*)T1;
        for (int cidx = 0; cidx < 2; ++cidx) {
            long long r0 = 4100LL * cidx;
            int m = 4100;
            gemm2<0,0,1,0,0><<<dim3(24, 33, 1), blk512, 0, stream>>>(
                H + r0 * CDIM, w_fc, b_fc, nullptr, MID,
                m, 4*CDIM, CDIM, CDIM, 4*CDIM, 4*CDIM, 0, 1.f, 1, 0LL, 0LL, 0, 0, 0);
            gemm2<0,0,1,1,0><<<dim3(6, 33, 1), blk512, 0, stream>>>(
                MID, w_proj, b_proj, nullptr, FFN + r0 * CDIM,
                m, CDIM, 4*CDIM, 4*CDIM, CDIM, CDIM, 0, 1.f, 0, 0LL, 0LL, 0, 0, 0);
        }
    }

    adp_final_kernel<<<NROWS, blk, 0, stream>>>(FFN, w_down, b_down, w_up, b_up,
                                                X2, out, FEAT);

    // ---- stage B: cluster pooling + BN-GELU ----
    seg_kernel<<<NCLUST, blk, 0, stream>>>(FEAT, cluster, Y512);
    bn_gelu_kernel<<<CDIM, dim3(128), 0, stream>>>(Y512, bn3d_g, bn3d_b, 0LL, BN3D, NCLUST);

    // ---- stage C: 6 views ----
    const float inv_sqrt_c = 0.03608439182435161f; // 1/sqrt(768)
    for (int i = 0; i < NVIEW; ++i) {
        ln_kernel<<<NFEAT, blk, 0, stream>>>(FEAT, n3_g, n3_b, (long long)i * CDIM, H);

        gemm2<0,0,1,0,0><<<dim3(18, 64, 1), blk512, 0, stream>>>(
            H, vw_qkv, vb_qkv, nullptr, QKV,
            NFEAT, 3*CDIM, CDIM, CDIM, 3*CDIM, 3*CDIM, 0, 1.f, 0,
            (long long)i * CDIM * 3*CDIM, (long long)i * 3*CDIM, 0, 0, 0);

        gemm2<1,0,0,1,0><<<dim3(8, 8, BATCH), blk512, 0, stream>>>(
            QKV, QKV + CDIM, nullptr, nullptr, T1,
            GTOK, GTOK, CDIM, 3*CDIM, 3*CDIM, GTOK, 0, inv_sqrt_c, 0, 0LL, 0LL,
            (long long)GTOK * 3*CDIM, (long long)GTOK * 3*CDIM, (long long)GTOK * GTOK);

        softmax_rows<<<BATCH * GTOK, blk, 0, stream>>>(T1);

        gemm2<0,1,0,0,0><<<dim3(6, 8, BATCH), blk512, 0, stream>>>(
            T1, QKV + 2*CDIM, nullptr, nullptr, AO,
            GTOK, CDIM, GTOK, GTOK, 3*CDIM, CDIM, 0, 1.f, 0, 0LL, 0LL,
            (long long)GTOK * GTOK, (long long)GTOK * 3*CDIM, (long long)GTOK * CDIM);

        gemm2<0,0,1,1,1><<<dim3(6, 64, 1), blk512, 0, stream>>>(
            AO, vw_o, vb_o, FEAT, X2,
            NFEAT, CDIM, CDIM, CDIM, CDIM, CDIM, CDIM, 1.f, 0,
            (long long)i * CDIM * CDIM, (long long)i * CDIM, 0, 0, 0);

        seg_kernel<<<NGRID, blk, 0, stream>>>(X2, fgi + i * NFEAT, YG);
        bn_gelu_kernel<<<CDIM, dim3(128), 0, stream>>>(
            YG, bn1d_g, bn1d_b, (long long)i * CDIM,
            BN1D + (long long)i * NGRID * CDIM, NGRID);
    }

    // ---- final fusion ----
    fuse_final_kernel<<<NFEAT, blk, 0, stream>>>(FEAT, BN3D, BN1D, cluster, fgi, out);
}

// Round 15
// 3432.666 us; speedup vs baseline: 1.4577x; 1.4577x over previous
//
#include <hip/hip_runtime.h>
#include <math.h>
#include <float.h>

#define BATCH   8
#define SEQ     1025
#define GTOK    1024
#define CDIM    768
#define NHEAD   12
#define DHEAD   64
#define NVIEW   6
#define NCLUST  512
#define NGRID   1568
#define NROWS   8200
#define NFEAT   8192
#define SEGCAP  2048
#define LDT     1032   // main-attn score row stride (bf16, 16B-aligned rows)

typedef unsigned short bf16;
typedef __attribute__((ext_vector_type(8))) short bf16x8;
typedef __attribute__((ext_vector_type(4))) float f32x4;

__device__ __forceinline__ float b2f(bf16 u) {
    union { unsigned int i; float f; } v; v.i = ((unsigned int)u) << 16; return v.f;
}
__device__ __forceinline__ bf16 f2b(float f) {
    union { float f; unsigned int i; } v; v.f = f;
    unsigned int x = v.i;
    return (bf16)((x + 0x7fffu + ((x >> 16) & 1u)) >> 16);
}

__device__ __forceinline__ float block_reduce_sum(float v, float* red) {
    int tid = threadIdx.x;
    red[tid] = v; __syncthreads();
    for (int s = blockDim.x >> 1; s > 0; s >>= 1) {
        if (tid < s) red[tid] += red[tid + s];
        __syncthreads();
    }
    float r = red[0]; __syncthreads();
    return r;
}

__device__ __forceinline__ float gelu_exact(float v) {
    return 0.5f * v * (1.f + erff(v * 0.70710678118654752f));
}
__device__ __forceinline__ float quick_gelu(float v) {
    return v / (1.f + expf(-1.702f * v));
}

// ---------------------------------------------------------------------------
// Tiled transpose: W (K x N, f32) -> WT (N x K, bf16)
// ---------------------------------------------------------------------------
__global__ __launch_bounds__(256)
void transpose_kernel(const float* __restrict__ W, bf16* __restrict__ WT, int K, int N)
{
    __shared__ float t[32][33];
    int n0 = blockIdx.x * 32, k0 = blockIdx.y * 32;
    int tx = threadIdx.x & 31, ty = threadIdx.x >> 5;   // ty 0..7
    #pragma unroll
    for (int i = 0; i < 4; ++i) {
        int k = k0 + ty + i * 8, n = n0 + tx;
        t[ty + i * 8][tx] = (k < K && n < N) ? W[(long long)k * N + n] : 0.f;
    }
    __syncthreads();
    #pragma unroll
    for (int i = 0; i < 4; ++i) {
        int n = n0 + ty + i * 8, k = k0 + tx;
        if (n < N && k < K)
            WT[(long long)n * K + k] = f2b(t[tx][ty + i * 8]);
    }
}

// ---------------------------------------------------------------------------
// LayerNorm: one block per row (f32 input, f32 gamma/beta, bf16 out)
// ---------------------------------------------------------------------------
__global__ __launch_bounds__(256)
void ln_kernel(const float* __restrict__ x, const float* __restrict__ g,
               const float* __restrict__ b, long long goff, bf16* __restrict__ out)
{
    __shared__ float red[256];
    long long row = blockIdx.x;
    int tid = threadIdx.x;
    long long base = row * CDIM;
    float v0 = x[base + tid], v1 = x[base + tid + 256], v2 = x[base + tid + 512];
    float mean = block_reduce_sum(v0 + v1 + v2, red) * (1.f / CDIM);
    float d0 = v0 - mean, d1 = v1 - mean, d2 = v2 - mean;
    float var = block_reduce_sum(d0 * d0 + d1 * d1 + d2 * d2, red) * (1.f / CDIM);
    float rstd = rsqrtf(var + 1e-5f);
    bf16* orow = out + base;
    orow[tid]       = f2b(d0 * rstd * g[goff + tid]       + b[goff + tid]);
    orow[tid + 256] = f2b(d1 * rstd * g[goff + tid + 256] + b[goff + tid + 256]);
    orow[tid + 512] = f2b(d2 * rstd * g[goff + tid + 512] + b[goff + tid + 512]);
}

// ---------------------------------------------------------------------------
// gemm_k: 64x64-tile MFMA GEMM (narrow-N cases; main AV only).
// B always bf16; bias always f32. Non-transB staging = r13-proven form.
// ---------------------------------------------------------------------------
#define LDSK 40

template<int TRANSB, int ATY, int OTY, int RES>
__global__ __launch_bounds__(256)
void gemm_k(const void* __restrict__ Av, const bf16* __restrict__ B,
            const float* __restrict__ bias, const float* __restrict__ Res,
            void* __restrict__ Cv,
            int M, int N, int K, int lda, int ldb, int ldc, int ldres,
            float alpha, int act, long long boff, long long biasoff,
            long long sA, long long sB, long long sC)
{
    __shared__ short As[64][LDSK];
    __shared__ short Bs[64][LDSK];
    int bz = blockIdx.z;
    int tid = threadIdx.x;
    int m0 = blockIdx.y * 64, n0 = blockIdx.x * 64;
    long long Aoff = (long long)bz * sA;
    long long Boff = boff + (long long)bz * sB;

    int lane = tid & 63;
    int w = tid >> 6;
    int wr = w >> 1, wc = w & 1;
    int fr = lane & 15;
    int kg = lane >> 4;

    f32x4 acc[2][2] = {};

    for (int k0 = 0; k0 < K; k0 += 32) {
        {
            int r = tid >> 2, kb = (tid & 3) * 8;
            int gm = m0 + r;
            short tmp[8] = {};
            if (gm < M) {
                long long base = Aoff + (long long)gm * lda + k0 + kb;
                if (k0 + kb + 8 <= K) {
                    if (ATY == 0) {
                        *reinterpret_cast<uint4*>(tmp) =
                            *reinterpret_cast<const uint4*>((const bf16*)Av + base);
                    } else {
                        float4 f0 = *reinterpret_cast<const float4*>((const float*)Av + base);
                        float4 f1 = *reinterpret_cast<const float4*>((const float*)Av + base + 4);
                        tmp[0]=(short)f2b(f0.x); tmp[1]=(short)f2b(f0.y);
                        tmp[2]=(short)f2b(f0.z); tmp[3]=(short)f2b(f0.w);
                        tmp[4]=(short)f2b(f1.x); tmp[5]=(short)f2b(f1.y);
                        tmp[6]=(short)f2b(f1.z); tmp[7]=(short)f2b(f1.w);
                    }
                } else {
                    #pragma unroll
                    for (int j = 0; j < 8; ++j) {
                        if (k0 + kb + j < K)
                            tmp[j] = ATY ? (short)f2b(((const float*)Av)[base + j])
                                         : (short)((const bf16*)Av)[base + j];
                    }
                }
            }
            *reinterpret_cast<uint4*>(&As[r][kb]) = *reinterpret_cast<uint4*>(tmp);
        }
        {
            int col = tid >> 2, kb = (tid & 3) * 8;
            int gn = n0 + col;
            short tmp[8] = {};
            if (gn < N) {
                if (TRANSB) {
                    long long base = Boff + (long long)gn * ldb + k0 + kb;
                    if (k0 + kb + 8 <= K) {
                        *reinterpret_cast<uint4*>(tmp) =
                            *reinterpret_cast<const uint4*>(B + base);
                    } else {
                        #pragma unroll
                        for (int j = 0; j < 8; ++j)
                            if (k0 + kb + j < K) tmp[j] = (short)B[base + j];
                    }
                } else {
                    #pragma unroll
                    for (int j = 0; j < 8; ++j) {
                        int kk = k0 + kb + j;
                        if (kk < K)
                            tmp[j] = (short)B[Boff + (long long)kk * ldb + gn];
                    }
                }
            }
            *reinterpret_cast<uint4*>(&Bs[col][kb]) = *reinterpret_cast<uint4*>(tmp);
        }
        __syncthreads();

        bf16x8 a0 = *reinterpret_cast<const bf16x8*>(&As[wr * 32 + fr][kg * 8]);
        bf16x8 a1 = *reinterpret_cast<const bf16x8*>(&As[wr * 32 + 16 + fr][kg * 8]);
        bf16x8 b0 = *reinterpret_cast<const bf16x8*>(&Bs[wc * 32 + fr][kg * 8]);
        bf16x8 b1 = *reinterpret_cast<const bf16x8*>(&Bs[wc * 32 + 16 + fr][kg * 8]);
        acc[0][0] = __builtin_amdgcn_mfma_f32_16x16x32_bf16(a0, b0, acc[0][0], 0, 0, 0);
        acc[0][1] = __builtin_amdgcn_mfma_f32_16x16x32_bf16(a0, b1, acc[0][1], 0, 0, 0);
        acc[1][0] = __builtin_amdgcn_mfma_f32_16x16x32_bf16(a1, b0, acc[1][0], 0, 0, 0);
        acc[1][1] = __builtin_amdgcn_mfma_f32_16x16x32_bf16(a1, b1, acc[1][1], 0, 0, 0);
        __syncthreads();
    }

    #pragma unroll
    for (int m = 0; m < 2; ++m) {
        #pragma unroll
        for (int n = 0; n < 2; ++n) {
            #pragma unroll
            for (int i = 0; i < 4; ++i) {
                int gm = m0 + wr * 32 + m * 16 + kg * 4 + i;
                int gn = n0 + wc * 32 + n * 16 + fr;
                if (gm >= M || gn >= N) continue;
                float v = acc[m][n][i] * alpha;
                if (bias) v += bias[biasoff + gn];
                if (act == 1) v = quick_gelu(v);
                if (RES) v += Res[(long long)gm * ldres + gn];
                long long ci = sC * bz + (long long)gm * ldc + gn;
                if (OTY) ((float*)Cv)[ci] = v;
                else     ((bf16*)Cv)[ci] = f2b(v);
            }
        }
    }
}

// ---------------------------------------------------------------------------
// gemm2: 128x128-tile MFMA GEMM, BK=32, 8 waves, register-prefetch pipeline.
// B always bf16; bias always f32. Non-transB staging = r13-proven form.
// Requires K % 32 == 0.
// ---------------------------------------------------------------------------
template<int TRANSB, int ATY, int OTY, int RES>
__global__ __launch_bounds__(512)
void gemm2(const void* __restrict__ Av, const bf16* __restrict__ B,
           const float* __restrict__ bias, const float* __restrict__ Res,
           void* __restrict__ Cv,
           int M, int N, int K, int lda, int ldb, int ldc, int ldres,
           float alpha, int act, long long boff, long long biasoff,
           long long sA, long long sB, long long sC)
{
    __shared__ short As[128][LDSK];
    __shared__ short Bs[128][LDSK];
    int bz = blockIdx.z;
    int tid = threadIdx.x;               // 0..511
    int m0 = blockIdx.y * 128, n0 = blockIdx.x * 128;
    long long Aoff = (long long)bz * sA;
    long long Boff = boff + (long long)bz * sB;

    int lane = tid & 63;
    int w = tid >> 6;
    int wr = w >> 2, wc = w & 3;         // 2 x 4 wave grid
    int fr = lane & 15;
    int kg = lane >> 4;

    int srow = tid >> 2;                 // stage row/col 0..127
    int skb  = (tid & 3) * 8;            // k sub-offset

    short ra[8], rb[8];

    auto loadA = [&](int kk) {
        int gm = m0 + srow;
        if (gm < M) {
            long long base = Aoff + (long long)gm * lda + kk + skb;
            if (ATY == 0) {
                *reinterpret_cast<uint4*>(ra) =
                    *reinterpret_cast<const uint4*>((const bf16*)Av + base);
            } else {
                float4 f0 = *reinterpret_cast<const float4*>((const float*)Av + base);
                float4 f1 = *reinterpret_cast<const float4*>((const float*)Av + base + 4);
                ra[0]=(short)f2b(f0.x); ra[1]=(short)f2b(f0.y);
                ra[2]=(short)f2b(f0.z); ra[3]=(short)f2b(f0.w);
                ra[4]=(short)f2b(f1.x); ra[5]=(short)f2b(f1.y);
                ra[6]=(short)f2b(f1.z); ra[7]=(short)f2b(f1.w);
            }
        } else {
            #pragma unroll
            for (int j = 0; j < 8; ++j) ra[j] = 0;
        }
    };
    auto loadB = [&](int kk) {
        if (TRANSB) {
            int gn = n0 + srow;
            if (gn < N) {
                long long base = Boff + (long long)gn * ldb + kk + skb;
                *reinterpret_cast<uint4*>(rb) =
                    *reinterpret_cast<const uint4*>(B + base);
            } else {
                #pragma unroll
                for (int j = 0; j < 8; ++j) rb[j] = 0;
            }
        } else {
            int gn = n0 + srow;
            if (gn < N) {
                #pragma unroll
                for (int j = 0; j < 8; ++j) {
                    long long bi = Boff + (long long)(kk + skb + j) * ldb + gn;
                    rb[j] = (short)B[bi];
                }
            } else {
                #pragma unroll
                for (int j = 0; j < 8; ++j) rb[j] = 0;
            }
        }
    };

    f32x4 acc[4][2] = {};

    loadA(0); loadB(0);
    for (int k0 = 0; k0 < K; k0 += 32) {
        *reinterpret_cast<uint4*>(&As[srow][skb]) = *reinterpret_cast<uint4*>(ra);
        *reinterpret_cast<uint4*>(&Bs[srow][skb]) = *reinterpret_cast<uint4*>(rb);
        __syncthreads();
        if (k0 + 32 < K) { loadA(k0 + 32); loadB(k0 + 32); }

        bf16x8 a[4], bq[2];
        #pragma unroll
        for (int m = 0; m < 4; ++m)
            a[m] = *reinterpret_cast<const bf16x8*>(&As[wr * 64 + m * 16 + fr][kg * 8]);
        #pragma unroll
        for (int n = 0; n < 2; ++n)
            bq[n] = *reinterpret_cast<const bf16x8*>(&Bs[wc * 32 + n * 16 + fr][kg * 8]);
        #pragma unroll
        for (int m = 0; m < 4; ++m)
            #pragma unroll
            for (int n = 0; n < 2; ++n)
                acc[m][n] = __builtin_amdgcn_mfma_f32_16x16x32_bf16(a[m], bq[n], acc[m][n], 0, 0, 0);
        __syncthreads();
    }

    #pragma unroll
    for (int m = 0; m < 4; ++m) {
        #pragma unroll
        for (int n = 0; n < 2; ++n) {
            #pragma unroll
            for (int i = 0; i < 4; ++i) {
                int gm = m0 + wr * 64 + m * 16 + kg * 4 + i;
                int gn = n0 + wc * 32 + n * 16 + fr;
                if (gm >= M || gn >= N) continue;
                float v = acc[m][n][i] * alpha;
                if (bias) v += bias[biasoff + gn];
                if (act == 1) v = quick_gelu(v);
                if (RES) v += Res[(long long)gm * ldres + gn];
                long long ci = sC * bz + (long long)gm * ldc + gn;
                if (OTY) ((float*)Cv)[ci] = v;
                else     ((bf16*)Cv)[ci] = f2b(v);
            }
        }
    }
}

// ---------------------------------------------------------------------------
// Fused softmax + attn_weight accumulate. Scores bf16 rows, stride LDT.
// ---------------------------------------------------------------------------
__global__ __launch_bounds__(256)
void softmax_aw_kernel(bf16* __restrict__ T1, float* __restrict__ out, int first)
{
    __shared__ float red[256];
    __shared__ float srow[SEQ];
    long long r = blockIdx.x;
    bf16* sr = T1 + r * LDT;
    float* aw = out + (long long)NROWS * CDIM + r * SEQ;
    int tid = threadIdx.x;

    float lmax = -FLT_MAX;
    for (int k = tid; k < SEQ; k += 256) {
        float v = b2f(sr[k]);
        srow[k] = v;
        lmax = fmaxf(lmax, v);
    }
    red[tid] = lmax; __syncthreads();
    for (int st = 128; st > 0; st >>= 1) {
        if (tid < st) red[tid] = fmaxf(red[tid], red[tid + st]);
        __syncthreads();
    }
    float m = red[0]; __syncthreads();

    float ls = 0.f;
    for (int k = tid; k < SEQ; k += 256) {
        float p = expf(srow[k] - m);
        srow[k] = p; ls += p;
    }
    float Z = block_reduce_sum(ls, red);
    float inv = 1.f / fmaxf(Z, 1e-30f);
    const float hscale = 1.f / (float)NHEAD;
    for (int k = tid; k < SEQ; k += 256) {
        float p = srow[k] * inv;
        sr[k] = f2b(p);
        aw[k] = (first ? 0.f : aw[k]) + p * hscale;
    }
}

// ---------------------------------------------------------------------------
// Row softmax (view attention), f32 rows of width 1024, LDS-staged
// ---------------------------------------------------------------------------
__global__ __launch_bounds__(256)
void softmax_rows(float* __restrict__ s)
{
    __shared__ float red[256];
    __shared__ float srow[GTOK];
    long long row = blockIdx.x;
    float* sr = s + row * GTOK;
    int tid = threadIdx.x;
    float lmax = -FLT_MAX;
    #pragma unroll
    for (int i = 0; i < 4; ++i) {
        float v = sr[tid + i * 256];
        srow[tid + i * 256] = v;
        lmax = fmaxf(lmax, v);
    }
    red[tid] = lmax; __syncthreads();
    for (int st = 128; st > 0; st >>= 1) {
        if (tid < st) red[tid] = fmaxf(red[tid], red[tid + st]);
        __syncthreads();
    }
    float m = red[0]; __syncthreads();
    float ls = 0.f;
    #pragma unroll
    for (int i = 0; i < 4; ++i) {
        float p = expf(srow[tid + i * 256] - m);
        srow[tid + i * 256] = p; ls += p;
    }
    float Z = block_reduce_sum(ls, red);
    float inv = 1.f / fmaxf(Z, 1e-30f);
    #pragma unroll
    for (int i = 0; i < 4; ++i) sr[tid + i * 256] = srow[tid + i * 256] * inv;
}

// ---------------------------------------------------------------------------
// Fused adapter + final residual. ffn is bf16 now.
// adp = gelu(ffn @ w_down + b_down); v = x2 + ffn + 0.5*(adp @ w_up + b_up)
// ---------------------------------------------------------------------------
__global__ __launch_bounds__(256)
void adp_final_kernel(const bf16* __restrict__ ffn, const float* __restrict__ w_down,
                      const float* __restrict__ b_down, const float* __restrict__ w_up,
                      const float* __restrict__ b_up, const float* __restrict__ x2,
                      float* __restrict__ out, float* __restrict__ feat)
{
    __shared__ float rowsh[CDIM];
    __shared__ float red[256];
    __shared__ float a[16];
    long long row = blockIdx.x;
    int tid = threadIdx.x;
    for (int c = tid; c < CDIM; c += 256) rowsh[c] = b2f(ffn[row * CDIM + c]);
    __syncthreads();
    int n = tid >> 4;
    int part = tid & 15;
    float s = 0.f;
    for (int i = part; i < CDIM; i += 16) s += rowsh[i] * w_down[i * 16 + n];
    red[tid] = s; __syncthreads();
    if (part == 0) {
        float t = 0.f;
        #pragma unroll
        for (int p = 0; p < 16; ++p) t += red[n * 16 + p];
        a[n] = gelu_exact(t + b_down[n]);
    }
    __syncthreads();

    int b = (int)(row / SEQ);
    int sidx = (int)(row % SEQ);
    #pragma unroll
    for (int i = 0; i < 3; ++i) {
        int c = tid + i * 256;
        float acc = b_up[c];
        #pragma unroll
        for (int k = 0; k < 16; ++k) acc += a[k] * w_up[k * CDIM + c];
        float v = x2[row * CDIM + c] + rowsh[c] + 0.5f * acc;
        out[row * CDIM + c] = v;
        if (sidx > 0)
            feat[((long long)b * GTOK + (sidx - 1)) * CDIM + c] = v;
    }
}

// ---------------------------------------------------------------------------
// Deterministic segment max+mean, compacted (round 11, proven)
// ---------------------------------------------------------------------------
__global__ __launch_bounds__(256)
void seg_kernel(const float* __restrict__ feat, const int* __restrict__ idx,
                float* __restrict__ y)
{
    __shared__ int sidx[NFEAT];
    __shared__ int list[SEGCAP];
    __shared__ int offs[256];
    int seg = blockIdx.x;
    int tid = threadIdx.x;
    for (int j = tid; j < NFEAT; j += 256) sidx[j] = idx[j];
    __syncthreads();

    int base = tid * 32;
    int cnt = 0;
    #pragma unroll
    for (int i = 0; i < 32; ++i) cnt += (sidx[base + i] == seg) ? 1 : 0;
    offs[tid] = cnt;
    __syncthreads();
    for (int st = 1; st < 256; st <<= 1) {
        int v = (tid >= st) ? offs[tid - st] : 0;
        __syncthreads();
        offs[tid] += v;
        __syncthreads();
    }
    int total = offs[255];
    int pos = offs[tid] - cnt;
    __syncthreads();

    float mx0 = -FLT_MAX, mx1 = -FLT_MAX, mx2 = -FLT_MAX;
    float s0 = 0.f, s1 = 0.f, s2 = 0.f;

    if (total <= SEGCAP) {
        #pragma unroll
        for (int i = 0; i < 32; ++i) {
            int j = base + i;
            if (sidx[j] == seg) list[pos++] = j;
        }
        __syncthreads();
        for (int i = 0; i < total; ++i) {
            const float* fr = feat + (long long)list[i] * CDIM;
            float v0 = fr[tid], v1 = fr[tid + 256], v2 = fr[tid + 512];
            s0 += v0; s1 += v1; s2 += v2;
            mx0 = fmaxf(mx0, v0); mx1 = fmaxf(mx1, v1); mx2 = fmaxf(mx2, v2);
        }
    } else {
        for (int j = 0; j < NFEAT; ++j) {
            if (sidx[j] == seg) {
                const float* fr = feat + (long long)j * CDIM;
                float v0 = fr[tid], v1 = fr[tid + 256], v2 = fr[tid + 512];
                s0 += v0; s1 += v1; s2 += v2;
                mx0 = fmaxf(mx0, v0); mx1 = fmaxf(mx1, v1); mx2 = fmaxf(mx2, v2);
            }
        }
    }

    if (total == 0) { mx0 = mx1 = mx2 = 0.f; }
    float inv = 1.f / (float)(total > 0 ? total : 1);
    float* yr = y + (long long)seg * CDIM;
    yr[tid]       = mx0 + s0 * inv;
    yr[tid + 256] = mx1 + s1 * inv;
    yr[tid + 512] = mx2 + s2 * inv;
}

// ---------------------------------------------------------------------------
// BatchNorm over rows (two-pass) + exact GELU -> bf16
// ---------------------------------------------------------------------------
__global__ __launch_bounds__(128)
void bn_gelu_kernel(const float* __restrict__ y, const float* __restrict__ g,
                    const float* __restrict__ b, long long goff,
                    bf16* __restrict__ out, int R)
{
    __shared__ float red[128];
    int c = blockIdx.x;
    int tid = threadIdx.x;
    float s = 0.f;
    for (int r = tid; r < R; r += 128) s += y[(long long)r * CDIM + c];
    float mean = block_reduce_sum(s, red) / (float)R;
    float ss = 0.f;
    for (int r = tid; r < R; r += 128) {
        float d = y[(long long)r * CDIM + c] - mean;
        ss += d * d;
    }
    float var = fmaxf(block_reduce_sum(ss, red) / (float)R, 0.f);
    float rstd = rsqrtf(var + 1e-5f);
    float gc = g[goff + c], bc = b[goff + c];
    for (int r = tid; r < R; r += 128) {
        float v = (y[(long long)r * CDIM + c] - mean) * rstd * gc + bc;
        out[(long long)r * CDIM + c] = f2b(gelu_exact(v));
    }
}

// ---------------------------------------------------------------------------
// Final fusion: cosine sims over 6 views, weighted sum, write f32 out rows
// ---------------------------------------------------------------------------
__global__ __launch_bounds__(256)
void fuse_final_kernel(const float* __restrict__ feat, const bf16* __restrict__ bn3d,
                       const bf16* __restrict__ bn1d, const int* __restrict__ cluster,
                       const int* __restrict__ fgi, float* __restrict__ out)
{
    __shared__ float red[256];
    __shared__ float simsh[NVIEW];
    int j = blockIdx.x;
    int tid = threadIdx.x;
    int b = j >> 10, g = j & 1023;
    const bf16* x3 = bn3d + (long long)cluster[j] * CDIM;
    float s = 0.f;
    for (int c = tid; c < CDIM; c += 256) { float v = b2f(x3[c]); s += v * v; }
    float nx3 = fmaxf(sqrtf(block_reduce_sum(s, red)), 1e-8f);

    for (int i = 0; i < NVIEW; ++i) {
        const bf16* p = bn1d + ((long long)i * NGRID + fgi[i * NFEAT + j]) * CDIM;
        float d = 0.f, nn = 0.f;
        for (int c = tid; c < CDIM; c += 256) {
            float pv = b2f(p[c]);
            d += pv * b2f(x3[c]); nn += pv * pv;
        }
        float D = block_reduce_sum(d, red);
        float Np = sqrtf(block_reduce_sum(nn, red));
        if (tid == 0) {
            float cosv = D / (fmaxf(Np, 1e-8f) * nx3);
            simsh[i] = (cosv + 1.f) * 0.5f;
        }
        __syncthreads();
    }
    float ssum = 0.f;
    #pragma unroll
    for (int i = 0; i < NVIEW; ++i) ssum += simsh[i];
    float invs = 1.f / fmaxf(ssum, 1e-20f);
    long long orow = ((long long)b * SEQ + 1 + g) * CDIM;
    for (int c = tid; c < CDIM; c += 256) {
        float acc = 0.f;
        #pragma unroll
        for (int i = 0; i < NVIEW; ++i) {
            const bf16* p = bn1d + ((long long)i * NGRID + fgi[i * NFEAT + j]) * CDIM;
            acc += simsh[i] * invs * b2f(p[c]);
        }
        out[orow + c] = feat[(long long)j * CDIM + c] + 0.3f * acc;
    }
}

// ---------------------------------------------------------------------------
// Host side
// ---------------------------------------------------------------------------
extern "C" void kernel_launch(void* const* d_in, const int* in_sizes, int n_in,
                              void* d_out, int out_size, void* d_ws, size_t ws_size,
                              hipStream_t stream)
{
    const float* x      = (const float*)d_in[0];
    const int*  cluster = (const int*)d_in[2];
    const int*  fgi     = (const int*)d_in[3];
    const float* ln1_g = (const float*)d_in[6];
    const float* ln1_b = (const float*)d_in[7];
    const float* w_qkv = (const float*)d_in[8];
    const float* b_qkv = (const float*)d_in[9];
    const float* w_o   = (const float*)d_in[10];
    const float* b_o   = (const float*)d_in[11];
    const float* ln2_g = (const float*)d_in[12];
    const float* ln2_b = (const float*)d_in[13];
    const float* w_fc  = (const float*)d_in[14];
    const float* b_fc  = (const float*)d_in[15];
    const float* w_proj= (const float*)d_in[16];
    const float* b_proj= (const float*)d_in[17];
    const float* w_down= (const float*)d_in[18];
    const float* b_down= (const float*)d_in[19];
    const float* w_up  = (const float*)d_in[20];
    const float* b_up  = (const float*)d_in[21];
    const float* bn3d_g= (const float*)d_in[22];
    const float* bn3d_b= (const float*)d_in[23];
    const float* n3_g  = (const float*)d_in[24];
    const float* n3_b  = (const float*)d_in[25];
    const float* vw_qkv= (const float*)d_in[26];
    const float* vb_qkv= (const float*)d_in[27];
    const float* vw_o  = (const float*)d_in[28];
    const float* vb_o  = (const float*)d_in[29];
    const float* bn1d_g= (const float*)d_in[30];
    const float* bn1d_b= (const float*)d_in[31];
    (void)in_sizes; (void)n_in; (void)out_size; (void)ws_size;

    float* out = (float*)d_out;

    // workspace layout (bytes), total ~200.1 MB (< proven-safe 209)
    char* w = (char*)d_ws;
    bf16*  QKV    = (bf16*)w;  w += (long long)NROWS * 3 * CDIM * 2;      // 37.8
    bf16*  H      = (bf16*)w;  w += (long long)NROWS * CDIM * 2;          // 12.6
    float* X2     = (float*)w; w += (long long)NROWS * CDIM * 4;          // 25.2
    bf16*  AO     = (bf16*)w;  w += (long long)NROWS * CDIM * 2;          // 12.6
    bf16*  FFN    = (bf16*)w;  w += (long long)NROWS * CDIM * 2;          // 12.6 (bf16)
    float* T1     = (float*)w; w += (long long)BATCH * SEQ * SEQ * 4;     // 33.6
    float* FEAT   = (float*)w; w += (long long)NFEAT * CDIM * 4;          // 25.2
    float* Y512   = (float*)w; w += (long long)NCLUST * CDIM * 4;         // 1.6
    bf16*  BN3D   = (bf16*)w;  w += (long long)NCLUST * CDIM * 2;         // 0.8
    float* YG     = (float*)w; w += (long long)NGRID * CDIM * 4;          // 4.8
    bf16*  BN1D   = (bf16*)w;  w += (long long)NVIEW * NGRID * CDIM * 2;  // 14.5
    bf16*  WQKVT  = (bf16*)w;  w += (long long)(3*CDIM) * CDIM * 2;       // 3.5
    bf16*  WOT    = (bf16*)w;  w += (long long)CDIM * CDIM * 2;           // 1.2
    bf16*  WFCT   = (bf16*)w;  w += (long long)(4*CDIM) * CDIM * 2;       // 4.7
    bf16*  WPROJT = (bf16*)w;  w += (long long)CDIM * (4*CDIM) * 2;       // 4.7
    bf16*  VWQKVT = (bf16*)w;  w += (long long)(3*CDIM) * CDIM * 2;       // 3.5
    bf16*  VWOT   = (bf16*)w;  w += (long long)CDIM * CDIM * 2;           // 1.2
    bf16*  T1b    = (bf16*)T1;  // main-attn bf16 scores, stride LDT

    dim3 blk(256), blk512(512);

    // ---- weight transposes (f32 -> bf16, N x K) ----
    transpose_kernel<<<dim3(72, 24), blk, 0, stream>>>(w_qkv, WQKVT, CDIM, 3*CDIM);
    transpose_kernel<<<dim3(24, 24), blk, 0, stream>>>(w_o, WOT, CDIM, CDIM);
    transpose_kernel<<<dim3(96, 24), blk, 0, stream>>>(w_fc, WFCT, CDIM, 4*CDIM);
    transpose_kernel<<<dim3(24, 96), blk, 0, stream>>>(w_proj, WPROJT, 4*CDIM, CDIM);

    // ---- stage A: transformer block ----
    ln_kernel<<<NROWS, blk, 0, stream>>>(x, ln1_g, ln1_b, 0LL, H);

    gemm2<1,0,0,0><<<dim3(18, 65, 1), blk512, 0, stream>>>(
        H, WQKVT, b_qkv, nullptr, QKV,
        NROWS, 3*CDIM, CDIM, CDIM, CDIM, 3*CDIM, 0, 1.f, 0, 0LL, 0LL, 0, 0, 0);

    // ---- main attention via per-head MFMA GEMMs (bf16 scores, stride LDT) ----
    for (int h = 0; h < NHEAD; ++h) {
        gemm2<1,0,0,0><<<dim3(9, 9, BATCH), blk512, 0, stream>>>(
            QKV + h * DHEAD, QKV + CDIM + h * DHEAD, nullptr, nullptr, T1b,
            SEQ, SEQ, DHEAD, 3*CDIM, 3*CDIM, LDT, 0, 0.125f, 0, 0LL, 0LL,
            (long long)SEQ * 3*CDIM, (long long)SEQ * 3*CDIM, (long long)SEQ * LDT);

        softmax_aw_kernel<<<NROWS, blk, 0, stream>>>(T1b, out, h == 0 ? 1 : 0);

        gemm_k<0,0,0,0><<<dim3(1, 17, BATCH), blk, 0, stream>>>(
            T1b, QKV + 2*CDIM + h * DHEAD, nullptr, nullptr, AO + h * DHEAD,
            SEQ, DHEAD, SEQ, LDT, 3*CDIM, CDIM, 0, 1.f, 0, 0LL, 0LL,
            (long long)SEQ * LDT, (long long)SEQ * 3*CDIM, (long long)SEQ * CDIM);
    }

    // x2 = AO @ w_o + b_o + x   -> f32
    gemm2<1,0,1,1><<<dim3(6, 65, 1), blk512, 0, stream>>>(
        AO, WOT, b_o, x, X2,
        NROWS, CDIM, CDIM, CDIM, CDIM, CDIM, CDIM, 1.f, 0, 0LL, 0LL, 0, 0, 0);

    ln_kernel<<<NROWS, blk, 0, stream>>>(X2, ln2_g, ln2_b, 0LL, H);

    // FC + proj in 2 row-chunks of 4100; bf16 MID shares T1 region
    {
        bf16* MID = (bf16*)T1;
        for (int cidx = 0; cidx < 2; ++cidx) {
            long long r0 = 4100LL * cidx;
            int m = 4100;
            gemm2<1,0,0,0><<<dim3(24, 33, 1), blk512, 0, stream>>>(
                H + r0 * CDIM, WFCT, b_fc, nullptr, MID,
                m, 4*CDIM, CDIM, CDIM, CDIM, 4*CDIM, 0, 1.f, 1, 0LL, 0LL, 0, 0, 0);
            gemm2<1,0,0,0><<<dim3(6, 33, 1), blk512, 0, stream>>>(
                MID, WPROJT, b_proj, nullptr, FFN + r0 * CDIM,
                m, CDIM, 4*CDIM, 4*CDIM, 4*CDIM, CDIM, 0, 1.f, 0, 0LL, 0LL, 0, 0, 0);
        }
    }

    adp_final_kernel<<<NROWS, blk, 0, stream>>>(FFN, w_down, b_down, w_up, b_up,
                                                X2, out, FEAT);

    // ---- stage B: cluster pooling + BN-GELU ----
    seg_kernel<<<NCLUST, blk, 0, stream>>>(FEAT, cluster, Y512);
    bn_gelu_kernel<<<CDIM, dim3(128), 0, stream>>>(Y512, bn3d_g, bn3d_b, 0LL, BN3D, NCLUST);

    // ---- stage C: 6 views ----
    const float inv_sqrt_c = 0.03608439182435161f; // 1/sqrt(768)
    for (int i = 0; i < NVIEW; ++i) {
        transpose_kernel<<<dim3(72, 24), blk, 0, stream>>>(
            vw_qkv + (long long)i * CDIM * 3*CDIM, VWQKVT, CDIM, 3*CDIM);
        transpose_kernel<<<dim3(24, 24), blk, 0, stream>>>(
            vw_o + (long long)i * CDIM * CDIM, VWOT, CDIM, CDIM);

        ln_kernel<<<NFEAT, blk, 0, stream>>>(FEAT, n3_g, n3_b, (long long)i * CDIM, H);

        gemm2<1,0,0,0><<<dim3(18, 64, 1), blk512, 0, stream>>>(
            H, VWQKVT, vb_qkv, nullptr, QKV,
            NFEAT, 3*CDIM, CDIM, CDIM, CDIM, 3*CDIM, 0, 1.f, 0,
            0LL, (long long)i * 3*CDIM, 0, 0, 0);

        gemm2<1,0,1,0><<<dim3(8, 8, BATCH), blk512, 0, stream>>>(
            QKV, QKV + CDIM, nullptr, nullptr, T1,
            GTOK, GTOK, CDIM, 3*CDIM, 3*CDIM, GTOK, 0, inv_sqrt_c, 0, 0LL, 0LL,
            (long long)GTOK * 3*CDIM, (long long)GTOK * 3*CDIM, (long long)GTOK * GTOK);

        softmax_rows<<<BATCH * GTOK, blk, 0, stream>>>(T1);

        gemm2<0,1,0,0><<<dim3(6, 8, BATCH), blk512, 0, stream>>>(
            T1, QKV + 2*CDIM, nullptr, nullptr, AO,
            GTOK, CDIM, GTOK, GTOK, 3*CDIM, CDIM, 0, 1.f, 0, 0LL, 0LL,
            (long long)GTOK * GTOK, (long long)GTOK * 3*CDIM, (long long)GTOK * CDIM);

        gemm2<1,0,1,1><<<dim3(6, 64, 1), blk512, 0, stream>>>(
            AO, VWOT, vb_o, FEAT, X2,
            NFEAT, CDIM, CDIM, CDIM, CDIM, CDIM, CDIM, 1.f, 0,
            0LL, (long long)i * CDIM, 0, 0, 0);

        seg_kernel<<<NGRID, blk, 0, stream>>>(X2, fgi + i * NFEAT, YG);
        bn_gelu_kernel<<<CDIM, dim3(128), 0, stream>>>(
            YG, bn1d_g, bn1d_b, (long long)i * CDIM,
            BN1D + (long long)i * NGRID * CDIM, NGRID);
    }

    // ---- final fusion ----
    fuse_final_kernel<<<NFEAT, blk, 0, stream>>>(FEAT, BN3D, BN1D, cluster, fgi, out);
}

// Round 16
// 2922.184 us; speedup vs baseline: 1.7124x; 1.1747x over previous
//
#include <hip/hip_runtime.h>
#include <math.h>
#include <float.h>

#define BATCH   8
#define SEQ     1025
#define GTOK    1024
#define CDIM    768
#define NHEAD   12
#define DHEAD   64
#define NVIEW   6
#define NCLUST  512
#define NGRID   1568
#define NROWS   8200
#define NFEAT   8192
#define SEGCAP  2048
#define LDT     1032   // main-attn score row stride (bf16, 16B-aligned rows)
#define HG      3      // heads per group (main attention)

typedef unsigned short bf16;
typedef __attribute__((ext_vector_type(8))) short bf16x8;
typedef __attribute__((ext_vector_type(4))) float f32x4;

__device__ __forceinline__ float b2f(bf16 u) {
    union { unsigned int i; float f; } v; v.i = ((unsigned int)u) << 16; return v.f;
}
__device__ __forceinline__ bf16 f2b(float f) {
    union { float f; unsigned int i; } v; v.f = f;
    unsigned int x = v.i;
    return (bf16)((x + 0x7fffu + ((x >> 16) & 1u)) >> 16);
}

__device__ __forceinline__ float block_reduce_sum(float v, float* red) {
    int tid = threadIdx.x;
    red[tid] = v; __syncthreads();
    for (int s = blockDim.x >> 1; s > 0; s >>= 1) {
        if (tid < s) red[tid] += red[tid + s];
        __syncthreads();
    }
    float r = red[0]; __syncthreads();
    return r;
}

__device__ __forceinline__ float gelu_exact(float v) {
    return 0.5f * v * (1.f + erff(v * 0.70710678118654752f));
}
__device__ __forceinline__ float quick_gelu(float v) {
    return v / (1.f + expf(-1.702f * v));
}

// row remap: feat row j -> out row j + 1 + (j>>10)
__device__ __forceinline__ long long rmap(long long j, int remap) {
    return remap ? (j + 1 + (j >> 10)) : j;
}

// ---------------------------------------------------------------------------
// Tiled transpose: W (K x N, f32) -> WT (N x K, bf16)
// ---------------------------------------------------------------------------
__global__ __launch_bounds__(256)
void transpose_kernel(const float* __restrict__ W, bf16* __restrict__ WT, int K, int N)
{
    __shared__ float t[32][33];
    int n0 = blockIdx.x * 32, k0 = blockIdx.y * 32;
    int tx = threadIdx.x & 31, ty = threadIdx.x >> 5;
    #pragma unroll
    for (int i = 0; i < 4; ++i) {
        int k = k0 + ty + i * 8, n = n0 + tx;
        t[ty + i * 8][tx] = (k < K && n < N) ? W[(long long)k * N + n] : 0.f;
    }
    __syncthreads();
    #pragma unroll
    for (int i = 0; i < 4; ++i) {
        int n = n0 + ty + i * 8, k = k0 + tx;
        if (n < N && k < K)
            WT[(long long)n * K + k] = f2b(t[tx][ty + i * 8]);
    }
}

// ---------------------------------------------------------------------------
// LayerNorm: one block per row (f32 input, f32 gamma/beta, bf16 out)
// remap=1: input row remapped (reading d_out token rows)
// ---------------------------------------------------------------------------
__global__ __launch_bounds__(256)
void ln_kernel(const float* __restrict__ x, const float* __restrict__ g,
               const float* __restrict__ b, long long goff, bf16* __restrict__ out,
               int remap)
{
    __shared__ float red[256];
    long long row = blockIdx.x;
    int tid = threadIdx.x;
    long long ibase = rmap(row, remap) * CDIM;
    long long obase = row * CDIM;
    float v0 = x[ibase + tid], v1 = x[ibase + tid + 256], v2 = x[ibase + tid + 512];
    float mean = block_reduce_sum(v0 + v1 + v2, red) * (1.f / CDIM);
    float d0 = v0 - mean, d1 = v1 - mean, d2 = v2 - mean;
    float var = block_reduce_sum(d0 * d0 + d1 * d1 + d2 * d2, red) * (1.f / CDIM);
    float rstd = rsqrtf(var + 1e-5f);
    bf16* orow = out + obase;
    orow[tid]       = f2b(d0 * rstd * g[goff + tid]       + b[goff + tid]);
    orow[tid + 256] = f2b(d1 * rstd * g[goff + tid + 256] + b[goff + tid + 256]);
    orow[tid + 512] = f2b(d2 * rstd * g[goff + tid + 512] + b[goff + tid + 512]);
}

// ---------------------------------------------------------------------------
// gemm_k: 64x64-tile MFMA GEMM (narrow-N; main AV). Dual batch strides:
// bz1 = bz % zdiv, bz2 = bz / zdiv.
// ---------------------------------------------------------------------------
#define LDSK 40

template<int TRANSB, int ATY, int OTY, int RES>
__global__ __launch_bounds__(256)
void gemm_k(const void* __restrict__ Av, const bf16* __restrict__ B,
            const float* __restrict__ bias, const float* __restrict__ Res,
            void* __restrict__ Cv,
            int M, int N, int K, int lda, int ldb, int ldc, int ldres,
            float alpha, int act, long long boff, long long biasoff, int zdiv,
            long long sA1, long long sA2, long long sB1, long long sB2,
            long long sC1, long long sC2, long long sRes)
{
    __shared__ short As[64][LDSK];
    __shared__ short Bs[64][LDSK];
    int bz = blockIdx.z;
    int bz1 = bz % zdiv, bz2 = bz / zdiv;
    int tid = threadIdx.x;
    int m0 = blockIdx.y * 64, n0 = blockIdx.x * 64;
    long long Aoff = bz1 * sA1 + bz2 * sA2;
    long long Boff = boff + bz1 * sB1 + bz2 * sB2;
    long long Coff = bz1 * sC1 + bz2 * sC2;
    long long Roff = bz1 * sRes;

    int lane = tid & 63;
    int w = tid >> 6;
    int wr = w >> 1, wc = w & 1;
    int fr = lane & 15;
    int kg = lane >> 4;

    f32x4 acc[2][2] = {};

    for (int k0 = 0; k0 < K; k0 += 32) {
        {
            int r = tid >> 2, kb = (tid & 3) * 8;
            int gm = m0 + r;
            short tmp[8] = {};
            if (gm < M) {
                long long base = Aoff + (long long)gm * lda + k0 + kb;
                if (k0 + kb + 8 <= K) {
                    if (ATY == 0) {
                        *reinterpret_cast<uint4*>(tmp) =
                            *reinterpret_cast<const uint4*>((const bf16*)Av + base);
                    } else {
                        float4 f0 = *reinterpret_cast<const float4*>((const float*)Av + base);
                        float4 f1 = *reinterpret_cast<const float4*>((const float*)Av + base + 4);
                        tmp[0]=(short)f2b(f0.x); tmp[1]=(short)f2b(f0.y);
                        tmp[2]=(short)f2b(f0.z); tmp[3]=(short)f2b(f0.w);
                        tmp[4]=(short)f2b(f1.x); tmp[5]=(short)f2b(f1.y);
                        tmp[6]=(short)f2b(f1.z); tmp[7]=(short)f2b(f1.w);
                    }
                } else {
                    #pragma unroll
                    for (int j = 0; j < 8; ++j) {
                        if (k0 + kb + j < K)
                            tmp[j] = ATY ? (short)f2b(((const float*)Av)[base + j])
                                         : (short)((const bf16*)Av)[base + j];
                    }
                }
            }
            *reinterpret_cast<uint4*>(&As[r][kb]) = *reinterpret_cast<uint4*>(tmp);
        }
        {
            int col = tid >> 2, kb = (tid & 3) * 8;
            int gn = n0 + col;
            short tmp[8] = {};
            if (gn < N) {
                if (TRANSB) {
                    long long base = Boff + (long long)gn * ldb + k0 + kb;
                    if (k0 + kb + 8 <= K) {
                        *reinterpret_cast<uint4*>(tmp) =
                            *reinterpret_cast<const uint4*>(B + base);
                    } else {
                        #pragma unroll
                        for (int j = 0; j < 8; ++j)
                            if (k0 + kb + j < K) tmp[j] = (short)B[base + j];
                    }
                } else {
                    #pragma unroll
                    for (int j = 0; j < 8; ++j) {
                        int kk = k0 + kb + j;
                        if (kk < K)
                            tmp[j] = (short)B[Boff + (long long)kk * ldb + gn];
                    }
                }
            }
            *reinterpret_cast<uint4*>(&Bs[col][kb]) = *reinterpret_cast<uint4*>(tmp);
        }
        __syncthreads();

        bf16x8 a0 = *reinterpret_cast<const bf16x8*>(&As[wr * 32 + fr][kg * 8]);
        bf16x8 a1 = *reinterpret_cast<const bf16x8*>(&As[wr * 32 + 16 + fr][kg * 8]);
        bf16x8 b0 = *reinterpret_cast<const bf16x8*>(&Bs[wc * 32 + fr][kg * 8]);
        bf16x8 b1 = *reinterpret_cast<const bf16x8*>(&Bs[wc * 32 + 16 + fr][kg * 8]);
        acc[0][0] = __builtin_amdgcn_mfma_f32_16x16x32_bf16(a0, b0, acc[0][0], 0, 0, 0);
        acc[0][1] = __builtin_amdgcn_mfma_f32_16x16x32_bf16(a0, b1, acc[0][1], 0, 0, 0);
        acc[1][0] = __builtin_amdgcn_mfma_f32_16x16x32_bf16(a1, b0, acc[1][0], 0, 0, 0);
        acc[1][1] = __builtin_amdgcn_mfma_f32_16x16x32_bf16(a1, b1, acc[1][1], 0, 0, 0);
        __syncthreads();
    }

    #pragma unroll
    for (int m = 0; m < 2; ++m) {
        #pragma unroll
        for (int n = 0; n < 2; ++n) {
            #pragma unroll
            for (int i = 0; i < 4; ++i) {
                int gm = m0 + wr * 32 + m * 16 + kg * 4 + i;
                int gn = n0 + wc * 32 + n * 16 + fr;
                if (gm >= M || gn >= N) continue;
                float v = acc[m][n][i] * alpha;
                if (bias) v += bias[biasoff + gn];
                if (act == 1) v = quick_gelu(v);
                if (RES) v += Res[Roff + (long long)gm * ldres + gn];
                long long ci = Coff + (long long)gm * ldc + gn;
                if (OTY) ((float*)Cv)[ci] = v;
                else     ((bf16*)Cv)[ci] = f2b(v);
            }
        }
    }
}

// ---------------------------------------------------------------------------
// gemm2: 128x128-tile MFMA GEMM, BK=32, 8 waves, register-prefetch pipeline.
// Dual batch strides (bz1 = bz % zdiv, bz2 = bz / zdiv). Requires K % 32 == 0.
// ---------------------------------------------------------------------------
template<int TRANSB, int ATY, int OTY, int RES>
__global__ __launch_bounds__(512)
void gemm2(const void* __restrict__ Av, const bf16* __restrict__ B,
           const float* __restrict__ bias, const float* __restrict__ Res,
           void* __restrict__ Cv,
           int M, int N, int K, int lda, int ldb, int ldc, int ldres,
           float alpha, int act, long long boff, long long biasoff, int zdiv,
           long long sA1, long long sA2, long long sB1, long long sB2,
           long long sC1, long long sC2, long long sRes)
{
    __shared__ short As[128][LDSK];
    __shared__ short Bs[128][LDSK];
    int bz = blockIdx.z;
    int bz1 = bz % zdiv, bz2 = bz / zdiv;
    int tid = threadIdx.x;
    int m0 = blockIdx.y * 128, n0 = blockIdx.x * 128;
    long long Aoff = bz1 * sA1 + bz2 * sA2;
    long long Boff = boff + bz1 * sB1 + bz2 * sB2;
    long long Coff = bz1 * sC1 + bz2 * sC2;
    long long Roff = bz1 * sRes;

    int lane = tid & 63;
    int w = tid >> 6;
    int wr = w >> 2, wc = w & 3;
    int fr = lane & 15;
    int kg = lane >> 4;

    int srow = tid >> 2;
    int skb  = (tid & 3) * 8;

    short ra[8], rb[8];

    auto loadA = [&](int kk) {
        int gm = m0 + srow;
        if (gm < M) {
            long long base = Aoff + (long long)gm * lda + kk + skb;
            if (ATY == 0) {
                *reinterpret_cast<uint4*>(ra) =
                    *reinterpret_cast<const uint4*>((const bf16*)Av + base);
            } else {
                float4 f0 = *reinterpret_cast<const float4*>((const float*)Av + base);
                float4 f1 = *reinterpret_cast<const float4*>((const float*)Av + base + 4);
                ra[0]=(short)f2b(f0.x); ra[1]=(short)f2b(f0.y);
                ra[2]=(short)f2b(f0.z); ra[3]=(short)f2b(f0.w);
                ra[4]=(short)f2b(f1.x); ra[5]=(short)f2b(f1.y);
                ra[6]=(short)f2b(f1.z); ra[7]=(short)f2b(f1.w);
            }
        } else {
            #pragma unroll
            for (int j = 0; j < 8; ++j) ra[j] = 0;
        }
    };
    auto loadB = [&](int kk) {
        if (TRANSB) {
            int gn = n0 + srow;
            if (gn < N) {
                long long base = Boff + (long long)gn * ldb + kk + skb;
                *reinterpret_cast<uint4*>(rb) =
                    *reinterpret_cast<const uint4*>(B + base);
            } else {
                #pragma unroll
                for (int j = 0; j < 8; ++j) rb[j] = 0;
            }
        } else {
            int gn = n0 + srow;
            if (gn < N) {
                #pragma unroll
                for (int j = 0; j < 8; ++j) {
                    long long bi = Boff + (long long)(kk + skb + j) * ldb + gn;
                    rb[j] = (short)B[bi];
                }
            } else {
                #pragma unroll
                for (int j = 0; j < 8; ++j) rb[j] = 0;
            }
        }
    };

    f32x4 acc[4][2] = {};

    loadA(0); loadB(0);
    for (int k0 = 0; k0 < K; k0 += 32) {
        *reinterpret_cast<uint4*>(&As[srow][skb]) = *reinterpret_cast<uint4*>(ra);
        *reinterpret_cast<uint4*>(&Bs[srow][skb]) = *reinterpret_cast<uint4*>(rb);
        __syncthreads();
        if (k0 + 32 < K) { loadA(k0 + 32); loadB(k0 + 32); }

        bf16x8 a[4], bq[2];
        #pragma unroll
        for (int m = 0; m < 4; ++m)
            a[m] = *reinterpret_cast<const bf16x8*>(&As[wr * 64 + m * 16 + fr][kg * 8]);
        #pragma unroll
        for (int n = 0; n < 2; ++n)
            bq[n] = *reinterpret_cast<const bf16x8*>(&Bs[wc * 32 + n * 16 + fr][kg * 8]);
        #pragma unroll
        for (int m = 0; m < 4; ++m)
            #pragma unroll
            for (int n = 0; n < 2; ++n)
                acc[m][n] = __builtin_amdgcn_mfma_f32_16x16x32_bf16(a[m], bq[n], acc[m][n], 0, 0, 0);
        __syncthreads();
    }

    #pragma unroll
    for (int m = 0; m < 4; ++m) {
        #pragma unroll
        for (int n = 0; n < 2; ++n) {
            #pragma unroll
            for (int i = 0; i < 4; ++i) {
                int gm = m0 + wr * 64 + m * 16 + kg * 4 + i;
                int gn = n0 + wc * 32 + n * 16 + fr;
                if (gm >= M || gn >= N) continue;
                float v = acc[m][n][i] * alpha;
                if (bias) v += bias[biasoff + gn];
                if (act == 1) v = quick_gelu(v);
                if (RES) v += Res[Roff + (long long)gm * ldres + gn];
                long long ci = Coff + (long long)gm * ldc + gn;
                if (OTY) ((float*)Cv)[ci] = v;
                else     ((bf16*)Cv)[ci] = f2b(v);
            }
        }
    }
}

// ---------------------------------------------------------------------------
// Fused softmax + attn_weight accumulate, 3 heads per block.
// Score plane j (j=0..HG-1) for row r at T1b + j*HSTRIDE + r*LDT (bf16).
// aw (+)= sum_j p_j / NHEAD, touched once per group.
// ---------------------------------------------------------------------------
__global__ __launch_bounds__(256)
void softmax_aw3_kernel(bf16* __restrict__ T1, float* __restrict__ out, int first)
{
    __shared__ float red[256];
    __shared__ float srow[SEQ];
    __shared__ float awsh[SEQ];
    long long r = blockIdx.x;
    float* aw = out + (long long)NROWS * CDIM + r * SEQ;
    int tid = threadIdx.x;
    const long long HSTRIDE = (long long)BATCH * SEQ * LDT;
    const float hscale = 1.f / (float)NHEAD;

    for (int k = tid; k < SEQ; k += 256) awsh[k] = 0.f;

    for (int j = 0; j < HG; ++j) {
        bf16* sr = T1 + j * HSTRIDE + r * LDT;
        __syncthreads();
        float lmax = -FLT_MAX;
        for (int k = tid; k < SEQ; k += 256) {
            float v = b2f(sr[k]);
            srow[k] = v;
            lmax = fmaxf(lmax, v);
        }
        red[tid] = lmax; __syncthreads();
        for (int st = 128; st > 0; st >>= 1) {
            if (tid < st) red[tid] = fmaxf(red[tid], red[tid + st]);
            __syncthreads();
        }
        float m = red[0]; __syncthreads();

        float ls = 0.f;
        for (int k = tid; k < SEQ; k += 256) {
            float p = expf(srow[k] - m);
            srow[k] = p; ls += p;
        }
        float Z = block_reduce_sum(ls, red);
        float inv = 1.f / fmaxf(Z, 1e-30f);
        for (int k = tid; k < SEQ; k += 256) {
            float p = srow[k] * inv;
            sr[k] = f2b(p);
            awsh[k] += p * hscale;
        }
    }
    __syncthreads();
    for (int k = tid; k < SEQ; k += 256)
        aw[k] = (first ? 0.f : aw[k]) + awsh[k];
}

// ---------------------------------------------------------------------------
// Row softmax (view attention), f32 rows of width 1024, LDS-staged
// ---------------------------------------------------------------------------
__global__ __launch_bounds__(256)
void softmax_rows(float* __restrict__ s)
{
    __shared__ float red[256];
    __shared__ float srow[GTOK];
    long long row = blockIdx.x;
    float* sr = s + row * GTOK;
    int tid = threadIdx.x;
    float lmax = -FLT_MAX;
    #pragma unroll
    for (int i = 0; i < 4; ++i) {
        float v = sr[tid + i * 256];
        srow[tid + i * 256] = v;
        lmax = fmaxf(lmax, v);
    }
    red[tid] = lmax; __syncthreads();
    for (int st = 128; st > 0; st >>= 1) {
        if (tid < st) red[tid] = fmaxf(red[tid], red[tid + st]);
        __syncthreads();
    }
    float m = red[0]; __syncthreads();
    float ls = 0.f;
    #pragma unroll
    for (int i = 0; i < 4; ++i) {
        float p = expf(srow[tid + i * 256] - m);
        srow[tid + i * 256] = p; ls += p;
    }
    float Z = block_reduce_sum(ls, red);
    float inv = 1.f / fmaxf(Z, 1e-30f);
    #pragma unroll
    for (int i = 0; i < 4; ++i) sr[tid + i * 256] = srow[tid + i * 256] * inv;
}

// ---------------------------------------------------------------------------
// Fused adapter + final residual. ffn bf16. Writes only d_out.
// ---------------------------------------------------------------------------
__global__ __launch_bounds__(256)
void adp_final_kernel(const bf16* __restrict__ ffn, const float* __restrict__ w_down,
                      const float* __restrict__ b_down, const float* __restrict__ w_up,
                      const float* __restrict__ b_up, const float* __restrict__ x2,
                      float* __restrict__ out)
{
    __shared__ float rowsh[CDIM];
    __shared__ float red[256];
    __shared__ float a[16];
    long long row = blockIdx.x;
    int tid = threadIdx.x;
    for (int c = tid; c < CDIM; c += 256) rowsh[c] = b2f(ffn[row * CDIM + c]);
    __syncthreads();
    int n = tid >> 4;
    int part = tid & 15;
    float s = 0.f;
    for (int i = part; i < CDIM; i += 16) s += rowsh[i] * w_down[i * 16 + n];
    red[tid] = s; __syncthreads();
    if (part == 0) {
        float t = 0.f;
        #pragma unroll
        for (int p = 0; p < 16; ++p) t += red[n * 16 + p];
        a[n] = gelu_exact(t + b_down[n]);
    }
    __syncthreads();

    #pragma unroll
    for (int i = 0; i < 3; ++i) {
        int c = tid + i * 256;
        float acc = b_up[c];
        #pragma unroll
        for (int k = 0; k < 16; ++k) acc += a[k] * w_up[k * CDIM + c];
        out[row * CDIM + c] = x2[row * CDIM + c] + rowsh[c] + 0.5f * acc;
    }
}

// ---------------------------------------------------------------------------
// Deterministic segment max+mean, compacted. remap=1: rows come from d_out.
// ---------------------------------------------------------------------------
__global__ __launch_bounds__(256)
void seg_kernel(const float* __restrict__ feat, const int* __restrict__ idx,
                float* __restrict__ y, int remap)
{
    __shared__ int sidx[NFEAT];
    __shared__ int list[SEGCAP];
    __shared__ int offs[256];
    int seg = blockIdx.x;
    int tid = threadIdx.x;
    for (int j = tid; j < NFEAT; j += 256) sidx[j] = idx[j];
    __syncthreads();

    int base = tid * 32;
    int cnt = 0;
    #pragma unroll
    for (int i = 0; i < 32; ++i) cnt += (sidx[base + i] == seg) ? 1 : 0;
    offs[tid] = cnt;
    __syncthreads();
    for (int st = 1; st < 256; st <<= 1) {
        int v = (tid >= st) ? offs[tid - st] : 0;
        __syncthreads();
        offs[tid] += v;
        __syncthreads();
    }
    int total = offs[255];
    int pos = offs[tid] - cnt;
    __syncthreads();

    float mx0 = -FLT_MAX, mx1 = -FLT_MAX, mx2 = -FLT_MAX;
    float s0 = 0.f, s1 = 0.f, s2 = 0.f;

    if (total <= SEGCAP) {
        #pragma unroll
        for (int i = 0; i < 32; ++i) {
            int j = base + i;
            if (sidx[j] == seg) list[pos++] = j;
        }
        __syncthreads();
        for (int i = 0; i < total; ++i) {
            const float* fr = feat + rmap(list[i], remap) * CDIM;
            float v0 = fr[tid], v1 = fr[tid + 256], v2 = fr[tid + 512];
            s0 += v0; s1 += v1; s2 += v2;
            mx0 = fmaxf(mx0, v0); mx1 = fmaxf(mx1, v1); mx2 = fmaxf(mx2, v2);
        }
    } else {
        for (int j = 0; j < NFEAT; ++j) {
            if (sidx[j] == seg) {
                const float* fr = feat + rmap(j, remap) * CDIM;
                float v0 = fr[tid], v1 = fr[tid + 256], v2 = fr[tid + 512];
                s0 += v0; s1 += v1; s2 += v2;
                mx0 = fmaxf(mx0, v0); mx1 = fmaxf(mx1, v1); mx2 = fmaxf(mx2, v2);
            }
        }
    }

    if (total == 0) { mx0 = mx1 = mx2 = 0.f; }
    float inv = 1.f / (float)(total > 0 ? total : 1);
    float* yr = y + (long long)seg * CDIM;
    yr[tid]       = mx0 + s0 * inv;
    yr[tid + 256] = mx1 + s1 * inv;
    yr[tid + 512] = mx2 + s2 * inv;
}

// ---------------------------------------------------------------------------
// BatchNorm over rows (two-pass) + exact GELU -> bf16
// ---------------------------------------------------------------------------
__global__ __launch_bounds__(128)
void bn_gelu_kernel(const float* __restrict__ y, const float* __restrict__ g,
                    const float* __restrict__ b, long long goff,
                    bf16* __restrict__ out, int R)
{
    __shared__ float red[128];
    int c = blockIdx.x;
    int tid = threadIdx.x;
    float s = 0.f;
    for (int r = tid; r < R; r += 128) s += y[(long long)r * CDIM + c];
    float mean = block_reduce_sum(s, red) / (float)R;
    float ss = 0.f;
    for (int r = tid; r < R; r += 128) {
        float d = y[(long long)r * CDIM + c] - mean;
        ss += d * d;
    }
    float var = fmaxf(block_reduce_sum(ss, red) / (float)R, 0.f);
    float rstd = rsqrtf(var + 1e-5f);
    float gc = g[goff + c], bc = b[goff + c];
    for (int r = tid; r < R; r += 128) {
        float v = (y[(long long)r * CDIM + c] - mean) * rstd * gc + bc;
        out[(long long)r * CDIM + c] = f2b(gelu_exact(v));
    }
}

// ---------------------------------------------------------------------------
// Final fusion: cosine sims over 6 views, weighted sum; RMW d_out rows.
// ---------------------------------------------------------------------------
__global__ __launch_bounds__(256)
void fuse_final_kernel(const bf16* __restrict__ bn3d, const bf16* __restrict__ bn1d,
                       const int* __restrict__ cluster, const int* __restrict__ fgi,
                       float* __restrict__ out)
{
    __shared__ float red[256];
    __shared__ float simsh[NVIEW];
    int j = blockIdx.x;
    int tid = threadIdx.x;
    int b = j >> 10, g = j & 1023;
    const bf16* x3 = bn3d + (long long)cluster[j] * CDIM;
    float s = 0.f;
    for (int c = tid; c < CDIM; c += 256) { float v = b2f(x3[c]); s += v * v; }
    float nx3 = fmaxf(sqrtf(block_reduce_sum(s, red)), 1e-8f);

    for (int i = 0; i < NVIEW; ++i) {
        const bf16* p = bn1d + ((long long)i * NGRID + fgi[i * NFEAT + j]) * CDIM;
        float d = 0.f, nn = 0.f;
        for (int c = tid; c < CDIM; c += 256) {
            float pv = b2f(p[c]);
            d += pv * b2f(x3[c]); nn += pv * pv;
        }
        float D = block_reduce_sum(d, red);
        float Np = sqrtf(block_reduce_sum(nn, red));
        if (tid == 0) {
            float cosv = D / (fmaxf(Np, 1e-8f) * nx3);
            simsh[i] = (cosv + 1.f) * 0.5f;
        }
        __syncthreads();
    }
    float ssum = 0.f;
    #pragma unroll
    for (int i = 0; i < NVIEW; ++i) ssum += simsh[i];
    float invs = 1.f / fmaxf(ssum, 1e-20f);
    long long orow = ((long long)b * SEQ + 1 + g) * CDIM;
    for (int c = tid; c < CDIM; c += 256) {
        float acc = 0.f;
        #pragma unroll
        for (int i = 0; i < NVIEW; ++i) {
            const bf16* p = bn1d + ((long long)i * NGRID + fgi[i * NFEAT + j]) * CDIM;
            acc += simsh[i] * invs * b2f(p[c]);
        }
        out[orow + c] = out[orow + c] + 0.3f * acc;
    }
}

// ---------------------------------------------------------------------------
// Host side
// ---------------------------------------------------------------------------
extern "C" void kernel_launch(void* const* d_in, const int* in_sizes, int n_in,
                              void* d_out, int out_size, void* d_ws, size_t ws_size,
                              hipStream_t stream)
{
    const float* x      = (const float*)d_in[0];
    const int*  cluster = (const int*)d_in[2];
    const int*  fgi     = (const int*)d_in[3];
    const float* ln1_g = (const float*)d_in[6];
    const float* ln1_b = (const float*)d_in[7];
    const float* w_qkv = (const float*)d_in[8];
    const float* b_qkv = (const float*)d_in[9];
    const float* w_o   = (const float*)d_in[10];
    const float* b_o   = (const float*)d_in[11];
    const float* ln2_g = (const float*)d_in[12];
    const float* ln2_b = (const float*)d_in[13];
    const float* w_fc  = (const float*)d_in[14];
    const float* b_fc  = (const float*)d_in[15];
    const float* w_proj= (const float*)d_in[16];
    const float* b_proj= (const float*)d_in[17];
    const float* w_down= (const float*)d_in[18];
    const float* b_down= (const float*)d_in[19];
    const float* w_up  = (const float*)d_in[20];
    const float* b_up  = (const float*)d_in[21];
    const float* bn3d_g= (const float*)d_in[22];
    const float* bn3d_b= (const float*)d_in[23];
    const float* n3_g  = (const float*)d_in[24];
    const float* n3_b  = (const float*)d_in[25];
    const float* vw_qkv= (const float*)d_in[26];
    const float* vb_qkv= (const float*)d_in[27];
    const float* vw_o  = (const float*)d_in[28];
    const float* vb_o  = (const float*)d_in[29];
    const float* bn1d_g= (const float*)d_in[30];
    const float* bn1d_b= (const float*)d_in[31];
    (void)in_sizes; (void)n_in; (void)out_size; (void)ws_size;

    float* out = (float*)d_out;

    // workspace layout (bytes), total ~192 MB
    char* w = (char*)d_ws;
    bf16*  QKV    = (bf16*)w;  w += (long long)NROWS * 3 * CDIM * 2;          // 37.8
    bf16*  H      = (bf16*)w;  w += (long long)NROWS * CDIM * 2;              // 12.6
    float* X2     = (float*)w; w += (long long)NROWS * CDIM * 4;              // 25.2
    bf16*  AO     = (bf16*)w;  w += (long long)NROWS * CDIM * 2;              // 12.6
    bf16*  FFN    = (bf16*)w;  w += (long long)NROWS * CDIM * 2;              // 12.6
    float* T1     = (float*)w; w += (long long)HG * BATCH * SEQ * LDT * 2;    // 50.8 (bf16 scores x3 / f32 view / MID)
    float* Y512   = (float*)w; w += (long long)NCLUST * CDIM * 4;             // 1.6
    bf16*  BN3D   = (bf16*)w;  w += (long long)NCLUST * CDIM * 2;             // 0.8
    float* YG     = (float*)w; w += (long long)NGRID * CDIM * 4;              // 4.8
    bf16*  BN1D   = (bf16*)w;  w += (long long)NVIEW * NGRID * CDIM * 2;      // 14.5
    bf16*  WQKVT  = (bf16*)w;  w += (long long)(3*CDIM) * CDIM * 2;           // 3.5
    bf16*  WOT    = (bf16*)w;  w += (long long)CDIM * CDIM * 2;               // 1.2
    bf16*  WFCT   = (bf16*)w;  w += (long long)(4*CDIM) * CDIM * 2;           // 4.7
    bf16*  WPROJT = (bf16*)w;  w += (long long)CDIM * (4*CDIM) * 2;           // 4.7
    bf16*  VWQKVT = (bf16*)w;  w += (long long)(3*CDIM) * CDIM * 2;           // 3.5
    bf16*  VWOT   = (bf16*)w;  w += (long long)CDIM * CDIM * 2;               // 1.2
    bf16*  T1b    = (bf16*)T1;

    dim3 blk(256), blk512(512);

    // ---- weight transposes (f32 -> bf16, N x K) ----
    transpose_kernel<<<dim3(72, 24), blk, 0, stream>>>(w_qkv, WQKVT, CDIM, 3*CDIM);
    transpose_kernel<<<dim3(24, 24), blk, 0, stream>>>(w_o, WOT, CDIM, CDIM);
    transpose_kernel<<<dim3(96, 24), blk, 0, stream>>>(w_fc, WFCT, CDIM, 4*CDIM);
    transpose_kernel<<<dim3(24, 96), blk, 0, stream>>>(w_proj, WPROJT, 4*CDIM, CDIM);

    // ---- stage A: transformer block ----
    ln_kernel<<<NROWS, blk, 0, stream>>>(x, ln1_g, ln1_b, 0LL, H, 0);

    gemm2<1,0,0,0><<<dim3(18, 65, 1), blk512, 0, stream>>>(
        H, WQKVT, b_qkv, nullptr, QKV,
        NROWS, 3*CDIM, CDIM, CDIM, CDIM, 3*CDIM, 0, 1.f, 0, 0LL, 0LL,
        1, 0, 0, 0, 0, 0, 0, 0);

    // ---- main attention: 4 groups of 3 heads ----
    const long long HSTR = (long long)BATCH * SEQ * LDT;
    for (int g = 0; g < NHEAD / HG; ++g) {
        int hb = g * HG;
        // scores (z = j*8 + b): Aoff = b*(SEQ*3C) + j*64
        gemm2<1,0,0,0><<<dim3(9, 9, BATCH * HG), blk512, 0, stream>>>(
            QKV + hb * DHEAD, QKV + CDIM + hb * DHEAD, nullptr, nullptr, T1b,
            SEQ, SEQ, DHEAD, 3*CDIM, 3*CDIM, LDT, 0, 0.125f, 0, 0LL, 0LL,
            BATCH, (long long)SEQ * 3*CDIM, DHEAD,
            (long long)SEQ * 3*CDIM, DHEAD,
            (long long)SEQ * LDT, HSTR, 0);

        softmax_aw3_kernel<<<NROWS, blk, 0, stream>>>(T1b, out, g == 0 ? 1 : 0);

        gemm_k<0,0,0,0><<<dim3(1, 17, BATCH * HG), blk, 0, stream>>>(
            T1b, QKV + 2*CDIM + hb * DHEAD, nullptr, nullptr, AO + hb * DHEAD,
            SEQ, DHEAD, SEQ, LDT, 3*CDIM, CDIM, 0, 1.f, 0, 0LL, 0LL,
            BATCH, (long long)SEQ * LDT, HSTR,
            (long long)SEQ * 3*CDIM, DHEAD,
            (long long)SEQ * CDIM, DHEAD, 0);
    }

    // x2 = AO @ w_o + b_o + x   -> f32
    gemm2<1,0,1,1><<<dim3(6, 65, 1), blk512, 0, stream>>>(
        AO, WOT, b_o, x, X2,
        NROWS, CDIM, CDIM, CDIM, CDIM, CDIM, CDIM, 1.f, 0, 0LL, 0LL,
        1, 0, 0, 0, 0, 0, 0, 0);

    ln_kernel<<<NROWS, blk, 0, stream>>>(X2, ln2_g, ln2_b, 0LL, H, 0);

    // FC + proj in 2 row-chunks of 4100; bf16 MID shares T1 region
    {
        bf16* MID = (bf16*)T1;
        for (int cidx = 0; cidx < 2; ++cidx) {
            long long r0 = 4100LL * cidx;
            int m = 4100;
            gemm2<1,0,0,0><<<dim3(24, 33, 1), blk512, 0, stream>>>(
                H + r0 * CDIM, WFCT, b_fc, nullptr, MID,
                m, 4*CDIM, CDIM, CDIM, CDIM, 4*CDIM, 0, 1.f, 1, 0LL, 0LL,
                1, 0, 0, 0, 0, 0, 0, 0);
            gemm2<1,0,0,0><<<dim3(6, 33, 1), blk512, 0, stream>>>(
                MID, WPROJT, b_proj, nullptr, FFN + r0 * CDIM,
                m, CDIM, 4*CDIM, 4*CDIM, 4*CDIM, CDIM, 0, 1.f, 0, 0LL, 0LL,
                1, 0, 0, 0, 0, 0, 0, 0);
        }
    }

    adp_final_kernel<<<NROWS, blk, 0, stream>>>(FFN, w_down, b_down, w_up, b_up,
                                                X2, out);

    // ---- stage B: cluster pooling + BN-GELU (feat rows read from d_out) ----
    seg_kernel<<<NCLUST, blk, 0, stream>>>(out, cluster, Y512, 1);
    bn_gelu_kernel<<<CDIM, dim3(128), 0, stream>>>(Y512, bn3d_g, bn3d_b, 0LL, BN3D, NCLUST);

    // ---- stage C: 6 views ----
    const float inv_sqrt_c = 0.03608439182435161f; // 1/sqrt(768)
    for (int i = 0; i < NVIEW; ++i) {
        transpose_kernel<<<dim3(72, 24), blk, 0, stream>>>(
            vw_qkv + (long long)i * CDIM * 3*CDIM, VWQKVT, CDIM, 3*CDIM);
        transpose_kernel<<<dim3(24, 24), blk, 0, stream>>>(
            vw_o + (long long)i * CDIM * CDIM, VWOT, CDIM, CDIM);

        ln_kernel<<<NFEAT, blk, 0, stream>>>(out, n3_g, n3_b, (long long)i * CDIM, H, 1);

        gemm2<1,0,0,0><<<dim3(18, 64, 1), blk512, 0, stream>>>(
            H, VWQKVT, vb_qkv, nullptr, QKV,
            NFEAT, 3*CDIM, CDIM, CDIM, CDIM, 3*CDIM, 0, 1.f, 0,
            0LL, (long long)i * 3*CDIM, 1, 0, 0, 0, 0, 0, 0, 0);

        gemm2<1,0,1,0><<<dim3(8, 8, BATCH), blk512, 0, stream>>>(
            QKV, QKV + CDIM, nullptr, nullptr, T1,
            GTOK, GTOK, CDIM, 3*CDIM, 3*CDIM, GTOK, 0, inv_sqrt_c, 0, 0LL, 0LL,
            BATCH, (long long)GTOK * 3*CDIM, 0,
            (long long)GTOK * 3*CDIM, 0,
            (long long)GTOK * GTOK, 0, 0);

        softmax_rows<<<BATCH * GTOK, blk, 0, stream>>>(T1);

        gemm2<0,1,0,0><<<dim3(6, 8, BATCH), blk512, 0, stream>>>(
            T1, QKV + 2*CDIM, nullptr, nullptr, AO,
            GTOK, CDIM, GTOK, GTOK, 3*CDIM, CDIM, 0, 1.f, 0, 0LL, 0LL,
            BATCH, (long long)GTOK * GTOK, 0,
            (long long)GTOK * 3*CDIM, 0,
            (long long)GTOK * CDIM, 0, 0);

        // fx = o1 @ vw_o + vb_o + feat(out rows) -> X2, batched over b
        gemm2<1,0,1,1><<<dim3(6, 8, BATCH), blk512, 0, stream>>>(
            AO, VWOT, vb_o, out + CDIM, X2,
            GTOK, CDIM, CDIM, CDIM, CDIM, CDIM, CDIM, 1.f, 0,
            0LL, (long long)i * CDIM,
            BATCH, (long long)GTOK * CDIM, 0, 0, 0,
            (long long)GTOK * CDIM, 0, (long long)SEQ * CDIM);

        seg_kernel<<<NGRID, blk, 0, stream>>>(X2, fgi + i * NFEAT, YG, 0);
        bn_gelu_kernel<<<CDIM, dim3(128), 0, stream>>>(
            YG, bn1d_g, bn1d_b, (long long)i * CDIM,
            BN1D + (long long)i * NGRID * CDIM, NGRID);
    }

    // ---- final fusion (RMW d_out token rows) ----
    fuse_final_kernel<<<NFEAT, blk, 0, stream>>>(BN3D, BN1D, cluster, fgi, out);
}

// Round 17
// 2743.672 us; speedup vs baseline: 1.8238x; 1.0651x over previous
//
#include <hip/hip_runtime.h>
#include <math.h>
#include <float.h>

#define BATCH   8
#define SEQ     1025
#define GTOK    1024
#define CDIM    768
#define NHEAD   12
#define DHEAD   64
#define NVIEW   6
#define NCLUST  512
#define NGRID   1568
#define NROWS   8200
#define NFEAT   8192
#define SEGCAP  2048
#define LDT     1032   // main-attn score row stride (bf16, 16B-aligned rows)
#define HG      3      // heads per group (main attention)

typedef unsigned short bf16;
typedef __attribute__((ext_vector_type(8))) short bf16x8;
typedef __attribute__((ext_vector_type(4))) float f32x4;

__device__ __forceinline__ float b2f(bf16 u) {
    union { unsigned int i; float f; } v; v.i = ((unsigned int)u) << 16; return v.f;
}
__device__ __forceinline__ bf16 f2b(float f) {
    union { float f; unsigned int i; } v; v.f = f;
    unsigned int x = v.i;
    return (bf16)((x + 0x7fffu + ((x >> 16) & 1u)) >> 16);
}

__device__ __forceinline__ float block_reduce_sum(float v, float* red) {
    int tid = threadIdx.x;
    red[tid] = v; __syncthreads();
    for (int s = blockDim.x >> 1; s > 0; s >>= 1) {
        if (tid < s) red[tid] += red[tid + s];
        __syncthreads();
    }
    float r = red[0]; __syncthreads();
    return r;
}

__device__ __forceinline__ float gelu_exact(float v) {
    return 0.5f * v * (1.f + erff(v * 0.70710678118654752f));
}
__device__ __forceinline__ float quick_gelu(float v) {
    return v / (1.f + expf(-1.702f * v));
}

// row remap: feat row j -> out row j + 1 + (j>>10)
__device__ __forceinline__ long long rmap(long long j, int remap) {
    return remap ? (j + 1 + (j >> 10)) : j;
}

// ---------------------------------------------------------------------------
// Tiled transpose: W (K x N, f32) -> WT (N x K, bf16)
// ---------------------------------------------------------------------------
__global__ __launch_bounds__(256)
void transpose_kernel(const float* __restrict__ W, bf16* __restrict__ WT, int K, int N)
{
    __shared__ float t[32][33];
    int n0 = blockIdx.x * 32, k0 = blockIdx.y * 32;
    int tx = threadIdx.x & 31, ty = threadIdx.x >> 5;
    #pragma unroll
    for (int i = 0; i < 4; ++i) {
        int k = k0 + ty + i * 8, n = n0 + tx;
        t[ty + i * 8][tx] = (k < K && n < N) ? W[(long long)k * N + n] : 0.f;
    }
    __syncthreads();
    #pragma unroll
    for (int i = 0; i < 4; ++i) {
        int n = n0 + ty + i * 8, k = k0 + tx;
        if (n < N && k < K)
            WT[(long long)n * K + k] = f2b(t[tx][ty + i * 8]);
    }
}

// ---------------------------------------------------------------------------
// LayerNorm: one block per row (f32 input, f32 gamma/beta, bf16 out)
// ---------------------------------------------------------------------------
__global__ __launch_bounds__(256)
void ln_kernel(const float* __restrict__ x, const float* __restrict__ g,
               const float* __restrict__ b, long long goff, bf16* __restrict__ out,
               int remap)
{
    __shared__ float red[256];
    long long row = blockIdx.x;
    int tid = threadIdx.x;
    long long ibase = rmap(row, remap) * CDIM;
    long long obase = row * CDIM;
    float v0 = x[ibase + tid], v1 = x[ibase + tid + 256], v2 = x[ibase + tid + 512];
    float mean = block_reduce_sum(v0 + v1 + v2, red) * (1.f / CDIM);
    float d0 = v0 - mean, d1 = v1 - mean, d2 = v2 - mean;
    float var = block_reduce_sum(d0 * d0 + d1 * d1 + d2 * d2, red) * (1.f / CDIM);
    float rstd = rsqrtf(var + 1e-5f);
    bf16* orow = out + obase;
    orow[tid]       = f2b(d0 * rstd * g[goff + tid]       + b[goff + tid]);
    orow[tid + 256] = f2b(d1 * rstd * g[goff + tid + 256] + b[goff + tid + 256]);
    orow[tid + 512] = f2b(d2 * rstd * g[goff + tid + 512] + b[goff + tid + 512]);
}

// ---------------------------------------------------------------------------
// gemm_k: 64x64-tile MFMA GEMM (narrow-N; main AV). Dual batch strides.
// ---------------------------------------------------------------------------
#define LDSK 40

template<int TRANSB, int ATY, int OTY, int RES>
__global__ __launch_bounds__(256)
void gemm_k(const void* __restrict__ Av, const bf16* __restrict__ B,
            const float* __restrict__ bias, const float* __restrict__ Res,
            void* __restrict__ Cv,
            int M, int N, int K, int lda, int ldb, int ldc, int ldres,
            float alpha, int act, long long boff, long long biasoff, int zdiv,
            long long sA1, long long sA2, long long sB1, long long sB2,
            long long sC1, long long sC2, long long sRes)
{
    __shared__ short As[64][LDSK];
    __shared__ short Bs[64][LDSK];
    int bz = blockIdx.z;
    int bz1 = bz % zdiv, bz2 = bz / zdiv;
    int tid = threadIdx.x;
    int m0 = blockIdx.y * 64, n0 = blockIdx.x * 64;
    long long Aoff = bz1 * sA1 + bz2 * sA2;
    long long Boff = boff + bz1 * sB1 + bz2 * sB2;
    long long Coff = bz1 * sC1 + bz2 * sC2;
    long long Roff = bz1 * sRes;

    int lane = tid & 63;
    int w = tid >> 6;
    int wr = w >> 1, wc = w & 1;
    int fr = lane & 15;
    int kg = lane >> 4;

    f32x4 acc[2][2] = {};

    for (int k0 = 0; k0 < K; k0 += 32) {
        {
            int r = tid >> 2, kb = (tid & 3) * 8;
            int gm = m0 + r;
            short tmp[8] = {};
            if (gm < M) {
                long long base = Aoff + (long long)gm * lda + k0 + kb;
                if (k0 + kb + 8 <= K) {
                    if (ATY == 0) {
                        *reinterpret_cast<uint4*>(tmp) =
                            *reinterpret_cast<const uint4*>((const bf16*)Av + base);
                    } else {
                        float4 f0 = *reinterpret_cast<const float4*>((const float*)Av + base);
                        float4 f1 = *reinterpret_cast<const float4*>((const float*)Av + base + 4);
                        tmp[0]=(short)f2b(f0.x); tmp[1]=(short)f2b(f0.y);
                        tmp[2]=(short)f2b(f0.z); tmp[3]=(short)f2b(f0.w);
                        tmp[4]=(short)f2b(f1.x); tmp[5]=(short)f2b(f1.y);
                        tmp[6]=(short)f2b(f1.z); tmp[7]=(short)f2b(f1.w);
                    }
                } else {
                    #pragma unroll
                    for (int j = 0; j < 8; ++j) {
                        if (k0 + kb + j < K)
                            tmp[j] = ATY ? (short)f2b(((const float*)Av)[base + j])
                                         : (short)((const bf16*)Av)[base + j];
                    }
                }
            }
            *reinterpret_cast<uint4*>(&As[r][kb]) = *reinterpret_cast<uint4*>(tmp);
        }
        {
            int col = tid >> 2, kb = (tid & 3) * 8;
            int gn = n0 + col;
            short tmp[8] = {};
            if (gn < N) {
                if (TRANSB) {
                    long long base = Boff + (long long)gn * ldb + k0 + kb;
                    if (k0 + kb + 8 <= K) {
                        *reinterpret_cast<uint4*>(tmp) =
                            *reinterpret_cast<const uint4*>(B + base);
                    } else {
                        #pragma unroll
                        for (int j = 0; j < 8; ++j)
                            if (k0 + kb + j < K) tmp[j] = (short)B[base + j];
                    }
                } else {
                    #pragma unroll
                    for (int j = 0; j < 8; ++j) {
                        int kk = k0 + kb + j;
                        if (kk < K)
                            tmp[j] = (short)B[Boff + (long long)kk * ldb + gn];
                    }
                }
            }
            *reinterpret_cast<uint4*>(&Bs[col][kb]) = *reinterpret_cast<uint4*>(tmp);
        }
        __syncthreads();

        bf16x8 a0 = *reinterpret_cast<const bf16x8*>(&As[wr * 32 + fr][kg * 8]);
        bf16x8 a1 = *reinterpret_cast<const bf16x8*>(&As[wr * 32 + 16 + fr][kg * 8]);
        bf16x8 b0 = *reinterpret_cast<const bf16x8*>(&Bs[wc * 32 + fr][kg * 8]);
        bf16x8 b1 = *reinterpret_cast<const bf16x8*>(&Bs[wc * 32 + 16 + fr][kg * 8]);
        acc[0][0] = __builtin_amdgcn_mfma_f32_16x16x32_bf16(a0, b0, acc[0][0], 0, 0, 0);
        acc[0][1] = __builtin_amdgcn_mfma_f32_16x16x32_bf16(a0, b1, acc[0][1], 0, 0, 0);
        acc[1][0] = __builtin_amdgcn_mfma_f32_16x16x32_bf16(a1, b0, acc[1][0], 0, 0, 0);
        acc[1][1] = __builtin_amdgcn_mfma_f32_16x16x32_bf16(a1, b1, acc[1][1], 0, 0, 0);
        __syncthreads();
    }

    #pragma unroll
    for (int m = 0; m < 2; ++m) {
        #pragma unroll
        for (int n = 0; n < 2; ++n) {
            #pragma unroll
            for (int i = 0; i < 4; ++i) {
                int gm = m0 + wr * 32 + m * 16 + kg * 4 + i;
                int gn = n0 + wc * 32 + n * 16 + fr;
                if (gm >= M || gn >= N) continue;
                float v = acc[m][n][i] * alpha;
                if (bias) v += bias[biasoff + gn];
                if (act == 1) v = quick_gelu(v);
                if (RES) v += Res[Roff + (long long)gm * ldres + gn];
                long long ci = Coff + (long long)gm * ldc + gn;
                if (OTY) ((float*)Cv)[ci] = v;
                else     ((bf16*)Cv)[ci] = f2b(v);
            }
        }
    }
}

// ---------------------------------------------------------------------------
// gemm2: 128x128-tile MFMA GEMM, BK=32, 8 waves, register-prefetch pipeline.
// Dual batch strides. Requires K % 32 == 0.
// ---------------------------------------------------------------------------
template<int TRANSB, int ATY, int OTY, int RES>
__global__ __launch_bounds__(512)
void gemm2(const void* __restrict__ Av, const bf16* __restrict__ B,
           const float* __restrict__ bias, const float* __restrict__ Res,
           void* __restrict__ Cv,
           int M, int N, int K, int lda, int ldb, int ldc, int ldres,
           float alpha, int act, long long boff, long long biasoff, int zdiv,
           long long sA1, long long sA2, long long sB1, long long sB2,
           long long sC1, long long sC2, long long sRes)
{
    __shared__ short As[128][LDSK];
    __shared__ short Bs[128][LDSK];
    int bz = blockIdx.z;
    int bz1 = bz % zdiv, bz2 = bz / zdiv;
    int tid = threadIdx.x;
    int m0 = blockIdx.y * 128, n0 = blockIdx.x * 128;
    long long Aoff = bz1 * sA1 + bz2 * sA2;
    long long Boff = boff + bz1 * sB1 + bz2 * sB2;
    long long Coff = bz1 * sC1 + bz2 * sC2;
    long long Roff = bz1 * sRes;

    int lane = tid & 63;
    int w = tid >> 6;
    int wr = w >> 2, wc = w & 3;
    int fr = lane & 15;
    int kg = lane >> 4;

    int srow = tid >> 2;
    int skb  = (tid & 3) * 8;

    short ra[8], rb[8];

    auto loadA = [&](int kk) {
        int gm = m0 + srow;
        if (gm < M) {
            long long base = Aoff + (long long)gm * lda + kk + skb;
            if (ATY == 0) {
                *reinterpret_cast<uint4*>(ra) =
                    *reinterpret_cast<const uint4*>((const bf16*)Av + base);
            } else {
                float4 f0 = *reinterpret_cast<const float4*>((const float*)Av + base);
                float4 f1 = *reinterpret_cast<const float4*>((const float*)Av + base + 4);
                ra[0]=(short)f2b(f0.x); ra[1]=(short)f2b(f0.y);
                ra[2]=(short)f2b(f0.z); ra[3]=(short)f2b(f0.w);
                ra[4]=(short)f2b(f1.x); ra[5]=(short)f2b(f1.y);
                ra[6]=(short)f2b(f1.z); ra[7]=(short)f2b(f1.w);
            }
        } else {
            #pragma unroll
            for (int j = 0; j < 8; ++j) ra[j] = 0;
        }
    };
    auto loadB = [&](int kk) {
        if (TRANSB) {
            int gn = n0 + srow;
            if (gn < N) {
                long long base = Boff + (long long)gn * ldb + kk + skb;
                *reinterpret_cast<uint4*>(rb) =
                    *reinterpret_cast<const uint4*>(B + base);
            } else {
                #pragma unroll
                for (int j = 0; j < 8; ++j) rb[j] = 0;
            }
        } else {
            int gn = n0 + srow;
            if (gn < N) {
                #pragma unroll
                for (int j = 0; j < 8; ++j) {
                    long long bi = Boff + (long long)(kk + skb + j) * ldb + gn;
                    rb[j] = (short)B[bi];
                }
            } else {
                #pragma unroll
                for (int j = 0; j < 8; ++j) rb[j] = 0;
            }
        }
    };

    f32x4 acc[4][2] = {};

    loadA(0); loadB(0);
    for (int k0 = 0; k0 < K; k0 += 32) {
        *reinterpret_cast<uint4*>(&As[srow][skb]) = *reinterpret_cast<uint4*>(ra);
        *reinterpret_cast<uint4*>(&Bs[srow][skb]) = *reinterpret_cast<uint4*>(rb);
        __syncthreads();
        if (k0 + 32 < K) { loadA(k0 + 32); loadB(k0 + 32); }

        bf16x8 a[4], bq[2];
        #pragma unroll
        for (int m = 0; m < 4; ++m)
            a[m] = *reinterpret_cast<const bf16x8*>(&As[wr * 64 + m * 16 + fr][kg * 8]);
        #pragma unroll
        for (int n = 0; n < 2; ++n)
            bq[n] = *reinterpret_cast<const bf16x8*>(&Bs[wc * 32 + n * 16 + fr][kg * 8]);
        #pragma unroll
        for (int m = 0; m < 4; ++m)
            #pragma unroll
            for (int n = 0; n < 2; ++n)
                acc[m][n] = __builtin_amdgcn_mfma_f32_16x16x32_bf16(a[m], bq[n], acc[m][n], 0, 0, 0);
        __syncthreads();
    }

    #pragma unroll
    for (int m = 0; m < 4; ++m) {
        #pragma unroll
        for (int n = 0; n < 2; ++n) {
            #pragma unroll
            for (int i = 0; i < 4; ++i) {
                int gm = m0 + wr * 64 + m * 16 + kg * 4 + i;
                int gn = n0 + wc * 32 + n * 16 + fr;
                if (gm >= M || gn >= N) continue;
                float v = acc[m][n][i] * alpha;
                if (bias) v += bias[biasoff + gn];
                if (act == 1) v = quick_gelu(v);
                if (RES) v += Res[Roff + (long long)gm * ldres + gn];
                long long ci = Coff + (long long)gm * ldc + gn;
                if (OTY) ((float*)Cv)[ci] = v;
                else     ((bf16*)Cv)[ci] = f2b(v);
            }
        }
    }
}

// ---------------------------------------------------------------------------
// Fused softmax + attn_weight accumulate, 3 heads per block (main attention)
// ---------------------------------------------------------------------------
__global__ __launch_bounds__(256)
void softmax_aw3_kernel(bf16* __restrict__ T1, float* __restrict__ out, int first)
{
    __shared__ float red[256];
    __shared__ float srow[SEQ];
    __shared__ float awsh[SEQ];
    long long r = blockIdx.x;
    float* aw = out + (long long)NROWS * CDIM + r * SEQ;
    int tid = threadIdx.x;
    const long long HSTRIDE = (long long)BATCH * SEQ * LDT;
    const float hscale = 1.f / (float)NHEAD;

    for (int k = tid; k < SEQ; k += 256) awsh[k] = 0.f;

    for (int j = 0; j < HG; ++j) {
        bf16* sr = T1 + j * HSTRIDE + r * LDT;
        __syncthreads();
        float lmax = -FLT_MAX;
        for (int k = tid; k < SEQ; k += 256) {
            float v = b2f(sr[k]);
            srow[k] = v;
            lmax = fmaxf(lmax, v);
        }
        red[tid] = lmax; __syncthreads();
        for (int st = 128; st > 0; st >>= 1) {
            if (tid < st) red[tid] = fmaxf(red[tid], red[tid + st]);
            __syncthreads();
        }
        float m = red[0]; __syncthreads();

        float ls = 0.f;
        for (int k = tid; k < SEQ; k += 256) {
            float p = expf(srow[k] - m);
            srow[k] = p; ls += p;
        }
        float Z = block_reduce_sum(ls, red);
        float inv = 1.f / fmaxf(Z, 1e-30f);
        for (int k = tid; k < SEQ; k += 256) {
            float p = srow[k] * inv;
            sr[k] = f2b(p);
            awsh[k] += p * hscale;
        }
    }
    __syncthreads();
    for (int k = tid; k < SEQ; k += 256)
        aw[k] = (first ? 0.f : aw[k]) + awsh[k];
}

// ---------------------------------------------------------------------------
// Row softmax (view attention), bf16 rows of width 1024, f32 math in LDS
// ---------------------------------------------------------------------------
__global__ __launch_bounds__(256)
void softmax_rows_bf16(bf16* __restrict__ s)
{
    __shared__ float red[256];
    __shared__ float srow[GTOK];
    long long row = blockIdx.x;
    bf16* sr = s + row * GTOK;
    int tid = threadIdx.x;
    float lmax = -FLT_MAX;
    #pragma unroll
    for (int i = 0; i < 4; ++i) {
        float v = b2f(sr[tid + i * 256]);
        srow[tid + i * 256] = v;
        lmax = fmaxf(lmax, v);
    }
    red[tid] = lmax; __syncthreads();
    for (int st = 128; st > 0; st >>= 1) {
        if (tid < st) red[tid] = fmaxf(red[tid], red[tid + st]);
        __syncthreads();
    }
    float m = red[0]; __syncthreads();
    float ls = 0.f;
    #pragma unroll
    for (int i = 0; i < 4; ++i) {
        float p = expf(srow[tid + i * 256] - m);
        srow[tid + i * 256] = p; ls += p;
    }
    float Z = block_reduce_sum(ls, red);
    float inv = 1.f / fmaxf(Z, 1e-30f);
    #pragma unroll
    for (int i = 0; i < 4; ++i) sr[tid + i * 256] = f2b(srow[tid + i * 256] * inv);
}

// ---------------------------------------------------------------------------
// Fused adapter + final residual. ffn bf16. Coalesced w_down access:
// n = tid&15 (output col), part = tid>>4 -> consecutive lanes read
// consecutive w_down words.
// ---------------------------------------------------------------------------
__global__ __launch_bounds__(256)
void adp_final_kernel(const bf16* __restrict__ ffn, const float* __restrict__ w_down,
                      const float* __restrict__ b_down, const float* __restrict__ w_up,
                      const float* __restrict__ b_up, const float* __restrict__ x2,
                      float* __restrict__ out)
{
    __shared__ float rowsh[CDIM];
    __shared__ float red[256];
    __shared__ float a[16];
    long long row = blockIdx.x;
    int tid = threadIdx.x;
    for (int c = tid; c < CDIM; c += 256) rowsh[c] = b2f(ffn[row * CDIM + c]);
    __syncthreads();
    int n = tid & 15;        // output col
    int part = tid >> 4;     // partial id
    float s = 0.f;
    for (int i = part; i < CDIM; i += 16) s += rowsh[i] * w_down[i * 16 + n];
    red[tid] = s; __syncthreads();
    if (tid < 16) {          // tid == n, gathers partials p*16 + n
        float t = 0.f;
        #pragma unroll
        for (int p = 0; p < 16; ++p) t += red[p * 16 + tid];
        a[tid] = gelu_exact(t + b_down[tid]);
    }
    __syncthreads();

    #pragma unroll
    for (int i = 0; i < 3; ++i) {
        int c = tid + i * 256;
        float acc = b_up[c];
        #pragma unroll
        for (int k = 0; k < 16; ++k) acc += a[k] * w_up[k * CDIM + c];
        out[row * CDIM + c] = x2[row * CDIM + c] + rowsh[c] + 0.5f * acc;
    }
}

// ---------------------------------------------------------------------------
// Deterministic segment max+mean, compacted. remap=1: rows come from d_out.
// ---------------------------------------------------------------------------
__global__ __launch_bounds__(256)
void seg_kernel(const float* __restrict__ feat, const int* __restrict__ idx,
                float* __restrict__ y, int remap)
{
    __shared__ int sidx[NFEAT];
    __shared__ int list[SEGCAP];
    __shared__ int offs[256];
    int seg = blockIdx.x;
    int tid = threadIdx.x;
    for (int j = tid; j < NFEAT; j += 256) sidx[j] = idx[j];
    __syncthreads();

    int base = tid * 32;
    int cnt = 0;
    #pragma unroll
    for (int i = 0; i < 32; ++i) cnt += (sidx[base + i] == seg) ? 1 : 0;
    offs[tid] = cnt;
    __syncthreads();
    for (int st = 1; st < 256; st <<= 1) {
        int v = (tid >= st) ? offs[tid - st] : 0;
        __syncthreads();
        offs[tid] += v;
        __syncthreads();
    }
    int total = offs[255];
    int pos = offs[tid] - cnt;
    __syncthreads();

    float mx0 = -FLT_MAX, mx1 = -FLT_MAX, mx2 = -FLT_MAX;
    float s0 = 0.f, s1 = 0.f, s2 = 0.f;

    if (total <= SEGCAP) {
        #pragma unroll
        for (int i = 0; i < 32; ++i) {
            int j = base + i;
            if (sidx[j] == seg) list[pos++] = j;
        }
        __syncthreads();
        for (int i = 0; i < total; ++i) {
            const float* fr = feat + rmap(list[i], remap) * CDIM;
            float v0 = fr[tid], v1 = fr[tid + 256], v2 = fr[tid + 512];
            s0 += v0; s1 += v1; s2 += v2;
            mx0 = fmaxf(mx0, v0); mx1 = fmaxf(mx1, v1); mx2 = fmaxf(mx2, v2);
        }
    } else {
        for (int j = 0; j < NFEAT; ++j) {
            if (sidx[j] == seg) {
                const float* fr = feat + rmap(j, remap) * CDIM;
                float v0 = fr[tid], v1 = fr[tid + 256], v2 = fr[tid + 512];
                s0 += v0; s1 += v1; s2 += v2;
                mx0 = fmaxf(mx0, v0); mx1 = fmaxf(mx1, v1); mx2 = fmaxf(mx2, v2);
            }
        }
    }

    if (total == 0) { mx0 = mx1 = mx2 = 0.f; }
    float inv = 1.f / (float)(total > 0 ? total : 1);
    float* yr = y + (long long)seg * CDIM;
    yr[tid]       = mx0 + s0 * inv;
    yr[tid + 256] = mx1 + s1 * inv;
    yr[tid + 512] = mx2 + s2 * inv;
}

// ---------------------------------------------------------------------------
// BatchNorm over rows (two-pass) + exact GELU -> bf16
// ---------------------------------------------------------------------------
__global__ __launch_bounds__(128)
void bn_gelu_kernel(const float* __restrict__ y, const float* __restrict__ g,
                    const float* __restrict__ b, long long goff,
                    bf16* __restrict__ out, int R)
{
    __shared__ float red[128];
    int c = blockIdx.x;
    int tid = threadIdx.x;
    float s = 0.f;
    for (int r = tid; r < R; r += 128) s += y[(long long)r * CDIM + c];
    float mean = block_reduce_sum(s, red) / (float)R;
    float ss = 0.f;
    for (int r = tid; r < R; r += 128) {
        float d = y[(long long)r * CDIM + c] - mean;
        ss += d * d;
    }
    float var = fmaxf(block_reduce_sum(ss, red) / (float)R, 0.f);
    float rstd = rsqrtf(var + 1e-5f);
    float gc = g[goff + c], bc = b[goff + c];
    for (int r = tid; r < R; r += 128) {
        float v = (y[(long long)r * CDIM + c] - mean) * rstd * gc + bc;
        out[(long long)r * CDIM + c] = f2b(gelu_exact(v));
    }
}

// ---------------------------------------------------------------------------
// Final fusion: cosine sims over 6 views, weighted sum; RMW d_out rows.
// ---------------------------------------------------------------------------
__global__ __launch_bounds__(256)
void fuse_final_kernel(const bf16* __restrict__ bn3d, const bf16* __restrict__ bn1d,
                       const int* __restrict__ cluster, const int* __restrict__ fgi,
                       float* __restrict__ out)
{
    __shared__ float red[256];
    __shared__ float simsh[NVIEW];
    int j = blockIdx.x;
    int tid = threadIdx.x;
    int b = j >> 10, g = j & 1023;
    const bf16* x3 = bn3d + (long long)cluster[j] * CDIM;
    float s = 0.f;
    for (int c = tid; c < CDIM; c += 256) { float v = b2f(x3[c]); s += v * v; }
    float nx3 = fmaxf(sqrtf(block_reduce_sum(s, red)), 1e-8f);

    for (int i = 0; i < NVIEW; ++i) {
        const bf16* p = bn1d + ((long long)i * NGRID + fgi[i * NFEAT + j]) * CDIM;
        float d = 0.f, nn = 0.f;
        for (int c = tid; c < CDIM; c += 256) {
            float pv = b2f(p[c]);
            d += pv * b2f(x3[c]); nn += pv * pv;
        }
        float D = block_reduce_sum(d, red);
        float Np = sqrtf(block_reduce_sum(nn, red));
        if (tid == 0) {
            float cosv = D / (fmaxf(Np, 1e-8f) * nx3);
            simsh[i] = (cosv + 1.f) * 0.5f;
        }
        __syncthreads();
    }
    float ssum = 0.f;
    #pragma unroll
    for (int i = 0; i < NVIEW; ++i) ssum += simsh[i];
    float invs = 1.f / fmaxf(ssum, 1e-20f);
    long long orow = ((long long)b * SEQ + 1 + g) * CDIM;
    for (int c = tid; c < CDIM; c += 256) {
        float acc = 0.f;
        #pragma unroll
        for (int i = 0; i < NVIEW; ++i) {
            const bf16* p = bn1d + ((long long)i * NGRID + fgi[i * NFEAT + j]) * CDIM;
            acc += simsh[i] * invs * b2f(p[c]);
        }
        out[orow + c] = out[orow + c] + 0.3f * acc;
    }
}

// ---------------------------------------------------------------------------
// Host side
// ---------------------------------------------------------------------------
extern "C" void kernel_launch(void* const* d_in, const int* in_sizes, int n_in,
                              void* d_out, int out_size, void* d_ws, size_t ws_size,
                              hipStream_t stream)
{
    const float* x      = (const float*)d_in[0];
    const int*  cluster = (const int*)d_in[2];
    const int*  fgi     = (const int*)d_in[3];
    const float* ln1_g = (const float*)d_in[6];
    const float* ln1_b = (const float*)d_in[7];
    const float* w_qkv = (const float*)d_in[8];
    const float* b_qkv = (const float*)d_in[9];
    const float* w_o   = (const float*)d_in[10];
    const float* b_o   = (const float*)d_in[11];
    const float* ln2_g = (const float*)d_in[12];
    const float* ln2_b = (const float*)d_in[13];
    const float* w_fc  = (const float*)d_in[14];
    const float* b_fc  = (const float*)d_in[15];
    const float* w_proj= (const float*)d_in[16];
    const float* b_proj= (const float*)d_in[17];
    const float* w_down= (const float*)d_in[18];
    const float* b_down= (const float*)d_in[19];
    const float* w_up  = (const float*)d_in[20];
    const float* b_up  = (const float*)d_in[21];
    const float* bn3d_g= (const float*)d_in[22];
    const float* bn3d_b= (const float*)d_in[23];
    const float* n3_g  = (const float*)d_in[24];
    const float* n3_b  = (const float*)d_in[25];
    const float* vw_qkv= (const float*)d_in[26];
    const float* vb_qkv= (const float*)d_in[27];
    const float* vw_o  = (const float*)d_in[28];
    const float* vb_o  = (const float*)d_in[29];
    const float* bn1d_g= (const float*)d_in[30];
    const float* bn1d_b= (const float*)d_in[31];
    (void)in_sizes; (void)n_in; (void)out_size; (void)ws_size;

    float* out = (float*)d_out;

    // workspace layout (bytes), total ~192 MB
    char* w = (char*)d_ws;
    bf16*  QKV    = (bf16*)w;  w += (long long)NROWS * 3 * CDIM * 2;
    bf16*  H      = (bf16*)w;  w += (long long)NROWS * CDIM * 2;
    float* X2     = (float*)w; w += (long long)NROWS * CDIM * 4;
    bf16*  AO     = (bf16*)w;  w += (long long)NROWS * CDIM * 2;
    bf16*  FFN    = (bf16*)w;  w += (long long)NROWS * CDIM * 2;
    float* T1     = (float*)w; w += (long long)HG * BATCH * SEQ * LDT * 2;
    float* Y512   = (float*)w; w += (long long)NCLUST * CDIM * 4;
    bf16*  BN3D   = (bf16*)w;  w += (long long)NCLUST * CDIM * 2;
    float* YG     = (float*)w; w += (long long)NGRID * CDIM * 4;
    bf16*  BN1D   = (bf16*)w;  w += (long long)NVIEW * NGRID * CDIM * 2;
    bf16*  WQKVT  = (bf16*)w;  w += (long long)(3*CDIM) * CDIM * 2;
    bf16*  WOT    = (bf16*)w;  w += (long long)CDIM * CDIM * 2;
    bf16*  WFCT   = (bf16*)w;  w += (long long)(4*CDIM) * CDIM * 2;
    bf16*  WPROJT = (bf16*)w;  w += (long long)CDIM * (4*CDIM) * 2;
    bf16*  VWQKVT = (bf16*)w;  w += (long long)(3*CDIM) * CDIM * 2;
    bf16*  VWOT   = (bf16*)w;  w += (long long)CDIM * CDIM * 2;
    bf16*  T1b    = (bf16*)T1;

    dim3 blk(256), blk512(512);

    // ---- weight transposes (f32 -> bf16, N x K) ----
    transpose_kernel<<<dim3(72, 24), blk, 0, stream>>>(w_qkv, WQKVT, CDIM, 3*CDIM);
    transpose_kernel<<<dim3(24, 24), blk, 0, stream>>>(w_o, WOT, CDIM, CDIM);
    transpose_kernel<<<dim3(96, 24), blk, 0, stream>>>(w_fc, WFCT, CDIM, 4*CDIM);
    transpose_kernel<<<dim3(24, 96), blk, 0, stream>>>(w_proj, WPROJT, 4*CDIM, CDIM);

    // ---- stage A: transformer block ----
    ln_kernel<<<NROWS, blk, 0, stream>>>(x, ln1_g, ln1_b, 0LL, H, 0);

    gemm2<1,0,0,0><<<dim3(18, 65, 1), blk512, 0, stream>>>(
        H, WQKVT, b_qkv, nullptr, QKV,
        NROWS, 3*CDIM, CDIM, CDIM, CDIM, 3*CDIM, 0, 1.f, 0, 0LL, 0LL,
        1, 0, 0, 0, 0, 0, 0, 0);

    // ---- main attention: 4 groups of 3 heads ----
    const long long HSTR = (long long)BATCH * SEQ * LDT;
    for (int g = 0; g < NHEAD / HG; ++g) {
        int hb = g * HG;
        gemm2<1,0,0,0><<<dim3(9, 9, BATCH * HG), blk512, 0, stream>>>(
            QKV + hb * DHEAD, QKV + CDIM + hb * DHEAD, nullptr, nullptr, T1b,
            SEQ, SEQ, DHEAD, 3*CDIM, 3*CDIM, LDT, 0, 0.125f, 0, 0LL, 0LL,
            BATCH, (long long)SEQ * 3*CDIM, DHEAD,
            (long long)SEQ * 3*CDIM, DHEAD,
            (long long)SEQ * LDT, HSTR, 0);

        softmax_aw3_kernel<<<NROWS, blk, 0, stream>>>(T1b, out, g == 0 ? 1 : 0);

        gemm_k<0,0,0,0><<<dim3(1, 17, BATCH * HG), blk, 0, stream>>>(
            T1b, QKV + 2*CDIM + hb * DHEAD, nullptr, nullptr, AO + hb * DHEAD,
            SEQ, DHEAD, SEQ, LDT, 3*CDIM, CDIM, 0, 1.f, 0, 0LL, 0LL,
            BATCH, (long long)SEQ * LDT, HSTR,
            (long long)SEQ * 3*CDIM, DHEAD,
            (long long)SEQ * CDIM, DHEAD, 0);
    }

    // x2 = AO @ w_o + b_o + x   -> f32
    gemm2<1,0,1,1><<<dim3(6, 65, 1), blk512, 0, stream>>>(
        AO, WOT, b_o, x, X2,
        NROWS, CDIM, CDIM, CDIM, CDIM, CDIM, CDIM, 1.f, 0, 0LL, 0LL,
        1, 0, 0, 0, 0, 0, 0, 0);

    ln_kernel<<<NROWS, blk, 0, stream>>>(X2, ln2_g, ln2_b, 0LL, H, 0);

    // FC + proj in 2 row-chunks of 4100; bf16 MID shares T1 region
    {
        bf16* MID = (bf16*)T1;
        for (int cidx = 0; cidx < 2; ++cidx) {
            long long r0 = 4100LL * cidx;
            int m = 4100;
            gemm2<1,0,0,0><<<dim3(24, 33, 1), blk512, 0, stream>>>(
                H + r0 * CDIM, WFCT, b_fc, nullptr, MID,
                m, 4*CDIM, CDIM, CDIM, CDIM, 4*CDIM, 0, 1.f, 1, 0LL, 0LL,
                1, 0, 0, 0, 0, 0, 0, 0);
            gemm2<1,0,0,0><<<dim3(6, 33, 1), blk512, 0, stream>>>(
                MID, WPROJT, b_proj, nullptr, FFN + r0 * CDIM,
                m, CDIM, 4*CDIM, 4*CDIM, 4*CDIM, CDIM, 0, 1.f, 0, 0LL, 0LL,
                1, 0, 0, 0, 0, 0, 0, 0);
        }
    }

    adp_final_kernel<<<NROWS, blk, 0, stream>>>(FFN, w_down, b_down, w_up, b_up,
                                                X2, out);

    // ---- stage B: cluster pooling + BN-GELU (feat rows read from d_out) ----
    seg_kernel<<<NCLUST, blk, 0, stream>>>(out, cluster, Y512, 1);
    bn_gelu_kernel<<<CDIM, dim3(128), 0, stream>>>(Y512, bn3d_g, bn3d_b, 0LL, BN3D, NCLUST);

    // ---- stage C: 6 views (bf16 scores in T1b, stride GTOK) ----
    const float inv_sqrt_c = 0.03608439182435161f; // 1/sqrt(768)
    for (int i = 0; i < NVIEW; ++i) {
        transpose_kernel<<<dim3(72, 24), blk, 0, stream>>>(
            vw_qkv + (long long)i * CDIM * 3*CDIM, VWQKVT, CDIM, 3*CDIM);
        transpose_kernel<<<dim3(24, 24), blk, 0, stream>>>(
            vw_o + (long long)i * CDIM * CDIM, VWOT, CDIM, CDIM);

        ln_kernel<<<NFEAT, blk, 0, stream>>>(out, n3_g, n3_b, (long long)i * CDIM, H, 1);

        gemm2<1,0,0,0><<<dim3(18, 64, 1), blk512, 0, stream>>>(
            H, VWQKVT, vb_qkv, nullptr, QKV,
            NFEAT, 3*CDIM, CDIM, CDIM, CDIM, 3*CDIM, 0, 1.f, 0,
            0LL, (long long)i * 3*CDIM, 1, 0, 0, 0, 0, 0, 0, 0);

        // scores -> bf16, ld = GTOK
        gemm2<1,0,0,0><<<dim3(8, 8, BATCH), blk512, 0, stream>>>(
            QKV, QKV + CDIM, nullptr, nullptr, T1b,
            GTOK, GTOK, CDIM, 3*CDIM, 3*CDIM, GTOK, 0, inv_sqrt_c, 0, 0LL, 0LL,
            BATCH, (long long)GTOK * 3*CDIM, 0,
            (long long)GTOK * 3*CDIM, 0,
            (long long)GTOK * GTOK, 0, 0);

        softmax_rows_bf16<<<BATCH * GTOK, blk, 0, stream>>>(T1b);

        // o1 = P(bf16) @ V -> AO (bf16)
        gemm2<0,0,0,0><<<dim3(6, 8, BATCH), blk512, 0, stream>>>(
            T1b, QKV + 2*CDIM, nullptr, nullptr, AO,
            GTOK, CDIM, GTOK, GTOK, 3*CDIM, CDIM, 0, 1.f, 0, 0LL, 0LL,
            BATCH, (long long)GTOK * GTOK, 0,
            (long long)GTOK * 3*CDIM, 0,
            (long long)GTOK * CDIM, 0, 0);

        // fx = o1 @ vw_o + vb_o + feat(out rows) -> X2, batched over b
        gemm2<1,0,1,1><<<dim3(6, 8, BATCH), blk512, 0, stream>>>(
            AO, VWOT, vb_o, out + CDIM, X2,
            GTOK, CDIM, CDIM, CDIM, CDIM, CDIM, CDIM, 1.f, 0,
            0LL, (long long)i * CDIM,
            BATCH, (long long)GTOK * CDIM, 0, 0, 0,
            (long long)GTOK * CDIM, 0, (long long)SEQ * CDIM);

        seg_kernel<<<NGRID, blk, 0, stream>>>(X2, fgi + i * NFEAT, YG, 0);
        bn_gelu_kernel<<<CDIM, dim3(128), 0, stream>>>(
            YG, bn1d_g, bn1d_b, (long long)i * CDIM,
            BN1D + (long long)i * NGRID * CDIM, NGRID);
    }

    // ---- final fusion (RMW d_out token rows) ----
    fuse_final_kernel<<<NFEAT, blk, 0, stream>>>(BN3D, BN1D, cluster, fgi, out);
}

// Round 18
// 2555.984 us; speedup vs baseline: 1.9577x; 1.0734x over previous
//
#include <hip/hip_runtime.h>
#include <math.h>
#include <float.h>

#define BATCH   8
#define SEQ     1025
#define GTOK    1024
#define CDIM    768
#define NHEAD   12
#define DHEAD   64
#define NVIEW   6
#define NCLUST  512
#define NGRID   1568
#define NROWS   8200
#define NFEAT   8192
#define SEGCAP  2048
#define LDT     1032
#define HG      3

typedef unsigned short bf16;
typedef __attribute__((ext_vector_type(8))) short bf16x8;
typedef __attribute__((ext_vector_type(4))) float f32x4;

__device__ __forceinline__ float b2f(bf16 u) {
    union { unsigned int i; float f; } v; v.i = ((unsigned int)u) << 16; return v.f;
}
__device__ __forceinline__ bf16 f2b(float f) {
    union { float f; unsigned int i; } v; v.f = f;
    unsigned int x = v.i;
    return (bf16)((x + 0x7fffu + ((x >> 16) & 1u)) >> 16);
}

// ---- classic tree reduce (seg/adp patterns) ----
__device__ __forceinline__ float block_reduce_sum(float v, float* red) {
    int tid = threadIdx.x;
    red[tid] = v; __syncthreads();
    for (int s = blockDim.x >> 1; s > 0; s >>= 1) {
        if (tid < s) red[tid] += red[tid + s];
        __syncthreads();
    }
    float r = red[0]; __syncthreads();
    return r;
}

// ---- fast wave-shfl reductions (2 barriers) ----
__device__ __forceinline__ float brs_fast(float v, float* red4, int nw) {
    #pragma unroll
    for (int o = 32; o > 0; o >>= 1) v += __shfl_down(v, o);
    int lane = threadIdx.x & 63, wid = threadIdx.x >> 6;
    if (lane == 0) red4[wid] = v;
    __syncthreads();
    float r = 0.f;
    for (int i = 0; i < nw; ++i) r += red4[i];
    __syncthreads();
    return r;
}
__device__ __forceinline__ float brm_fast(float v, float* red4, int nw) {
    #pragma unroll
    for (int o = 32; o > 0; o >>= 1) v = fmaxf(v, __shfl_down(v, o));
    int lane = threadIdx.x & 63, wid = threadIdx.x >> 6;
    if (lane == 0) red4[wid] = v;
    __syncthreads();
    float r = -FLT_MAX;
    for (int i = 0; i < nw; ++i) r = fmaxf(r, red4[i]);
    __syncthreads();
    return r;
}

__device__ __forceinline__ float gelu_exact(float v) {
    return 0.5f * v * (1.f + erff(v * 0.70710678118654752f));
}
__device__ __forceinline__ float quick_gelu(float v) {
    return v / (1.f + expf(-1.702f * v));
}

__device__ __forceinline__ long long rmap(long long j, int remap) {
    return remap ? (j + 1 + (j >> 10)) : j;
}

// ---------------------------------------------------------------------------
// Tiled transpose: W (K x N, f32) -> WT (N x K, bf16)
// ---------------------------------------------------------------------------
__global__ __launch_bounds__(256)
void transpose_kernel(const float* __restrict__ W, bf16* __restrict__ WT, int K, int N)
{
    __shared__ float t[32][33];
    int n0 = blockIdx.x * 32, k0 = blockIdx.y * 32;
    int tx = threadIdx.x & 31, ty = threadIdx.x >> 5;
    #pragma unroll
    for (int i = 0; i < 4; ++i) {
        int k = k0 + ty + i * 8, n = n0 + tx;
        t[ty + i * 8][tx] = (k < K && n < N) ? W[(long long)k * N + n] : 0.f;
    }
    __syncthreads();
    #pragma unroll
    for (int i = 0; i < 4; ++i) {
        int n = n0 + ty + i * 8, k = k0 + tx;
        if (n < N && k < K)
            WT[(long long)n * K + k] = f2b(t[tx][ty + i * 8]);
    }
}

// ---------------------------------------------------------------------------
// Batched bf16 transpose: src[z][k][n] (row stride lds) -> dst[z][n][k] (ldd)
// ---------------------------------------------------------------------------
__global__ __launch_bounds__(256)
void transpose_bf16_kernel(const bf16* __restrict__ src, bf16* __restrict__ dst,
                           int K, int N, int lds, int ldd,
                           long long sSrc, long long sDst)
{
    __shared__ bf16 t[32][34];
    int z = blockIdx.z;
    const bf16* S = src + (long long)z * sSrc;
    bf16* D = dst + (long long)z * sDst;
    int n0 = blockIdx.x * 32, k0 = blockIdx.y * 32;
    int tx = threadIdx.x & 31, ty = threadIdx.x >> 5;
    #pragma unroll
    for (int i = 0; i < 4; ++i) {
        int k = k0 + ty + i * 8, n = n0 + tx;
        t[ty + i * 8][tx] = (k < K && n < N) ? S[(long long)k * lds + n] : (bf16)0;
    }
    __syncthreads();
    #pragma unroll
    for (int i = 0; i < 4; ++i) {
        int n = n0 + ty + i * 8, k = k0 + tx;
        if (n < N && k < K)
            D[(long long)n * ldd + k] = t[tx][ty + i * 8];
    }
}

// ---------------------------------------------------------------------------
// LayerNorm (fast reductions)
// ---------------------------------------------------------------------------
__global__ __launch_bounds__(256)
void ln_kernel(const float* __restrict__ x, const float* __restrict__ g,
               const float* __restrict__ b, long long goff, bf16* __restrict__ out,
               int remap)
{
    __shared__ float red4[4];
    long long row = blockIdx.x;
    int tid = threadIdx.x;
    long long ibase = rmap(row, remap) * CDIM;
    long long obase = row * CDIM;
    float v0 = x[ibase + tid], v1 = x[ibase + tid + 256], v2 = x[ibase + tid + 512];
    float mean = brs_fast(v0 + v1 + v2, red4, 4) * (1.f / CDIM);
    float d0 = v0 - mean, d1 = v1 - mean, d2 = v2 - mean;
    float var = brs_fast(d0 * d0 + d1 * d1 + d2 * d2, red4, 4) * (1.f / CDIM);
    float rstd = rsqrtf(var + 1e-5f);
    bf16* orow = out + obase;
    orow[tid]       = f2b(d0 * rstd * g[goff + tid]       + b[goff + tid]);
    orow[tid + 256] = f2b(d1 * rstd * g[goff + tid + 256] + b[goff + tid + 256]);
    orow[tid + 512] = f2b(d2 * rstd * g[goff + tid + 512] + b[goff + tid + 512]);
}

// ---------------------------------------------------------------------------
// gemm_k: 64x64-tile MFMA GEMM. Dual batch strides.
// ---------------------------------------------------------------------------
#define LDSK 40

template<int TRANSB, int ATY, int OTY, int RES>
__global__ __launch_bounds__(256)
void gemm_k(const void* __restrict__ Av, const bf16* __restrict__ B,
            const float* __restrict__ bias, const float* __restrict__ Res,
            void* __restrict__ Cv,
            int M, int N, int K, int lda, int ldb, int ldc, int ldres,
            float alpha, int act, long long boff, long long biasoff, int zdiv,
            long long sA1, long long sA2, long long sB1, long long sB2,
            long long sC1, long long sC2, long long sRes)
{
    __shared__ short As[64][LDSK];
    __shared__ short Bs[64][LDSK];
    int bz = blockIdx.z;
    int bz1 = bz % zdiv, bz2 = bz / zdiv;
    int tid = threadIdx.x;
    int m0 = blockIdx.y * 64, n0 = blockIdx.x * 64;
    long long Aoff = bz1 * sA1 + bz2 * sA2;
    long long Boff = boff + bz1 * sB1 + bz2 * sB2;
    long long Coff = bz1 * sC1 + bz2 * sC2;
    long long Roff = bz1 * sRes;

    int lane = tid & 63;
    int w = tid >> 6;
    int wr = w >> 1, wc = w & 1;
    int fr = lane & 15;
    int kg = lane >> 4;

    f32x4 acc[2][2] = {};

    for (int k0 = 0; k0 < K; k0 += 32) {
        {
            int r = tid >> 2, kb = (tid & 3) * 8;
            int gm = m0 + r;
            short tmp[8] = {};
            if (gm < M) {
                long long base = Aoff + (long long)gm * lda + k0 + kb;
                if (k0 + kb + 8 <= K) {
                    if (ATY == 0) {
                        *reinterpret_cast<uint4*>(tmp) =
                            *reinterpret_cast<const uint4*>((const bf16*)Av + base);
                    } else {
                        float4 f0 = *reinterpret_cast<const float4*>((const float*)Av + base);
                        float4 f1 = *reinterpret_cast<const float4*>((const float*)Av + base + 4);
                        tmp[0]=(short)f2b(f0.x); tmp[1]=(short)f2b(f0.y);
                        tmp[2]=(short)f2b(f0.z); tmp[3]=(short)f2b(f0.w);
                        tmp[4]=(short)f2b(f1.x); tmp[5]=(short)f2b(f1.y);
                        tmp[6]=(short)f2b(f1.z); tmp[7]=(short)f2b(f1.w);
                    }
                } else {
                    #pragma unroll
                    for (int j = 0; j < 8; ++j) {
                        if (k0 + kb + j < K)
                            tmp[j] = ATY ? (short)f2b(((const float*)Av)[base + j])
                                         : (short)((const bf16*)Av)[base + j];
                    }
                }
            }
            *reinterpret_cast<uint4*>(&As[r][kb]) = *reinterpret_cast<uint4*>(tmp);
        }
        {
            int col = tid >> 2, kb = (tid & 3) * 8;
            int gn = n0 + col;
            short tmp[8] = {};
            if (gn < N) {
                if (TRANSB) {
                    long long base = Boff + (long long)gn * ldb + k0 + kb;
                    if (k0 + kb + 8 <= K) {
                        *reinterpret_cast<uint4*>(tmp) =
                            *reinterpret_cast<const uint4*>(B + base);
                    } else {
                        #pragma unroll
                        for (int j = 0; j < 8; ++j)
                            if (k0 + kb + j < K) tmp[j] = (short)B[base + j];
                    }
                } else {
                    #pragma unroll
                    for (int j = 0; j < 8; ++j) {
                        int kk = k0 + kb + j;
                        if (kk < K)
                            tmp[j] = (short)B[Boff + (long long)kk * ldb + gn];
                    }
                }
            }
            *reinterpret_cast<uint4*>(&Bs[col][kb]) = *reinterpret_cast<uint4*>(tmp);
        }
        __syncthreads();

        bf16x8 a0 = *reinterpret_cast<const bf16x8*>(&As[wr * 32 + fr][kg * 8]);
        bf16x8 a1 = *reinterpret_cast<const bf16x8*>(&As[wr * 32 + 16 + fr][kg * 8]);
        bf16x8 b0 = *reinterpret_cast<const bf16x8*>(&Bs[wc * 32 + fr][kg * 8]);
        bf16x8 b1 = *reinterpret_cast<const bf16x8*>(&Bs[wc * 32 + 16 + fr][kg * 8]);
        acc[0][0] = __builtin_amdgcn_mfma_f32_16x16x32_bf16(a0, b0, acc[0][0], 0, 0, 0);
        acc[0][1] = __builtin_amdgcn_mfma_f32_16x16x32_bf16(a0, b1, acc[0][1], 0, 0, 0);
        acc[1][0] = __builtin_amdgcn_mfma_f32_16x16x32_bf16(a1, b0, acc[1][0], 0, 0, 0);
        acc[1][1] = __builtin_amdgcn_mfma_f32_16x16x32_bf16(a1, b1, acc[1][1], 0, 0, 0);
        __syncthreads();
    }

    #pragma unroll
    for (int m = 0; m < 2; ++m) {
        #pragma unroll
        for (int n = 0; n < 2; ++n) {
            #pragma unroll
            for (int i = 0; i < 4; ++i) {
                int gm = m0 + wr * 32 + m * 16 + kg * 4 + i;
                int gn = n0 + wc * 32 + n * 16 + fr;
                if (gm >= M || gn >= N) continue;
                float v = acc[m][n][i] * alpha;
                if (bias) v += bias[biasoff + gn];
                if (act == 1) v = quick_gelu(v);
                if (RES) v += Res[Roff + (long long)gm * ldres + gn];
                long long ci = Coff + (long long)gm * ldc + gn;
                if (OTY) ((float*)Cv)[ci] = v;
                else     ((bf16*)Cv)[ci] = f2b(v);
            }
        }
    }
}

// ---------------------------------------------------------------------------
// gemm2: 128x128-tile MFMA GEMM, BK=32, 8 waves, register-prefetch pipeline.
// ---------------------------------------------------------------------------
template<int TRANSB, int ATY, int OTY, int RES>
__global__ __launch_bounds__(512)
void gemm2(const void* __restrict__ Av, const bf16* __restrict__ B,
           const float* __restrict__ bias, const float* __restrict__ Res,
           void* __restrict__ Cv,
           int M, int N, int K, int lda, int ldb, int ldc, int ldres,
           float alpha, int act, long long boff, long long biasoff, int zdiv,
           long long sA1, long long sA2, long long sB1, long long sB2,
           long long sC1, long long sC2, long long sRes)
{
    __shared__ short As[128][LDSK];
    __shared__ short Bs[128][LDSK];
    int bz = blockIdx.z;
    int bz1 = bz % zdiv, bz2 = bz / zdiv;
    int tid = threadIdx.x;
    int m0 = blockIdx.y * 128, n0 = blockIdx.x * 128;
    long long Aoff = bz1 * sA1 + bz2 * sA2;
    long long Boff = boff + bz1 * sB1 + bz2 * sB2;
    long long Coff = bz1 * sC1 + bz2 * sC2;
    long long Roff = bz1 * sRes;

    int lane = tid & 63;
    int w = tid >> 6;
    int wr = w >> 2, wc = w & 3;
    int fr = lane & 15;
    int kg = lane >> 4;

    int srow = tid >> 2;
    int skb  = (tid & 3) * 8;

    short ra[8], rb[8];

    auto loadA = [&](int kk) {
        int gm = m0 + srow;
        if (gm < M) {
            long long base = Aoff + (long long)gm * lda + kk + skb;
            if (ATY == 0) {
                *reinterpret_cast<uint4*>(ra) =
                    *reinterpret_cast<const uint4*>((const bf16*)Av + base);
            } else {
                float4 f0 = *reinterpret_cast<const float4*>((const float*)Av + base);
                float4 f1 = *reinterpret_cast<const float4*>((const float*)Av + base + 4);
                ra[0]=(short)f2b(f0.x); ra[1]=(short)f2b(f0.y);
                ra[2]=(short)f2b(f0.z); ra[3]=(short)f2b(f0.w);
                ra[4]=(short)f2b(f1.x); ra[5]=(short)f2b(f1.y);
                ra[6]=(short)f2b(f1.z); ra[7]=(short)f2b(f1.w);
            }
        } else {
            #pragma unroll
            for (int j = 0; j < 8; ++j) ra[j] = 0;
        }
    };
    auto loadB = [&](int kk) {
        if (TRANSB) {
            int gn = n0 + srow;
            if (gn < N) {
                long long base = Boff + (long long)gn * ldb + kk + skb;
                *reinterpret_cast<uint4*>(rb) =
                    *reinterpret_cast<const uint4*>(B + base);
            } else {
                #pragma unroll
                for (int j = 0; j < 8; ++j) rb[j] = 0;
            }
        } else {
            int gn = n0 + srow;
            if (gn < N) {
                #pragma unroll
                for (int j = 0; j < 8; ++j) {
                    long long bi = Boff + (long long)(kk + skb + j) * ldb + gn;
                    rb[j] = (short)B[bi];
                }
            } else {
                #pragma unroll
                for (int j = 0; j < 8; ++j) rb[j] = 0;
            }
        }
    };

    f32x4 acc[4][2] = {};

    loadA(0); loadB(0);
    for (int k0 = 0; k0 < K; k0 += 32) {
        *reinterpret_cast<uint4*>(&As[srow][skb]) = *reinterpret_cast<uint4*>(ra);
        *reinterpret_cast<uint4*>(&Bs[srow][skb]) = *reinterpret_cast<uint4*>(rb);
        __syncthreads();
        if (k0 + 32 < K) { loadA(k0 + 32); loadB(k0 + 32); }

        bf16x8 a[4], bq[2];
        #pragma unroll
        for (int m = 0; m < 4; ++m)
            a[m] = *reinterpret_cast<const bf16x8*>(&As[wr * 64 + m * 16 + fr][kg * 8]);
        #pragma unroll
        for (int n = 0; n < 2; ++n)
            bq[n] = *reinterpret_cast<const bf16x8*>(&Bs[wc * 32 + n * 16 + fr][kg * 8]);
        #pragma unroll
        for (int m = 0; m < 4; ++m)
            #pragma unroll
            for (int n = 0; n < 2; ++n)
                acc[m][n] = __builtin_amdgcn_mfma_f32_16x16x32_bf16(a[m], bq[n], acc[m][n], 0, 0, 0);
        __syncthreads();
    }

    #pragma unroll
    for (int m = 0; m < 4; ++m) {
        #pragma unroll
        for (int n = 0; n < 2; ++n) {
            #pragma unroll
            for (int i = 0; i < 4; ++i) {
                int gm = m0 + wr * 64 + m * 16 + kg * 4 + i;
                int gn = n0 + wc * 32 + n * 16 + fr;
                if (gm >= M || gn >= N) continue;
                float v = acc[m][n][i] * alpha;
                if (bias) v += bias[biasoff + gn];
                if (act == 1) v = quick_gelu(v);
                if (RES) v += Res[Roff + (long long)gm * ldres + gn];
                long long ci = Coff + (long long)gm * ldc + gn;
                if (OTY) ((float*)Cv)[ci] = v;
                else     ((bf16*)Cv)[ci] = f2b(v);
            }
        }
    }
}

// ---------------------------------------------------------------------------
// Fused softmax + attn_weight accumulate, 3 heads per block (fast reductions)
// ---------------------------------------------------------------------------
__global__ __launch_bounds__(256)
void softmax_aw3_kernel(bf16* __restrict__ T1, float* __restrict__ out, int first)
{
    __shared__ float red4[4];
    __shared__ float srow[SEQ];
    __shared__ float awsh[SEQ];
    long long r = blockIdx.x;
    float* aw = out + (long long)NROWS * CDIM + r * SEQ;
    int tid = threadIdx.x;
    const long long HSTRIDE = (long long)BATCH * SEQ * LDT;
    const float hscale = 1.f / (float)NHEAD;

    for (int k = tid; k < SEQ; k += 256) awsh[k] = 0.f;
    __syncthreads();

    for (int j = 0; j < HG; ++j) {
        bf16* sr = T1 + j * HSTRIDE + r * LDT;
        float lmax = -FLT_MAX;
        for (int k = tid; k < SEQ; k += 256) {
            float v = b2f(sr[k]);
            srow[k] = v;
            lmax = fmaxf(lmax, v);
        }
        __syncthreads();
        float m = brm_fast(lmax, red4, 4);

        float ls = 0.f;
        for (int k = tid; k < SEQ; k += 256) {
            float p = expf(srow[k] - m);
            srow[k] = p; ls += p;
        }
        float Z = brs_fast(ls, red4, 4);
        float inv = 1.f / fmaxf(Z, 1e-30f);
        for (int k = tid; k < SEQ; k += 256) {
            float p = srow[k] * inv;
            sr[k] = f2b(p);
            awsh[k] += p * hscale;
        }
        __syncthreads();
    }
    for (int k = tid; k < SEQ; k += 256)
        aw[k] = (first ? 0.f : aw[k]) + awsh[k];
}

// ---------------------------------------------------------------------------
// Row softmax (view attention), bf16 rows, fast reductions
// ---------------------------------------------------------------------------
__global__ __launch_bounds__(256)
void softmax_rows_bf16(bf16* __restrict__ s)
{
    __shared__ float red4[4];
    __shared__ float srow[GTOK];
    long long row = blockIdx.x;
    bf16* sr = s + row * GTOK;
    int tid = threadIdx.x;
    float lmax = -FLT_MAX;
    #pragma unroll
    for (int i = 0; i < 4; ++i) {
        float v = b2f(sr[tid + i * 256]);
        srow[tid + i * 256] = v;
        lmax = fmaxf(lmax, v);
    }
    __syncthreads();
    float m = brm_fast(lmax, red4, 4);
    float ls = 0.f;
    #pragma unroll
    for (int i = 0; i < 4; ++i) {
        float p = expf(srow[tid + i * 256] - m);
        srow[tid + i * 256] = p; ls += p;
    }
    float Z = brs_fast(ls, red4, 4);
    float inv = 1.f / fmaxf(Z, 1e-30f);
    #pragma unroll
    for (int i = 0; i < 4; ++i) sr[tid + i * 256] = f2b(srow[tid + i * 256] * inv);
}

// ---------------------------------------------------------------------------
// Fused adapter + final residual (coalesced w_down)
// ---------------------------------------------------------------------------
__global__ __launch_bounds__(256)
void adp_final_kernel(const bf16* __restrict__ ffn, const float* __restrict__ w_down,
                      const float* __restrict__ b_down, const float* __restrict__ w_up,
                      const float* __restrict__ b_up, const float* __restrict__ x2,
                      float* __restrict__ out)
{
    __shared__ float rowsh[CDIM];
    __shared__ float red[256];
    __shared__ float a[16];
    long long row = blockIdx.x;
    int tid = threadIdx.x;
    for (int c = tid; c < CDIM; c += 256) rowsh[c] = b2f(ffn[row * CDIM + c]);
    __syncthreads();
    int n = tid & 15;
    int part = tid >> 4;
    float s = 0.f;
    for (int i = part; i < CDIM; i += 16) s += rowsh[i] * w_down[i * 16 + n];
    red[tid] = s; __syncthreads();
    if (tid < 16) {
        float t = 0.f;
        #pragma unroll
        for (int p = 0; p < 16; ++p) t += red[p * 16 + tid];
        a[tid] = gelu_exact(t + b_down[tid]);
    }
    __syncthreads();

    #pragma unroll
    for (int i = 0; i < 3; ++i) {
        int c = tid + i * 256;
        float acc = b_up[c];
        #pragma unroll
        for (int k = 0; k < 16; ++k) acc += a[k] * w_up[k * CDIM + c];
        out[row * CDIM + c] = x2[row * CDIM + c] + rowsh[c] + 0.5f * acc;
    }
}

// ---------------------------------------------------------------------------
// Deterministic segment max+mean, compacted
// ---------------------------------------------------------------------------
__global__ __launch_bounds__(256)
void seg_kernel(const float* __restrict__ feat, const int* __restrict__ idx,
                float* __restrict__ y, int remap)
{
    __shared__ int sidx[NFEAT];
    __shared__ int list[SEGCAP];
    __shared__ int offs[256];
    int seg = blockIdx.x;
    int tid = threadIdx.x;
    for (int j = tid; j < NFEAT; j += 256) sidx[j] = idx[j];
    __syncthreads();

    int base = tid * 32;
    int cnt = 0;
    #pragma unroll
    for (int i = 0; i < 32; ++i) cnt += (sidx[base + i] == seg) ? 1 : 0;
    offs[tid] = cnt;
    __syncthreads();
    for (int st = 1; st < 256; st <<= 1) {
        int v = (tid >= st) ? offs[tid - st] : 0;
        __syncthreads();
        offs[tid] += v;
        __syncthreads();
    }
    int total = offs[255];
    int pos = offs[tid] - cnt;
    __syncthreads();

    float mx0 = -FLT_MAX, mx1 = -FLT_MAX, mx2 = -FLT_MAX;
    float s0 = 0.f, s1 = 0.f, s2 = 0.f;

    if (total <= SEGCAP) {
        #pragma unroll
        for (int i = 0; i < 32; ++i) {
            int j = base + i;
            if (sidx[j] == seg) list[pos++] = j;
        }
        __syncthreads();
        for (int i = 0; i < total; ++i) {
            const float* fr = feat + rmap(list[i], remap) * CDIM;
            float v0 = fr[tid], v1 = fr[tid + 256], v2 = fr[tid + 512];
            s0 += v0; s1 += v1; s2 += v2;
            mx0 = fmaxf(mx0, v0); mx1 = fmaxf(mx1, v1); mx2 = fmaxf(mx2, v2);
        }
    } else {
        for (int j = 0; j < NFEAT; ++j) {
            if (sidx[j] == seg) {
                const float* fr = feat + rmap(j, remap) * CDIM;
                float v0 = fr[tid], v1 = fr[tid + 256], v2 = fr[tid + 512];
                s0 += v0; s1 += v1; s2 += v2;
                mx0 = fmaxf(mx0, v0); mx1 = fmaxf(mx1, v1); mx2 = fmaxf(mx2, v2);
            }
        }
    }

    if (total == 0) { mx0 = mx1 = mx2 = 0.f; }
    float inv = 1.f / (float)(total > 0 ? total : 1);
    float* yr = y + (long long)seg * CDIM;
    yr[tid]       = mx0 + s0 * inv;
    yr[tid + 256] = mx1 + s1 * inv;
    yr[tid + 512] = mx2 + s2 * inv;
}

// ---------------------------------------------------------------------------
// BatchNorm over rows (two-pass, fast reductions) + exact GELU -> bf16
// ---------------------------------------------------------------------------
__global__ __launch_bounds__(128)
void bn_gelu_kernel(const float* __restrict__ y, const float* __restrict__ g,
                    const float* __restrict__ b, long long goff,
                    bf16* __restrict__ out, int R)
{
    __shared__ float red4[4];
    int c = blockIdx.x;
    int tid = threadIdx.x;
    float s = 0.f;
    for (int r = tid; r < R; r += 128) s += y[(long long)r * CDIM + c];
    float mean = brs_fast(s, red4, 2) / (float)R;
    float ss = 0.f;
    for (int r = tid; r < R; r += 128) {
        float d = y[(long long)r * CDIM + c] - mean;
        ss += d * d;
    }
    float var = fmaxf(brs_fast(ss, red4, 2) / (float)R, 0.f);
    float rstd = rsqrtf(var + 1e-5f);
    float gc = g[goff + c], bc = b[goff + c];
    for (int r = tid; r < R; r += 128) {
        float v = (y[(long long)r * CDIM + c] - mean) * rstd * gc + bc;
        out[(long long)r * CDIM + c] = f2b(gelu_exact(v));
    }
}

// ---------------------------------------------------------------------------
// Final fusion: LDS-cached p rows, fast reductions, RMW d_out rows
// ---------------------------------------------------------------------------
__global__ __launch_bounds__(256)
void fuse_final_kernel(const bf16* __restrict__ bn3d, const bf16* __restrict__ bn1d,
                       const int* __restrict__ cluster, const int* __restrict__ fgi,
                       float* __restrict__ out)
{
    __shared__ float red4[4];
    __shared__ float x3s[CDIM];
    __shared__ bf16 pc[NVIEW][CDIM];
    __shared__ float simsh[NVIEW];
    int j = blockIdx.x;
    int tid = threadIdx.x;
    int b = j >> 10, g = j & 1023;
    const bf16* x3 = bn3d + (long long)cluster[j] * CDIM;
    float s = 0.f;
    for (int c = tid; c < CDIM; c += 256) {
        float v = b2f(x3[c]);
        x3s[c] = v;
        s += v * v;
    }
    __syncthreads();
    float nx3 = fmaxf(sqrtf(brs_fast(s, red4, 4)), 1e-8f);

    for (int i = 0; i < NVIEW; ++i) {
        const bf16* p = bn1d + ((long long)i * NGRID + fgi[i * NFEAT + j]) * CDIM;
        float d = 0.f, nn = 0.f;
        for (int c = tid; c < CDIM; c += 256) {
            bf16 u = p[c];
            pc[i][c] = u;
            float pv = b2f(u);
            d += pv * x3s[c]; nn += pv * pv;
        }
        float D = brs_fast(d, red4, 4);
        float Np = sqrtf(brs_fast(nn, red4, 4));
        if (tid == 0) {
            float cosv = D / (fmaxf(Np, 1e-8f) * nx3);
            simsh[i] = (cosv + 1.f) * 0.5f;
        }
    }
    __syncthreads();
    float ssum = 0.f;
    #pragma unroll
    for (int i = 0; i < NVIEW; ++i) ssum += simsh[i];
    float invs = 1.f / fmaxf(ssum, 1e-20f);
    long long orow = ((long long)b * SEQ + 1 + g) * CDIM;
    for (int c = tid; c < CDIM; c += 256) {
        float acc = 0.f;
        #pragma unroll
        for (int i = 0; i < NVIEW; ++i) acc += simsh[i] * invs * b2f(pc[i][c]);
        out[orow + c] = out[orow + c] + 0.3f * acc;
    }
}

// ---------------------------------------------------------------------------
// Host side
// ---------------------------------------------------------------------------
extern "C" void kernel_launch(void* const* d_in, const int* in_sizes, int n_in,
                              void* d_out, int out_size, void* d_ws, size_t ws_size,
                              hipStream_t stream)
{
    const float* x      = (const float*)d_in[0];
    const int*  cluster = (const int*)d_in[2];
    const int*  fgi     = (const int*)d_in[3];
    const float* ln1_g = (const float*)d_in[6];
    const float* ln1_b = (const float*)d_in[7];
    const float* w_qkv = (const float*)d_in[8];
    const float* b_qkv = (const float*)d_in[9];
    const float* w_o   = (const float*)d_in[10];
    const float* b_o   = (const float*)d_in[11];
    const float* ln2_g = (const float*)d_in[12];
    const float* ln2_b = (const float*)d_in[13];
    const float* w_fc  = (const float*)d_in[14];
    const float* b_fc  = (const float*)d_in[15];
    const float* w_proj= (const float*)d_in[16];
    const float* b_proj= (const float*)d_in[17];
    const float* w_down= (const float*)d_in[18];
    const float* b_down= (const float*)d_in[19];
    const float* w_up  = (const float*)d_in[20];
    const float* b_up  = (const float*)d_in[21];
    const float* bn3d_g= (const float*)d_in[22];
    const float* bn3d_b= (const float*)d_in[23];
    const float* n3_g  = (const float*)d_in[24];
    const float* n3_b  = (const float*)d_in[25];
    const float* vw_qkv= (const float*)d_in[26];
    const float* vb_qkv= (const float*)d_in[27];
    const float* vw_o  = (const float*)d_in[28];
    const float* vb_o  = (const float*)d_in[29];
    const float* bn1d_g= (const float*)d_in[30];
    const float* bn1d_b= (const float*)d_in[31];
    (void)in_sizes; (void)n_in; (void)out_size; (void)ws_size;

    float* out = (float*)d_out;

    // workspace layout (bytes), total ~205 MB (< proven-safe 209)
    char* w = (char*)d_ws;
    bf16*  QKV    = (bf16*)w;  w += (long long)NROWS * 3 * CDIM * 2;
    bf16*  H      = (bf16*)w;  w += (long long)NROWS * CDIM * 2;
    float* X2     = (float*)w; w += (long long)NROWS * CDIM * 4;
    bf16*  AO     = (bf16*)w;  w += (long long)NROWS * CDIM * 2;
    bf16*  FFN    = (bf16*)w;  w += (long long)NROWS * CDIM * 2;
    float* T1     = (float*)w; w += (long long)HG * BATCH * SEQ * LDT * 2;
    float* Y512   = (float*)w; w += (long long)NCLUST * CDIM * 4;
    bf16*  BN3D   = (bf16*)w;  w += (long long)NCLUST * CDIM * 2;
    float* YG     = (float*)w; w += (long long)NGRID * CDIM * 4;
    bf16*  BN1D   = (bf16*)w;  w += (long long)NVIEW * NGRID * CDIM * 2;
    bf16*  WQKVT  = (bf16*)w;  w += (long long)(3*CDIM) * CDIM * 2;
    bf16*  WOT    = (bf16*)w;  w += (long long)CDIM * CDIM * 2;
    bf16*  WFCT   = (bf16*)w;  w += (long long)(4*CDIM) * CDIM * 2;
    bf16*  WPROJT = (bf16*)w;  w += (long long)CDIM * (4*CDIM) * 2;
    bf16*  VWQKVT = (bf16*)w;  w += (long long)(3*CDIM) * CDIM * 2;
    bf16*  VWOT   = (bf16*)w;  w += (long long)CDIM * CDIM * 2;
    bf16*  VT     = (bf16*)w;  w += (long long)BATCH * CDIM * LDT * 2;   // 12.7 MB (V^T)
    bf16*  T1b    = (bf16*)T1;

    dim3 blk(256), blk512(512);

    // ---- weight transposes (f32 -> bf16, N x K) ----
    transpose_kernel<<<dim3(72, 24), blk, 0, stream>>>(w_qkv, WQKVT, CDIM, 3*CDIM);
    transpose_kernel<<<dim3(24, 24), blk, 0, stream>>>(w_o, WOT, CDIM, CDIM);
    transpose_kernel<<<dim3(96, 24), blk, 0, stream>>>(w_fc, WFCT, CDIM, 4*CDIM);
    transpose_kernel<<<dim3(24, 96), blk, 0, stream>>>(w_proj, WPROJT, 4*CDIM, CDIM);

    // ---- stage A: transformer block ----
    ln_kernel<<<NROWS, blk, 0, stream>>>(x, ln1_g, ln1_b, 0LL, H, 0);

    gemm2<1,0,0,0><<<dim3(18, 65, 1), blk512, 0, stream>>>(
        H, WQKVT, b_qkv, nullptr, QKV,
        NROWS, 3*CDIM, CDIM, CDIM, CDIM, 3*CDIM, 0, 1.f, 0, 0LL, 0LL,
        1, 0, 0, 0, 0, 0, 0, 0);

    // V^T for main attention: per b, VT[b][c][k] (ld = LDT)
    transpose_bf16_kernel<<<dim3(24, 33, BATCH), blk, 0, stream>>>(
        QKV + 2*CDIM, VT, SEQ, CDIM, 3*CDIM, LDT,
        (long long)SEQ * 3*CDIM, (long long)CDIM * LDT);

    // ---- main attention: 4 groups of 3 heads ----
    const long long HSTR = (long long)BATCH * SEQ * LDT;
    for (int g = 0; g < NHEAD / HG; ++g) {
        int hb = g * HG;
        gemm2<1,0,0,0><<<dim3(9, 9, BATCH * HG), blk512, 0, stream>>>(
            QKV + hb * DHEAD, QKV + CDIM + hb * DHEAD, nullptr, nullptr, T1b,
            SEQ, SEQ, DHEAD, 3*CDIM, 3*CDIM, LDT, 0, 0.125f, 0, 0LL, 0LL,
            BATCH, (long long)SEQ * 3*CDIM, DHEAD,
            (long long)SEQ * 3*CDIM, DHEAD,
            (long long)SEQ * LDT, HSTR, 0);

        softmax_aw3_kernel<<<NROWS, blk, 0, stream>>>(T1b, out, g == 0 ? 1 : 0);

        // AV with transposed V (coalesced TRANSB path)
        gemm_k<1,0,0,0><<<dim3(1, 17, BATCH * HG), blk, 0, stream>>>(
            T1b, VT + (long long)hb * DHEAD * LDT, nullptr, nullptr, AO + hb * DHEAD,
            SEQ, DHEAD, SEQ, LDT, LDT, CDIM, 0, 1.f, 0, 0LL, 0LL,
            BATCH, (long long)SEQ * LDT, HSTR,
            (long long)CDIM * LDT, (long long)DHEAD * LDT,
            (long long)SEQ * CDIM, DHEAD, 0);
    }

    // x2 = AO @ w_o + b_o + x   -> f32
    gemm2<1,0,1,1><<<dim3(6, 65, 1), blk512, 0, stream>>>(
        AO, WOT, b_o, x, X2,
        NROWS, CDIM, CDIM, CDIM, CDIM, CDIM, CDIM, 1.f, 0, 0LL, 0LL,
        1, 0, 0, 0, 0, 0, 0, 0);

    ln_kernel<<<NROWS, blk, 0, stream>>>(X2, ln2_g, ln2_b, 0LL, H, 0);

    // FC + proj in 2 row-chunks of 4100; bf16 MID shares T1 region
    {
        bf16* MID = (bf16*)T1;
        for (int cidx = 0; cidx < 2; ++cidx) {
            long long r0 = 4100LL * cidx;
            int m = 4100;
            gemm2<1,0,0,0><<<dim3(24, 33, 1), blk512, 0, stream>>>(
                H + r0 * CDIM, WFCT, b_fc, nullptr, MID,
                m, 4*CDIM, CDIM, CDIM, CDIM, 4*CDIM, 0, 1.f, 1, 0LL, 0LL,
                1, 0, 0, 0, 0, 0, 0, 0);
            gemm2<1,0,0,0><<<dim3(6, 33, 1), blk512, 0, stream>>>(
                MID, WPROJT, b_proj, nullptr, FFN + r0 * CDIM,
                m, CDIM, 4*CDIM, 4*CDIM, 4*CDIM, CDIM, 0, 1.f, 0, 0LL, 0LL,
                1, 0, 0, 0, 0, 0, 0, 0);
        }
    }

    adp_final_kernel<<<NROWS, blk, 0, stream>>>(FFN, w_down, b_down, w_up, b_up,
                                                X2, out);

    // ---- stage B: cluster pooling + BN-GELU ----
    seg_kernel<<<NCLUST, blk, 0, stream>>>(out, cluster, Y512, 1);
    bn_gelu_kernel<<<CDIM, dim3(128), 0, stream>>>(Y512, bn3d_g, bn3d_b, 0LL, BN3D, NCLUST);

    // ---- stage C: 6 views ----
    const float inv_sqrt_c = 0.03608439182435161f; // 1/sqrt(768)
    for (int i = 0; i < NVIEW; ++i) {
        transpose_kernel<<<dim3(72, 24), blk, 0, stream>>>(
            vw_qkv + (long long)i * CDIM * 3*CDIM, VWQKVT, CDIM, 3*CDIM);
        transpose_kernel<<<dim3(24, 24), blk, 0, stream>>>(
            vw_o + (long long)i * CDIM * CDIM, VWOT, CDIM, CDIM);

        ln_kernel<<<NFEAT, blk, 0, stream>>>(out, n3_g, n3_b, (long long)i * CDIM, H, 1);

        gemm2<1,0,0,0><<<dim3(18, 64, 1), blk512, 0, stream>>>(
            H, VWQKVT, vb_qkv, nullptr, QKV,
            NFEAT, 3*CDIM, CDIM, CDIM, CDIM, 3*CDIM, 0, 1.f, 0,
            0LL, (long long)i * 3*CDIM, 1, 0, 0, 0, 0, 0, 0, 0);

        // V^T for this view: VT[b][c][k], ld = GTOK
        transpose_bf16_kernel<<<dim3(24, 32, BATCH), blk, 0, stream>>>(
            QKV + 2*CDIM, VT, GTOK, CDIM, 3*CDIM, GTOK,
            (long long)GTOK * 3*CDIM, (long long)CDIM * GTOK);

        // scores -> bf16, ld = GTOK
        gemm2<1,0,0,0><<<dim3(8, 8, BATCH), blk512, 0, stream>>>(
            QKV, QKV + CDIM, nullptr, nullptr, T1b,
            GTOK, GTOK, CDIM, 3*CDIM, 3*CDIM, GTOK, 0, inv_sqrt_c, 0, 0LL, 0LL,
            BATCH, (long long)GTOK * 3*CDIM, 0,
            (long long)GTOK * 3*CDIM, 0,
            (long long)GTOK * GTOK, 0, 0);

        softmax_rows_bf16<<<BATCH * GTOK, blk, 0, stream>>>(T1b);

        // o1 = P(bf16) @ V via V^T (coalesced TRANSB path)
        gemm2<1,0,0,0><<<dim3(6, 8, BATCH), blk512, 0, stream>>>(
            T1b, VT, nullptr, nullptr, AO,
            GTOK, CDIM, GTOK, GTOK, GTOK, CDIM, 0, 1.f, 0, 0LL, 0LL,
            BATCH, (long long)GTOK * GTOK, 0,
            (long long)CDIM * GTOK, 0,
            (long long)GTOK * CDIM, 0, 0);

        // fx = o1 @ vw_o + vb_o + feat(out rows) -> X2, batched over b
        gemm2<1,0,1,1><<<dim3(6, 8, BATCH), blk512, 0, stream>>>(
            AO, VWOT, vb_o, out + CDIM, X2,
            GTOK, CDIM, CDIM, CDIM, CDIM, CDIM, CDIM, 1.f, 0,
            0LL, (long long)i * CDIM,
            BATCH, (long long)GTOK * CDIM, 0, 0, 0,
            (long long)GTOK * CDIM, 0, (long long)SEQ * CDIM);

        seg_kernel<<<NGRID, blk, 0, stream>>>(X2, fgi + i * NFEAT, YG, 0);
        bn_gelu_kernel<<<CDIM, dim3(128), 0, stream>>>(
            YG, bn1d_g, bn1d_b, (long long)i * CDIM,
            BN1D + (long long)i * NGRID * CDIM, NGRID);
    }

    // ---- final fusion (RMW d_out token rows) ----
    fuse_final_kernel<<<NFEAT, blk, 0, stream>>>(BN3D, BN1D, cluster, fgi, out);
}

// Round 19
// 2438.699 us; speedup vs baseline: 2.0519x; 1.0481x over previous
//
#include <hip/hip_runtime.h>
#include <math.h>
#include <float.h>

#define BATCH   8
#define SEQ     1025
#define GTOK    1024
#define CDIM    768
#define NHEAD   12
#define DHEAD   64
#define NVIEW   6
#define NCLUST  512
#define NGRID   1568
#define NROWS   8200
#define NFEAT   8192
#define SEGCAP  2048
#define LDT     1032
#define HG      3
#define BNCH    16

typedef unsigned short bf16;
typedef __attribute__((ext_vector_type(8))) short bf16x8;
typedef __attribute__((ext_vector_type(4))) float f32x4;

__device__ __forceinline__ float b2f(bf16 u) {
    union { unsigned int i; float f; } v; v.i = ((unsigned int)u) << 16; return v.f;
}
__device__ __forceinline__ bf16 f2b(float f) {
    union { float f; unsigned int i; } v; v.f = f;
    unsigned int x = v.i;
    return (bf16)((x + 0x7fffu + ((x >> 16) & 1u)) >> 16);
}

__device__ __forceinline__ float block_reduce_sum(float v, float* red) {
    int tid = threadIdx.x;
    red[tid] = v; __syncthreads();
    for (int s = blockDim.x >> 1; s > 0; s >>= 1) {
        if (tid < s) red[tid] += red[tid + s];
        __syncthreads();
    }
    float r = red[0]; __syncthreads();
    return r;
}

__device__ __forceinline__ float brs_fast(float v, float* red4, int nw) {
    #pragma unroll
    for (int o = 32; o > 0; o >>= 1) v += __shfl_down(v, o);
    int lane = threadIdx.x & 63, wid = threadIdx.x >> 6;
    if (lane == 0) red4[wid] = v;
    __syncthreads();
    float r = 0.f;
    for (int i = 0; i < nw; ++i) r += red4[i];
    __syncthreads();
    return r;
}
__device__ __forceinline__ float brm_fast(float v, float* red4, int nw) {
    #pragma unroll
    for (int o = 32; o > 0; o >>= 1) v = fmaxf(v, __shfl_down(v, o));
    int lane = threadIdx.x & 63, wid = threadIdx.x >> 6;
    if (lane == 0) red4[wid] = v;
    __syncthreads();
    float r = -FLT_MAX;
    for (int i = 0; i < nw; ++i) r = fmaxf(r, red4[i]);
    __syncthreads();
    return r;
}

__device__ __forceinline__ float gelu_exact(float v) {
    return 0.5f * v * (1.f + erff(v * 0.70710678118654752f));
}
__device__ __forceinline__ float quick_gelu(float v) {
    return v / (1.f + expf(-1.702f * v));
}

__device__ __forceinline__ long long rmap(long long j, int remap) {
    return remap ? (j + 1 + (j >> 10)) : j;
}

// ---------------------------------------------------------------------------
// Tiled transpose: W (K x N, f32) -> WT (N x K, bf16)
// ---------------------------------------------------------------------------
__global__ __launch_bounds__(256)
void transpose_kernel(const float* __restrict__ W, bf16* __restrict__ WT, int K, int N)
{
    __shared__ float t[32][33];
    int n0 = blockIdx.x * 32, k0 = blockIdx.y * 32;
    int tx = threadIdx.x & 31, ty = threadIdx.x >> 5;
    #pragma unroll
    for (int i = 0; i < 4; ++i) {
        int k = k0 + ty + i * 8, n = n0 + tx;
        t[ty + i * 8][tx] = (k < K && n < N) ? W[(long long)k * N + n] : 0.f;
    }
    __syncthreads();
    #pragma unroll
    for (int i = 0; i < 4; ++i) {
        int n = n0 + ty + i * 8, k = k0 + tx;
        if (n < N && k < K)
            WT[(long long)n * K + k] = f2b(t[tx][ty + i * 8]);
    }
}

// ---------------------------------------------------------------------------
// Batched bf16 transpose
// ---------------------------------------------------------------------------
__global__ __launch_bounds__(256)
void transpose_bf16_kernel(const bf16* __restrict__ src, bf16* __restrict__ dst,
                           int K, int N, int lds, int ldd,
                           long long sSrc, long long sDst)
{
    __shared__ bf16 t[32][34];
    int z = blockIdx.z;
    const bf16* S = src + (long long)z * sSrc;
    bf16* D = dst + (long long)z * sDst;
    int n0 = blockIdx.x * 32, k0 = blockIdx.y * 32;
    int tx = threadIdx.x & 31, ty = threadIdx.x >> 5;
    #pragma unroll
    for (int i = 0; i < 4; ++i) {
        int k = k0 + ty + i * 8, n = n0 + tx;
        t[ty + i * 8][tx] = (k < K && n < N) ? S[(long long)k * lds + n] : (bf16)0;
    }
    __syncthreads();
    #pragma unroll
    for (int i = 0; i < 4; ++i) {
        int n = n0 + ty + i * 8, k = k0 + tx;
        if (n < N && k < K)
            D[(long long)n * ldd + k] = t[tx][ty + i * 8];
    }
}

// ---------------------------------------------------------------------------
// LayerNorm (fast reductions)
// ---------------------------------------------------------------------------
__global__ __launch_bounds__(256)
void ln_kernel(const float* __restrict__ x, const float* __restrict__ g,
               const float* __restrict__ b, long long goff, bf16* __restrict__ out,
               int remap)
{
    __shared__ float red4[4];
    long long row = blockIdx.x;
    int tid = threadIdx.x;
    long long ibase = rmap(row, remap) * CDIM;
    long long obase = row * CDIM;
    float v0 = x[ibase + tid], v1 = x[ibase + tid + 256], v2 = x[ibase + tid + 512];
    float mean = brs_fast(v0 + v1 + v2, red4, 4) * (1.f / CDIM);
    float d0 = v0 - mean, d1 = v1 - mean, d2 = v2 - mean;
    float var = brs_fast(d0 * d0 + d1 * d1 + d2 * d2, red4, 4) * (1.f / CDIM);
    float rstd = rsqrtf(var + 1e-5f);
    bf16* orow = out + obase;
    orow[tid]       = f2b(d0 * rstd * g[goff + tid]       + b[goff + tid]);
    orow[tid + 256] = f2b(d1 * rstd * g[goff + tid + 256] + b[goff + tid + 256]);
    orow[tid + 512] = f2b(d2 * rstd * g[goff + tid + 512] + b[goff + tid + 512]);
}

// ---------------------------------------------------------------------------
// norm only: (x - mean) * rstd -> bf16 (shared across views)
// ---------------------------------------------------------------------------
__global__ __launch_bounds__(256)
void norm_kernel(const float* __restrict__ x, bf16* __restrict__ out)
{
    __shared__ float red4[4];
    long long row = blockIdx.x;
    int tid = threadIdx.x;
    long long ibase = rmap(row, 1) * CDIM;
    long long obase = row * CDIM;
    float v0 = x[ibase + tid], v1 = x[ibase + tid + 256], v2 = x[ibase + tid + 512];
    float mean = brs_fast(v0 + v1 + v2, red4, 4) * (1.f / CDIM);
    float d0 = v0 - mean, d1 = v1 - mean, d2 = v2 - mean;
    float var = brs_fast(d0 * d0 + d1 * d1 + d2 * d2, red4, 4) * (1.f / CDIM);
    float rstd = rsqrtf(var + 1e-5f);
    bf16* orow = out + obase;
    orow[tid]       = f2b(d0 * rstd);
    orow[tid + 256] = f2b(d1 * rstd);
    orow[tid + 512] = f2b(d2 * rstd);
}

// ---------------------------------------------------------------------------
// gemm_k: 64x64-tile MFMA GEMM. Dual batch strides.
// ---------------------------------------------------------------------------
#define LDSK 40

template<int TRANSB, int ATY, int OTY, int RES>
__global__ __launch_bounds__(256)
void gemm_k(const void* __restrict__ Av, const bf16* __restrict__ B,
            const float* __restrict__ bias, const float* __restrict__ Res,
            void* __restrict__ Cv,
            int M, int N, int K, int lda, int ldb, int ldc, int ldres,
            float alpha, int act, long long boff, long long biasoff, int zdiv,
            long long sA1, long long sA2, long long sB1, long long sB2,
            long long sC1, long long sC2, long long sRes)
{
    __shared__ short As[64][LDSK];
    __shared__ short Bs[64][LDSK];
    int bz = blockIdx.z;
    int bz1 = bz % zdiv, bz2 = bz / zdiv;
    int tid = threadIdx.x;
    int m0 = blockIdx.y * 64, n0 = blockIdx.x * 64;
    long long Aoff = bz1 * sA1 + bz2 * sA2;
    long long Boff = boff + bz1 * sB1 + bz2 * sB2;
    long long Coff = bz1 * sC1 + bz2 * sC2;
    long long Roff = bz1 * sRes;

    int lane = tid & 63;
    int w = tid >> 6;
    int wr = w >> 1, wc = w & 1;
    int fr = lane & 15;
    int kg = lane >> 4;

    f32x4 acc[2][2] = {};

    for (int k0 = 0; k0 < K; k0 += 32) {
        {
            int r = tid >> 2, kb = (tid & 3) * 8;
            int gm = m0 + r;
            short tmp[8] = {};
            if (gm < M) {
                long long base = Aoff + (long long)gm * lda + k0 + kb;
                if (k0 + kb + 8 <= K) {
                    if (ATY == 0) {
                        *reinterpret_cast<uint4*>(tmp) =
                            *reinterpret_cast<const uint4*>((const bf16*)Av + base);
                    } else {
                        float4 f0 = *reinterpret_cast<const float4*>((const float*)Av + base);
                        float4 f1 = *reinterpret_cast<const float4*>((const float*)Av + base + 4);
                        tmp[0]=(short)f2b(f0.x); tmp[1]=(short)f2b(f0.y);
                        tmp[2]=(short)f2b(f0.z); tmp[3]=(short)f2b(f0.w);
                        tmp[4]=(short)f2b(f1.x); tmp[5]=(short)f2b(f1.y);
                        tmp[6]=(short)f2b(f1.z); tmp[7]=(short)f2b(f1.w);
                    }
                } else {
                    #pragma unroll
                    for (int j = 0; j < 8; ++j) {
                        if (k0 + kb + j < K)
                            tmp[j] = ATY ? (short)f2b(((const float*)Av)[base + j])
                                         : (short)((const bf16*)Av)[base + j];
                    }
                }
            }
            *reinterpret_cast<uint4*>(&As[r][kb]) = *reinterpret_cast<uint4*>(tmp);
        }
        {
            int col = tid >> 2, kb = (tid & 3) * 8;
            int gn = n0 + col;
            short tmp[8] = {};
            if (gn < N) {
                if (TRANSB) {
                    long long base = Boff + (long long)gn * ldb + k0 + kb;
                    if (k0 + kb + 8 <= K) {
                        *reinterpret_cast<uint4*>(tmp) =
                            *reinterpret_cast<const uint4*>(B + base);
                    } else {
                        #pragma unroll
                        for (int j = 0; j < 8; ++j)
                            if (k0 + kb + j < K) tmp[j] = (short)B[base + j];
                    }
                } else {
                    #pragma unroll
                    for (int j = 0; j < 8; ++j) {
                        int kk = k0 + kb + j;
                        if (kk < K)
                            tmp[j] = (short)B[Boff + (long long)kk * ldb + gn];
                    }
                }
            }
            *reinterpret_cast<uint4*>(&Bs[col][kb]) = *reinterpret_cast<uint4*>(tmp);
        }
        __syncthreads();

        bf16x8 a0 = *reinterpret_cast<const bf16x8*>(&As[wr * 32 + fr][kg * 8]);
        bf16x8 a1 = *reinterpret_cast<const bf16x8*>(&As[wr * 32 + 16 + fr][kg * 8]);
        bf16x8 b0 = *reinterpret_cast<const bf16x8*>(&Bs[wc * 32 + fr][kg * 8]);
        bf16x8 b1 = *reinterpret_cast<const bf16x8*>(&Bs[wc * 32 + 16 + fr][kg * 8]);
        acc[0][0] = __builtin_amdgcn_mfma_f32_16x16x32_bf16(a0, b0, acc[0][0], 0, 0, 0);
        acc[0][1] = __builtin_amdgcn_mfma_f32_16x16x32_bf16(a0, b1, acc[0][1], 0, 0, 0);
        acc[1][0] = __builtin_amdgcn_mfma_f32_16x16x32_bf16(a1, b0, acc[1][0], 0, 0, 0);
        acc[1][1] = __builtin_amdgcn_mfma_f32_16x16x32_bf16(a1, b1, acc[1][1], 0, 0, 0);
        __syncthreads();
    }

    #pragma unroll
    for (int m = 0; m < 2; ++m) {
        #pragma unroll
        for (int n = 0; n < 2; ++n) {
            #pragma unroll
            for (int i = 0; i < 4; ++i) {
                int gm = m0 + wr * 32 + m * 16 + kg * 4 + i;
                int gn = n0 + wc * 32 + n * 16 + fr;
                if (gm >= M || gn >= N) continue;
                float v = acc[m][n][i] * alpha;
                if (bias) v += bias[biasoff + gn];
                if (act == 1) v = quick_gelu(v);
                if (RES) v += Res[Roff + (long long)gm * ldres + gn];
                long long ci = Coff + (long long)gm * ldc + gn;
                if (OTY) ((float*)Cv)[ci] = v;
                else     ((bf16*)Cv)[ci] = f2b(v);
            }
        }
    }
}

// ---------------------------------------------------------------------------
// gemm2: 128x128-tile MFMA GEMM, register-prefetch pipeline.
// ASC=1: A (bf16) scaled per-k: a*gsc[gsoff+k]+gbs[gsoff+k] during staging.
// ---------------------------------------------------------------------------
template<int TRANSB, int ATY, int OTY, int RES, int ASC>
__global__ __launch_bounds__(512)
void gemm2(const void* __restrict__ Av, const bf16* __restrict__ B,
           const float* __restrict__ bias, const float* __restrict__ Res,
           void* __restrict__ Cv,
           int M, int N, int K, int lda, int ldb, int ldc, int ldres,
           float alpha, int act, long long boff, long long biasoff, int zdiv,
           long long sA1, long long sA2, long long sB1, long long sB2,
           long long sC1, long long sC2, long long sRes,
           const float* __restrict__ gsc, const float* __restrict__ gbs,
           long long gsoff)
{
    __shared__ short As[128][LDSK];
    __shared__ short Bs[128][LDSK];
    int bz = blockIdx.z;
    int bz1 = bz % zdiv, bz2 = bz / zdiv;
    int tid = threadIdx.x;
    int m0 = blockIdx.y * 128, n0 = blockIdx.x * 128;
    long long Aoff = bz1 * sA1 + bz2 * sA2;
    long long Boff = boff + bz1 * sB1 + bz2 * sB2;
    long long Coff = bz1 * sC1 + bz2 * sC2;
    long long Roff = bz1 * sRes;

    int lane = tid & 63;
    int w = tid >> 6;
    int wr = w >> 2, wc = w & 3;
    int fr = lane & 15;
    int kg = lane >> 4;

    int srow = tid >> 2;
    int skb  = (tid & 3) * 8;

    short ra[8], rb[8];

    auto loadA = [&](int kk) {
        int gm = m0 + srow;
        if (gm < M) {
            long long base = Aoff + (long long)gm * lda + kk + skb;
            if (ATY == 0) {
                *reinterpret_cast<uint4*>(ra) =
                    *reinterpret_cast<const uint4*>((const bf16*)Av + base);
                if (ASC) {
                    #pragma unroll
                    for (int j = 0; j < 8; ++j) {
                        long long gi = gsoff + kk + skb + j;
                        ra[j] = (short)f2b(b2f((bf16)ra[j]) * gsc[gi] + gbs[gi]);
                    }
                }
            } else {
                float4 f0 = *reinterpret_cast<const float4*>((const float*)Av + base);
                float4 f1 = *reinterpret_cast<const float4*>((const float*)Av + base + 4);
                ra[0]=(short)f2b(f0.x); ra[1]=(short)f2b(f0.y);
                ra[2]=(short)f2b(f0.z); ra[3]=(short)f2b(f0.w);
                ra[4]=(short)f2b(f1.x); ra[5]=(short)f2b(f1.y);
                ra[6]=(short)f2b(f1.z); ra[7]=(short)f2b(f1.w);
            }
        } else {
            #pragma unroll
            for (int j = 0; j < 8; ++j) ra[j] = 0;
        }
    };
    auto loadB = [&](int kk) {
        if (TRANSB) {
            int gn = n0 + srow;
            if (gn < N) {
                long long base = Boff + (long long)gn * ldb + kk + skb;
                *reinterpret_cast<uint4*>(rb) =
                    *reinterpret_cast<const uint4*>(B + base);
            } else {
                #pragma unroll
                for (int j = 0; j < 8; ++j) rb[j] = 0;
            }
        } else {
            int gn = n0 + srow;
            if (gn < N) {
                #pragma unroll
                for (int j = 0; j < 8; ++j) {
                    long long bi = Boff + (long long)(kk + skb + j) * ldb + gn;
                    rb[j] = (short)B[bi];
                }
            } else {
                #pragma unroll
                for (int j = 0; j < 8; ++j) rb[j] = 0;
            }
        }
    };

    f32x4 acc[4][2] = {};

    loadA(0); loadB(0);
    for (int k0 = 0; k0 < K; k0 += 32) {
        *reinterpret_cast<uint4*>(&As[srow][skb]) = *reinterpret_cast<uint4*>(ra);
        *reinterpret_cast<uint4*>(&Bs[srow][skb]) = *reinterpret_cast<uint4*>(rb);
        __syncthreads();
        if (k0 + 32 < K) { loadA(k0 + 32); loadB(k0 + 32); }

        bf16x8 a[4], bq[2];
        #pragma unroll
        for (int m = 0; m < 4; ++m)
            a[m] = *reinterpret_cast<const bf16x8*>(&As[wr * 64 + m * 16 + fr][kg * 8]);
        #pragma unroll
        for (int n = 0; n < 2; ++n)
            bq[n] = *reinterpret_cast<const bf16x8*>(&Bs[wc * 32 + n * 16 + fr][kg * 8]);
        #pragma unroll
        for (int m = 0; m < 4; ++m)
            #pragma unroll
            for (int n = 0; n < 2; ++n)
                acc[m][n] = __builtin_amdgcn_mfma_f32_16x16x32_bf16(a[m], bq[n], acc[m][n], 0, 0, 0);
        __syncthreads();
    }

    #pragma unroll
    for (int m = 0; m < 4; ++m) {
        #pragma unroll
        for (int n = 0; n < 2; ++n) {
            #pragma unroll
            for (int i = 0; i < 4; ++i) {
                int gm = m0 + wr * 64 + m * 16 + kg * 4 + i;
                int gn = n0 + wc * 32 + n * 16 + fr;
                if (gm >= M || gn >= N) continue;
                float v = acc[m][n][i] * alpha;
                if (bias) v += bias[biasoff + gn];
                if (act == 1) v = quick_gelu(v);
                if (RES) v += Res[Roff + (long long)gm * ldres + gn];
                long long ci = Coff + (long long)gm * ldc + gn;
                if (OTY) ((float*)Cv)[ci] = v;
                else     ((bf16*)Cv)[ci] = f2b(v);
            }
        }
    }
}

// ---------------------------------------------------------------------------
// Fused softmax + attn_weight accumulate, 3 heads per block
// ---------------------------------------------------------------------------
__global__ __launch_bounds__(256)
void softmax_aw3_kernel(bf16* __restrict__ T1, float* __restrict__ out, int first)
{
    __shared__ float red4[4];
    __shared__ float srow[SEQ];
    __shared__ float awsh[SEQ];
    long long r = blockIdx.x;
    float* aw = out + (long long)NROWS * CDIM + r * SEQ;
    int tid = threadIdx.x;
    const long long HSTRIDE = (long long)BATCH * SEQ * LDT;
    const float hscale = 1.f / (float)NHEAD;

    for (int k = tid; k < SEQ; k += 256) awsh[k] = 0.f;
    __syncthreads();

    for (int j = 0; j < HG; ++j) {
        bf16* sr = T1 + j * HSTRIDE + r * LDT;
        float lmax = -FLT_MAX;
        for (int k = tid; k < SEQ; k += 256) {
            float v = b2f(sr[k]);
            srow[k] = v;
            lmax = fmaxf(lmax, v);
        }
        __syncthreads();
        float m = brm_fast(lmax, red4, 4);

        float ls = 0.f;
        for (int k = tid; k < SEQ; k += 256) {
            float p = expf(srow[k] - m);
            srow[k] = p; ls += p;
        }
        float Z = brs_fast(ls, red4, 4);
        float inv = 1.f / fmaxf(Z, 1e-30f);
        for (int k = tid; k < SEQ; k += 256) {
            float p = srow[k] * inv;
            sr[k] = f2b(p);
            awsh[k] += p * hscale;
        }
        __syncthreads();
    }
    for (int k = tid; k < SEQ; k += 256)
        aw[k] = (first ? 0.f : aw[k]) + awsh[k];
}

// ---------------------------------------------------------------------------
// Row softmax (view attention), bf16 rows
// ---------------------------------------------------------------------------
__global__ __launch_bounds__(256)
void softmax_rows_bf16(bf16* __restrict__ s)
{
    __shared__ float red4[4];
    __shared__ float srow[GTOK];
    long long row = blockIdx.x;
    bf16* sr = s + row * GTOK;
    int tid = threadIdx.x;
    float lmax = -FLT_MAX;
    #pragma unroll
    for (int i = 0; i < 4; ++i) {
        float v = b2f(sr[tid + i * 256]);
        srow[tid + i * 256] = v;
        lmax = fmaxf(lmax, v);
    }
    __syncthreads();
    float m = brm_fast(lmax, red4, 4);
    float ls = 0.f;
    #pragma unroll
    for (int i = 0; i < 4; ++i) {
        float p = expf(srow[tid + i * 256] - m);
        srow[tid + i * 256] = p; ls += p;
    }
    float Z = brs_fast(ls, red4, 4);
    float inv = 1.f / fmaxf(Z, 1e-30f);
    #pragma unroll
    for (int i = 0; i < 4; ++i) sr[tid + i * 256] = f2b(srow[tid + i * 256] * inv);
}

// ---------------------------------------------------------------------------
// Fused adapter + final residual (coalesced w_down)
// ---------------------------------------------------------------------------
__global__ __launch_bounds__(256)
void adp_final_kernel(const bf16* __restrict__ ffn, const float* __restrict__ w_down,
                      const float* __restrict__ b_down, const float* __restrict__ w_up,
                      const float* __restrict__ b_up, const float* __restrict__ x2,
                      float* __restrict__ out)
{
    __shared__ float rowsh[CDIM];
    __shared__ float red[256];
    __shared__ float a[16];
    long long row = blockIdx.x;
    int tid = threadIdx.x;
    for (int c = tid; c < CDIM; c += 256) rowsh[c] = b2f(ffn[row * CDIM + c]);
    __syncthreads();
    int n = tid & 15;
    int part = tid >> 4;
    float s = 0.f;
    for (int i = part; i < CDIM; i += 16) s += rowsh[i] * w_down[i * 16 + n];
    red[tid] = s; __syncthreads();
    if (tid < 16) {
        float t = 0.f;
        #pragma unroll
        for (int p = 0; p < 16; ++p) t += red[p * 16 + tid];
        a[tid] = gelu_exact(t + b_down[tid]);
    }
    __syncthreads();

    #pragma unroll
    for (int i = 0; i < 3; ++i) {
        int c = tid + i * 256;
        float acc = b_up[c];
        #pragma unroll
        for (int k = 0; k < 16; ++k) acc += a[k] * w_up[k * CDIM + c];
        out[row * CDIM + c] = x2[row * CDIM + c] + rowsh[c] + 0.5f * acc;
    }
}

// ---------------------------------------------------------------------------
// Deterministic segment max+mean, compacted
// ---------------------------------------------------------------------------
__global__ __launch_bounds__(256)
void seg_kernel(const float* __restrict__ feat, const int* __restrict__ idx,
                float* __restrict__ y, int remap)
{
    __shared__ int sidx[NFEAT];
    __shared__ int list[SEGCAP];
    __shared__ int offs[256];
    int seg = blockIdx.x;
    int tid = threadIdx.x;
    for (int j = tid; j < NFEAT; j += 256) sidx[j] = idx[j];
    __syncthreads();

    int base = tid * 32;
    int cnt = 0;
    #pragma unroll
    for (int i = 0; i < 32; ++i) cnt += (sidx[base + i] == seg) ? 1 : 0;
    offs[tid] = cnt;
    __syncthreads();
    for (int st = 1; st < 256; st <<= 1) {
        int v = (tid >= st) ? offs[tid - st] : 0;
        __syncthreads();
        offs[tid] += v;
        __syncthreads();
    }
    int total = offs[255];
    int pos = offs[tid] - cnt;
    __syncthreads();

    float mx0 = -FLT_MAX, mx1 = -FLT_MAX, mx2 = -FLT_MAX;
    float s0 = 0.f, s1 = 0.f, s2 = 0.f;

    if (total <= SEGCAP) {
        #pragma unroll
        for (int i = 0; i < 32; ++i) {
            int j = base + i;
            if (sidx[j] == seg) list[pos++] = j;
        }
        __syncthreads();
        for (int i = 0; i < total; ++i) {
            const float* fr = feat + rmap(list[i], remap) * CDIM;
            float v0 = fr[tid], v1 = fr[tid + 256], v2 = fr[tid + 512];
            s0 += v0; s1 += v1; s2 += v2;
            mx0 = fmaxf(mx0, v0); mx1 = fmaxf(mx1, v1); mx2 = fmaxf(mx2, v2);
        }
    } else {
        for (int j = 0; j < NFEAT; ++j) {
            if (sidx[j] == seg) {
                const float* fr = feat + rmap(j, remap) * CDIM;
                float v0 = fr[tid], v1 = fr[tid + 256], v2 = fr[tid + 512];
                s0 += v0; s1 += v1; s2 += v2;
                mx0 = fmaxf(mx0, v0); mx1 = fmaxf(mx1, v1); mx2 = fmaxf(mx2, v2);
            }
        }
    }

    if (total == 0) { mx0 = mx1 = mx2 = 0.f; }
    float inv = 1.f / (float)(total > 0 ? total : 1);
    float* yr = y + (long long)seg * CDIM;
    yr[tid]       = mx0 + s0 * inv;
    yr[tid + 256] = mx1 + s1 * inv;
    yr[tid + 512] = mx2 + s2 * inv;
}

// ---------------------------------------------------------------------------
// BatchNorm 3-phase (coalesced): partials -> stats -> apply+GELU
// ---------------------------------------------------------------------------
__global__ __launch_bounds__(256)
void bn_part_kernel(const float* __restrict__ y, float* __restrict__ part, int R)
{
    __shared__ float sh[2][4][64];
    int cb = blockIdx.x * 64;
    int ch = blockIdx.y;
    int r0 = (R * ch) / BNCH, r1 = (R * (ch + 1)) / BNCH;
    int tx = threadIdx.x & 63, ty = threadIdx.x >> 6;
    int c = cb + tx;
    float s = 0.f, ss = 0.f;
    for (int r = r0 + ty; r < r1; r += 4) {
        float v = y[(long long)r * CDIM + c];
        s += v; ss += v * v;
    }
    sh[0][ty][tx] = s; sh[1][ty][tx] = ss;
    __syncthreads();
    if (ty == 0) {
        float S  = sh[0][0][tx] + sh[0][1][tx] + sh[0][2][tx] + sh[0][3][tx];
        float SS = sh[1][0][tx] + sh[1][1][tx] + sh[1][2][tx] + sh[1][3][tx];
        part[(long long)ch * CDIM * 2 + c]        = S;
        part[(long long)ch * CDIM * 2 + CDIM + c] = SS;
    }
}

__global__ __launch_bounds__(256)
void bn_stat_kernel(const float* __restrict__ part, float* __restrict__ meanr, int R)
{
    int c = blockIdx.x * 256 + threadIdx.x;
    if (c >= CDIM) return;
    float S = 0.f, SS = 0.f;
    for (int ch = 0; ch < BNCH; ++ch) {
        S  += part[(long long)ch * CDIM * 2 + c];
        SS += part[(long long)ch * CDIM * 2 + CDIM + c];
    }
    float mean = S / (float)R;
    float var = fmaxf(SS / (float)R - mean * mean, 0.f);
    meanr[c] = mean;
    meanr[CDIM + c] = rsqrtf(var + 1e-5f);
}

__global__ __launch_bounds__(256)
void bn_apply_kernel(const float* __restrict__ y, const float* __restrict__ meanr,
                     const float* __restrict__ g, const float* __restrict__ b,
                     long long goff, bf16* __restrict__ out)
{
    long long r = blockIdx.x;
    int tid = threadIdx.x;
    #pragma unroll
    for (int i = 0; i < 3; ++i) {
        int c = tid + i * 256;
        float v = (y[r * CDIM + c] - meanr[c]) * meanr[CDIM + c] * g[goff + c] + b[goff + c];
        out[r * CDIM + c] = f2b(gelu_exact(v));
    }
}

// ---------------------------------------------------------------------------
// Final fusion: LDS-cached p rows, fast reductions, RMW d_out rows
// ---------------------------------------------------------------------------
__global__ __launch_bounds__(256)
void fuse_final_kernel(const bf16* __restrict__ bn3d, const bf16* __restrict__ bn1d,
                       const int* __restrict__ cluster, const int* __restrict__ fgi,
                       float* __restrict__ out)
{
    __shared__ float red4[4];
    __shared__ float x3s[CDIM];
    __shared__ bf16 pc[NVIEW][CDIM];
    __shared__ float simsh[NVIEW];
    int j = blockIdx.x;
    int tid = threadIdx.x;
    int b = j >> 10, g = j & 1023;
    const bf16* x3 = bn3d + (long long)cluster[j] * CDIM;
    float s = 0.f;
    for (int c = tid; c < CDIM; c += 256) {
        float v = b2f(x3[c]);
        x3s[c] = v;
        s += v * v;
    }
    __syncthreads();
    float nx3 = fmaxf(sqrtf(brs_fast(s, red4, 4)), 1e-8f);

    for (int i = 0; i < NVIEW; ++i) {
        const bf16* p = bn1d + ((long long)i * NGRID + fgi[i * NFEAT + j]) * CDIM;
        float d = 0.f, nn = 0.f;
        for (int c = tid; c < CDIM; c += 256) {
            bf16 u = p[c];
            pc[i][c] = u;
            float pv = b2f(u);
            d += pv * x3s[c]; nn += pv * pv;
        }
        float D = brs_fast(d, red4, 4);
        float Np = sqrtf(brs_fast(nn, red4, 4));
        if (tid == 0) {
            float cosv = D / (fmaxf(Np, 1e-8f) * nx3);
            simsh[i] = (cosv + 1.f) * 0.5f;
        }
    }
    __syncthreads();
    float ssum = 0.f;
    #pragma unroll
    for (int i = 0; i < NVIEW; ++i) ssum += simsh[i];
    float invs = 1.f / fmaxf(ssum, 1e-20f);
    long long orow = ((long long)b * SEQ + 1 + g) * CDIM;
    for (int c = tid; c < CDIM; c += 256) {
        float acc = 0.f;
        #pragma unroll
        for (int i = 0; i < NVIEW; ++i) acc += simsh[i] * invs * b2f(pc[i][c]);
        out[orow + c] = out[orow + c] + 0.3f * acc;
    }
}

// ---------------------------------------------------------------------------
// Host side
// ---------------------------------------------------------------------------
extern "C" void kernel_launch(void* const* d_in, const int* in_sizes, int n_in,
                              void* d_out, int out_size, void* d_ws, size_t ws_size,
                              hipStream_t stream)
{
    const float* x      = (const float*)d_in[0];
    const int*  cluster = (const int*)d_in[2];
    const int*  fgi     = (const int*)d_in[3];
    const float* ln1_g = (const float*)d_in[6];
    const float* ln1_b = (const float*)d_in[7];
    const float* w_qkv = (const float*)d_in[8];
    const float* b_qkv = (const float*)d_in[9];
    const float* w_o   = (const float*)d_in[10];
    const float* b_o   = (const float*)d_in[11];
    const float* ln2_g = (const float*)d_in[12];
    const float* ln2_b = (const float*)d_in[13];
    const float* w_fc  = (const float*)d_in[14];
    const float* b_fc  = (const float*)d_in[15];
    const float* w_proj= (const float*)d_in[16];
    const float* b_proj= (const float*)d_in[17];
    const float* w_down= (const float*)d_in[18];
    const float* b_down= (const float*)d_in[19];
    const float* w_up  = (const float*)d_in[20];
    const float* b_up  = (const float*)d_in[21];
    const float* bn3d_g= (const float*)d_in[22];
    const float* bn3d_b= (const float*)d_in[23];
    const float* n3_g  = (const float*)d_in[24];
    const float* n3_b  = (const float*)d_in[25];
    const float* vw_qkv= (const float*)d_in[26];
    const float* vb_qkv= (const float*)d_in[27];
    const float* vw_o  = (const float*)d_in[28];
    const float* vb_o  = (const float*)d_in[29];
    const float* bn1d_g= (const float*)d_in[30];
    const float* bn1d_b= (const float*)d_in[31];
    (void)in_sizes; (void)n_in; (void)out_size; (void)ws_size;

    float* out = (float*)d_out;

    // workspace layout (bytes), total ~205 MB (< proven-safe 209)
    char* w = (char*)d_ws;
    bf16*  QKV    = (bf16*)w;  w += (long long)NROWS * 3 * CDIM * 2;
    bf16*  H      = (bf16*)w;  w += (long long)NROWS * CDIM * 2;
    float* X2     = (float*)w; w += (long long)NROWS * CDIM * 4;
    bf16*  AO     = (bf16*)w;  w += (long long)NROWS * CDIM * 2;
    bf16*  FFN    = (bf16*)w;  w += (long long)NROWS * CDIM * 2;
    float* T1     = (float*)w; w += (long long)HG * BATCH * SEQ * LDT * 2;
    float* Y512   = (float*)w; w += (long long)NCLUST * CDIM * 4;
    bf16*  BN3D   = (bf16*)w;  w += (long long)NCLUST * CDIM * 2;
    float* YG     = (float*)w; w += (long long)NGRID * CDIM * 4;
    bf16*  BN1D   = (bf16*)w;  w += (long long)NVIEW * NGRID * CDIM * 2;
    bf16*  WQKVT  = (bf16*)w;  w += (long long)(3*CDIM) * CDIM * 2;
    bf16*  WOT    = (bf16*)w;  w += (long long)CDIM * CDIM * 2;
    bf16*  WFCT   = (bf16*)w;  w += (long long)(4*CDIM) * CDIM * 2;
    bf16*  WPROJT = (bf16*)w;  w += (long long)CDIM * (4*CDIM) * 2;
    bf16*  VWQKVT = (bf16*)w;  w += (long long)(3*CDIM) * CDIM * 2;
    bf16*  VWOT   = (bf16*)w;  w += (long long)CDIM * CDIM * 2;
    bf16*  VT     = (bf16*)w;  w += (long long)BATCH * CDIM * LDT * 2;
    float* BPART  = (float*)w; w += (long long)BNCH * CDIM * 2 * 4;
    float* BSTAT  = (float*)w; w += (long long)CDIM * 2 * 4;
    bf16*  T1b    = (bf16*)T1;

    dim3 blk(256), blk512(512);

    // ---- weight transposes (f32 -> bf16, N x K) ----
    transpose_kernel<<<dim3(72, 24), blk, 0, stream>>>(w_qkv, WQKVT, CDIM, 3*CDIM);
    transpose_kernel<<<dim3(24, 24), blk, 0, stream>>>(w_o, WOT, CDIM, CDIM);
    transpose_kernel<<<dim3(96, 24), blk, 0, stream>>>(w_fc, WFCT, CDIM, 4*CDIM);
    transpose_kernel<<<dim3(24, 96), blk, 0, stream>>>(w_proj, WPROJT, 4*CDIM, CDIM);

    // ---- stage A ----
    ln_kernel<<<NROWS, blk, 0, stream>>>(x, ln1_g, ln1_b, 0LL, H, 0);

    gemm2<1,0,0,0,0><<<dim3(18, 65, 1), blk512, 0, stream>>>(
        H, WQKVT, b_qkv, nullptr, QKV,
        NROWS, 3*CDIM, CDIM, CDIM, CDIM, 3*CDIM, 0, 1.f, 0, 0LL, 0LL,
        1, 0, 0, 0, 0, 0, 0, 0, nullptr, nullptr, 0);

    transpose_bf16_kernel<<<dim3(24, 33, BATCH), blk, 0, stream>>>(
        QKV + 2*CDIM, VT, SEQ, CDIM, 3*CDIM, LDT,
        (long long)SEQ * 3*CDIM, (long long)CDIM * LDT);

    const long long HSTR = (long long)BATCH * SEQ * LDT;
    for (int g = 0; g < NHEAD / HG; ++g) {
        int hb = g * HG;
        gemm2<1,0,0,0,0><<<dim3(9, 9, BATCH * HG), blk512, 0, stream>>>(
            QKV + hb * DHEAD, QKV + CDIM + hb * DHEAD, nullptr, nullptr, T1b,
            SEQ, SEQ, DHEAD, 3*CDIM, 3*CDIM, LDT, 0, 0.125f, 0, 0LL, 0LL,
            BATCH, (long long)SEQ * 3*CDIM, DHEAD,
            (long long)SEQ * 3*CDIM, DHEAD,
            (long long)SEQ * LDT, HSTR, 0, nullptr, nullptr, 0);

        softmax_aw3_kernel<<<NROWS, blk, 0, stream>>>(T1b, out, g == 0 ? 1 : 0);

        gemm_k<1,0,0,0><<<dim3(1, 17, BATCH * HG), blk, 0, stream>>>(
            T1b, VT + (long long)hb * DHEAD * LDT, nullptr, nullptr, AO + hb * DHEAD,
            SEQ, DHEAD, SEQ, LDT, LDT, CDIM, 0, 1.f, 0, 0LL, 0LL,
            BATCH, (long long)SEQ * LDT, HSTR,
            (long long)CDIM * LDT, (long long)DHEAD * LDT,
            (long long)SEQ * CDIM, DHEAD, 0);
    }

    gemm2<1,0,1,1,0><<<dim3(6, 65, 1), blk512, 0, stream>>>(
        AO, WOT, b_o, x, X2,
        NROWS, CDIM, CDIM, CDIM, CDIM, CDIM, CDIM, 1.f, 0, 0LL, 0LL,
        1, 0, 0, 0, 0, 0, 0, 0, nullptr, nullptr, 0);

    ln_kernel<<<NROWS, blk, 0, stream>>>(X2, ln2_g, ln2_b, 0LL, H, 0);

    // FC + proj unchunked (MID 50.4MB fits T1 50.8MB)
    {
        bf16* MID = (bf16*)T1;
        gemm2<1,0,0,0,0><<<dim3(24, 65, 1), blk512, 0, stream>>>(
            H, WFCT, b_fc, nullptr, MID,
            NROWS, 4*CDIM, CDIM, CDIM, CDIM, 4*CDIM, 0, 1.f, 1, 0LL, 0LL,
            1, 0, 0, 0, 0, 0, 0, 0, nullptr, nullptr, 0);
        gemm2<1,0,0,0,0><<<dim3(6, 65, 1), blk512, 0, stream>>>(
            MID, WPROJT, b_proj, nullptr, FFN,
            NROWS, CDIM, 4*CDIM, 4*CDIM, 4*CDIM, CDIM, 0, 1.f, 0, 0LL, 0LL,
            1, 0, 0, 0, 0, 0, 0, 0, nullptr, nullptr, 0);
    }

    adp_final_kernel<<<NROWS, blk, 0, stream>>>(FFN, w_down, b_down, w_up, b_up,
                                                X2, out);

    // shared norm for all views: H = (feat - mu) / sigma (bf16)
    norm_kernel<<<NFEAT, blk, 0, stream>>>(out, H);

    // ---- stage B ----
    seg_kernel<<<NCLUST, blk, 0, stream>>>(out, cluster, Y512, 1);
    bn_part_kernel<<<dim3(12, BNCH), blk, 0, stream>>>(Y512, BPART, NCLUST);
    bn_stat_kernel<<<dim3(3), blk, 0, stream>>>(BPART, BSTAT, NCLUST);
    bn_apply_kernel<<<NCLUST, blk, 0, stream>>>(Y512, BSTAT, bn3d_g, bn3d_b, 0LL, BN3D);

    // ---- stage C: 6 views ----
    const float inv_sqrt_c = 0.03608439182435161f;
    for (int i = 0; i < NVIEW; ++i) {
        transpose_kernel<<<dim3(72, 24), blk, 0, stream>>>(
            vw_qkv + (long long)i * CDIM * 3*CDIM, VWQKVT, CDIM, 3*CDIM);
        transpose_kernel<<<dim3(24, 24), blk, 0, stream>>>(
            vw_o + (long long)i * CDIM * CDIM, VWOT, CDIM, CDIM);

        // view QKV with fused per-view gamma/beta on A staging
        gemm2<1,0,0,0,1><<<dim3(18, 64, 1), blk512, 0, stream>>>(
            H, VWQKVT, vb_qkv, nullptr, QKV,
            NFEAT, 3*CDIM, CDIM, CDIM, CDIM, 3*CDIM, 0, 1.f, 0,
            0LL, (long long)i * 3*CDIM, 1, 0, 0, 0, 0, 0, 0, 0,
            n3_g, n3_b, (long long)i * CDIM);

        transpose_bf16_kernel<<<dim3(24, 32, BATCH), blk, 0, stream>>>(
            QKV + 2*CDIM, VT, GTOK, CDIM, 3*CDIM, GTOK,
            (long long)GTOK * 3*CDIM, (long long)CDIM * GTOK);

        gemm2<1,0,0,0,0><<<dim3(8, 8, BATCH), blk512, 0, stream>>>(
            QKV, QKV + CDIM, nullptr, nullptr, T1b,
            GTOK, GTOK, CDIM, 3*CDIM, 3*CDIM, GTOK, 0, inv_sqrt_c, 0, 0LL, 0LL,
            BATCH, (long long)GTOK * 3*CDIM, 0,
            (long long)GTOK * 3*CDIM, 0,
            (long long)GTOK * GTOK, 0, 0, nullptr, nullptr, 0);

        softmax_rows_bf16<<<BATCH * GTOK, blk, 0, stream>>>(T1b);

        gemm2<1,0,0,0,0><<<dim3(6, 8, BATCH), blk512, 0, stream>>>(
            T1b, VT, nullptr, nullptr, AO,
            GTOK, CDIM, GTOK, GTOK, GTOK, CDIM, 0, 1.f, 0, 0LL, 0LL,
            BATCH, (long long)GTOK * GTOK, 0,
            (long long)CDIM * GTOK, 0,
            (long long)GTOK * CDIM, 0, 0, nullptr, nullptr, 0);

        gemm2<1,0,1,1,0><<<dim3(6, 8, BATCH), blk512, 0, stream>>>(
            AO, VWOT, vb_o, out + CDIM, X2,
            GTOK, CDIM, CDIM, CDIM, CDIM, CDIM, CDIM, 1.f, 0,
            0LL, (long long)i * CDIM,
            BATCH, (long long)GTOK * CDIM, 0, 0, 0,
            (long long)GTOK * CDIM, 0, (long long)SEQ * CDIM, nullptr, nullptr, 0);

        seg_kernel<<<NGRID, blk, 0, stream>>>(X2, fgi + i * NFEAT, YG, 0);
        bn_part_kernel<<<dim3(12, BNCH), blk, 0, stream>>>(YG, BPART, NGRID);
        bn_stat_kernel<<<dim3(3), blk, 0, stream>>>(BPART, BSTAT, NGRID);
        bn_apply_kernel<<<NGRID, blk, 0, stream>>>(YG, BSTAT, bn1d_g, bn1d_b,
                                                   (long long)i * CDIM,
                                                   BN1D + (long long)i * NGRID * CDIM);
    }

    // ---- final fusion ----
    fuse_final_kernel<<<NFEAT, blk, 0, stream>>>(BN3D, BN1D, cluster, fgi, out);
}

// Round 20
// 2391.414 us; speedup vs baseline: 2.0925x; 1.0198x over previous
//
#include <hip/hip_runtime.h>
#include <math.h>
#include <float.h>

#define BATCH   8
#define SEQ     1025
#define GTOK    1024
#define CDIM    768
#define NHEAD   12
#define DHEAD   64
#define NVIEW   6
#define NCLUST  512
#define NGRID   1568
#define NROWS   8200
#define NFEAT   8192
#define SEGCAP  2048
#define LDT     1032
#define HG      3
#define BNCH    16

typedef unsigned short bf16;
typedef __attribute__((ext_vector_type(8))) short bf16x8;
typedef __attribute__((ext_vector_type(4))) float f32x4;

__device__ __forceinline__ float b2f(bf16 u) {
    union { unsigned int i; float f; } v; v.i = ((unsigned int)u) << 16; return v.f;
}
__device__ __forceinline__ bf16 f2b(float f) {
    union { float f; unsigned int i; } v; v.f = f;
    unsigned int x = v.i;
    return (bf16)((x + 0x7fffu + ((x >> 16) & 1u)) >> 16);
}

__device__ __forceinline__ float brs_fast(float v, float* red4, int nw) {
    #pragma unroll
    for (int o = 32; o > 0; o >>= 1) v += __shfl_down(v, o);
    int lane = threadIdx.x & 63, wid = threadIdx.x >> 6;
    if (lane == 0) red4[wid] = v;
    __syncthreads();
    float r = 0.f;
    for (int i = 0; i < nw; ++i) r += red4[i];
    __syncthreads();
    return r;
}
__device__ __forceinline__ float brm_fast(float v, float* red4, int nw) {
    #pragma unroll
    for (int o = 32; o > 0; o >>= 1) v = fmaxf(v, __shfl_down(v, o));
    int lane = threadIdx.x & 63, wid = threadIdx.x >> 6;
    if (lane == 0) red4[wid] = v;
    __syncthreads();
    float r = -FLT_MAX;
    for (int i = 0; i < nw; ++i) r = fmaxf(r, red4[i]);
    __syncthreads();
    return r;
}

__device__ __forceinline__ float gelu_exact(float v) {
    return 0.5f * v * (1.f + erff(v * 0.70710678118654752f));
}
__device__ __forceinline__ float quick_gelu(float v) {
    return v / (1.f + expf(-1.702f * v));
}

__device__ __forceinline__ long long rmap(long long j, int remap) {
    return remap ? (j + 1 + (j >> 10)) : j;
}

// bijective XCD-chunked block remap (m204 variant): physical flat -> logical
__device__ __forceinline__ long long xcd_swz(long long flat, long long nwg) {
    long long q = nwg >> 3, r = nwg & 7;
    long long xcd = flat & 7, idx = flat >> 3;
    long long start = (xcd < r) ? xcd * (q + 1) : r * (q + 1) + (xcd - r) * q;
    return start + idx;
}

// ---------------------------------------------------------------------------
// Tiled transpose: W (K x N, f32) -> WT (N x K, bf16)
// ---------------------------------------------------------------------------
__global__ __launch_bounds__(256)
void transpose_kernel(const float* __restrict__ W, bf16* __restrict__ WT, int K, int N)
{
    __shared__ float t[32][33];
    int n0 = blockIdx.x * 32, k0 = blockIdx.y * 32;
    int tx = threadIdx.x & 31, ty = threadIdx.x >> 5;
    #pragma unroll
    for (int i = 0; i < 4; ++i) {
        int k = k0 + ty + i * 8, n = n0 + tx;
        t[ty + i * 8][tx] = (k < K && n < N) ? W[(long long)k * N + n] : 0.f;
    }
    __syncthreads();
    #pragma unroll
    for (int i = 0; i < 4; ++i) {
        int n = n0 + ty + i * 8, k = k0 + tx;
        if (n < N && k < K)
            WT[(long long)n * K + k] = f2b(t[tx][ty + i * 8]);
    }
}

// ---------------------------------------------------------------------------
// Batched bf16 transpose
// ---------------------------------------------------------------------------
__global__ __launch_bounds__(256)
void transpose_bf16_kernel(const bf16* __restrict__ src, bf16* __restrict__ dst,
                           int K, int N, int lds, int ldd,
                           long long sSrc, long long sDst)
{
    __shared__ bf16 t[32][34];
    int z = blockIdx.z;
    const bf16* S = src + (long long)z * sSrc;
    bf16* D = dst + (long long)z * sDst;
    int n0 = blockIdx.x * 32, k0 = blockIdx.y * 32;
    int tx = threadIdx.x & 31, ty = threadIdx.x >> 5;
    #pragma unroll
    for (int i = 0; i < 4; ++i) {
        int k = k0 + ty + i * 8, n = n0 + tx;
        t[ty + i * 8][tx] = (k < K && n < N) ? S[(long long)k * lds + n] : (bf16)0;
    }
    __syncthreads();
    #pragma unroll
    for (int i = 0; i < 4; ++i) {
        int n = n0 + ty + i * 8, k = k0 + tx;
        if (n < N && k < K)
            D[(long long)n * ldd + k] = t[tx][ty + i * 8];
    }
}

// ---------------------------------------------------------------------------
// LayerNorm (fast reductions)
// ---------------------------------------------------------------------------
__global__ __launch_bounds__(256)
void ln_kernel(const float* __restrict__ x, const float* __restrict__ g,
               const float* __restrict__ b, long long goff, bf16* __restrict__ out,
               int remap)
{
    __shared__ float red4[4];
    long long row = blockIdx.x;
    int tid = threadIdx.x;
    long long ibase = rmap(row, remap) * CDIM;
    long long obase = row * CDIM;
    float v0 = x[ibase + tid], v1 = x[ibase + tid + 256], v2 = x[ibase + tid + 512];
    float mean = brs_fast(v0 + v1 + v2, red4, 4) * (1.f / CDIM);
    float d0 = v0 - mean, d1 = v1 - mean, d2 = v2 - mean;
    float var = brs_fast(d0 * d0 + d1 * d1 + d2 * d2, red4, 4) * (1.f / CDIM);
    float rstd = rsqrtf(var + 1e-5f);
    bf16* orow = out + obase;
    orow[tid]       = f2b(d0 * rstd * g[goff + tid]       + b[goff + tid]);
    orow[tid + 256] = f2b(d1 * rstd * g[goff + tid + 256] + b[goff + tid + 256]);
    orow[tid + 512] = f2b(d2 * rstd * g[goff + tid + 512] + b[goff + tid + 512]);
}

// ---------------------------------------------------------------------------
// norm only: (x - mean) * rstd -> bf16 (shared across views)
// ---------------------------------------------------------------------------
__global__ __launch_bounds__(256)
void norm_kernel(const float* __restrict__ x, bf16* __restrict__ out)
{
    __shared__ float red4[4];
    long long row = blockIdx.x;
    int tid = threadIdx.x;
    long long ibase = rmap(row, 1) * CDIM;
    long long obase = row * CDIM;
    float v0 = x[ibase + tid], v1 = x[ibase + tid + 256], v2 = x[ibase + tid + 512];
    float mean = brs_fast(v0 + v1 + v2, red4, 4) * (1.f / CDIM);
    float d0 = v0 - mean, d1 = v1 - mean, d2 = v2 - mean;
    float var = brs_fast(d0 * d0 + d1 * d1 + d2 * d2, red4, 4) * (1.f / CDIM);
    float rstd = rsqrtf(var + 1e-5f);
    bf16* orow = out + obase;
    orow[tid]       = f2b(d0 * rstd);
    orow[tid + 256] = f2b(d1 * rstd);
    orow[tid + 512] = f2b(d2 * rstd);
}

// ---------------------------------------------------------------------------
// gemm_k: 64x64-tile MFMA GEMM. Dual batch strides + optional XCD swizzle.
// ---------------------------------------------------------------------------
#define LDSK 40

template<int TRANSB, int ATY, int OTY, int RES, int SWZ>
__global__ __launch_bounds__(256)
void gemm_k(const void* __restrict__ Av, const bf16* __restrict__ B,
            const float* __restrict__ bias, const float* __restrict__ Res,
            void* __restrict__ Cv,
            int M, int N, int K, int lda, int ldb, int ldc, int ldres,
            float alpha, int act, long long boff, long long biasoff, int zdiv,
            long long sA1, long long sA2, long long sB1, long long sB2,
            long long sC1, long long sC2, long long sRes)
{
    __shared__ short As[64][LDSK];
    __shared__ short Bs[64][LDSK];
    int bx = blockIdx.x, by = blockIdx.y, bz = blockIdx.z;
    if (SWZ) {
        long long nwg = (long long)gridDim.x * gridDim.y * gridDim.z;
        long long flat = blockIdx.x + (long long)gridDim.x *
                         (blockIdx.y + (long long)gridDim.y * blockIdx.z);
        long long l = xcd_swz(flat, nwg);
        bx = (int)(l % gridDim.x);
        by = (int)((l / gridDim.x) % gridDim.y);
        bz = (int)(l / ((long long)gridDim.x * gridDim.y));
    }
    int bz1 = bz % zdiv, bz2 = bz / zdiv;
    int tid = threadIdx.x;
    int m0 = by * 64, n0 = bx * 64;
    long long Aoff = bz1 * sA1 + bz2 * sA2;
    long long Boff = boff + bz1 * sB1 + bz2 * sB2;
    long long Coff = bz1 * sC1 + bz2 * sC2;
    long long Roff = bz1 * sRes;

    int lane = tid & 63;
    int w = tid >> 6;
    int wr = w >> 1, wc = w & 1;
    int fr = lane & 15;
    int kg = lane >> 4;

    f32x4 acc[2][2] = {};

    for (int k0 = 0; k0 < K; k0 += 32) {
        {
            int r = tid >> 2, kb = (tid & 3) * 8;
            int gm = m0 + r;
            short tmp[8] = {};
            if (gm < M) {
                long long base = Aoff + (long long)gm * lda + k0 + kb;
                if (k0 + kb + 8 <= K) {
                    if (ATY == 0) {
                        *reinterpret_cast<uint4*>(tmp) =
                            *reinterpret_cast<const uint4*>((const bf16*)Av + base);
                    } else {
                        float4 f0 = *reinterpret_cast<const float4*>((const float*)Av + base);
                        float4 f1 = *reinterpret_cast<const float4*>((const float*)Av + base + 4);
                        tmp[0]=(short)f2b(f0.x); tmp[1]=(short)f2b(f0.y);
                        tmp[2]=(short)f2b(f0.z); tmp[3]=(short)f2b(f0.w);
                        tmp[4]=(short)f2b(f1.x); tmp[5]=(short)f2b(f1.y);
                        tmp[6]=(short)f2b(f1.z); tmp[7]=(short)f2b(f1.w);
                    }
                } else {
                    #pragma unroll
                    for (int j = 0; j < 8; ++j) {
                        if (k0 + kb + j < K)
                            tmp[j] = ATY ? (short)f2b(((const float*)Av)[base + j])
                                         : (short)((const bf16*)Av)[base + j];
                    }
                }
            }
            *reinterpret_cast<uint4*>(&As[r][kb]) = *reinterpret_cast<uint4*>(tmp);
        }
        {
            int col = tid >> 2, kb = (tid & 3) * 8;
            int gn = n0 + col;
            short tmp[8] = {};
            if (gn < N) {
                if (TRANSB) {
                    long long base = Boff + (long long)gn * ldb + k0 + kb;
                    if (k0 + kb + 8 <= K) {
                        *reinterpret_cast<uint4*>(tmp) =
                            *reinterpret_cast<const uint4*>(B + base);
                    } else {
                        #pragma unroll
                        for (int j = 0; j < 8; ++j)
                            if (k0 + kb + j < K) tmp[j] = (short)B[base + j];
                    }
                } else {
                    #pragma unroll
                    for (int j = 0; j < 8; ++j) {
                        int kk = k0 + kb + j;
                        if (kk < K)
                            tmp[j] = (short)B[Boff + (long long)kk * ldb + gn];
                    }
                }
            }
            *reinterpret_cast<uint4*>(&Bs[col][kb]) = *reinterpret_cast<uint4*>(tmp);
        }
        __syncthreads();

        bf16x8 a0 = *reinterpret_cast<const bf16x8*>(&As[wr * 32 + fr][kg * 8]);
        bf16x8 a1 = *reinterpret_cast<const bf16x8*>(&As[wr * 32 + 16 + fr][kg * 8]);
        bf16x8 b0 = *reinterpret_cast<const bf16x8*>(&Bs[wc * 32 + fr][kg * 8]);
        bf16x8 b1 = *reinterpret_cast<const bf16x8*>(&Bs[wc * 32 + 16 + fr][kg * 8]);
        acc[0][0] = __builtin_amdgcn_mfma_f32_16x16x32_bf16(a0, b0, acc[0][0], 0, 0, 0);
        acc[0][1] = __builtin_amdgcn_mfma_f32_16x16x32_bf16(a0, b1, acc[0][1], 0, 0, 0);
        acc[1][0] = __builtin_amdgcn_mfma_f32_16x16x32_bf16(a1, b0, acc[1][0], 0, 0, 0);
        acc[1][1] = __builtin_amdgcn_mfma_f32_16x16x32_bf16(a1, b1, acc[1][1], 0, 0, 0);
        __syncthreads();
    }

    #pragma unroll
    for (int m = 0; m < 2; ++m) {
        #pragma unroll
        for (int n = 0; n < 2; ++n) {
            #pragma unroll
            for (int i = 0; i < 4; ++i) {
                int gm = m0 + wr * 32 + m * 16 + kg * 4 + i;
                int gn = n0 + wc * 32 + n * 16 + fr;
                if (gm >= M || gn >= N) continue;
                float v = acc[m][n][i] * alpha;
                if (bias) v += bias[biasoff + gn];
                if (act == 1) v = quick_gelu(v);
                if (RES) v += Res[Roff + (long long)gm * ldres + gn];
                long long ci = Coff + (long long)gm * ldc + gn;
                if (OTY) ((float*)Cv)[ci] = v;
                else     ((bf16*)Cv)[ci] = f2b(v);
            }
        }
    }
}

// ---------------------------------------------------------------------------
// gemm2: 128x128-tile MFMA GEMM, register-prefetch pipeline, XCD swizzle.
// ---------------------------------------------------------------------------
template<int TRANSB, int ATY, int OTY, int RES, int ASC, int SWZ>
__global__ __launch_bounds__(512)
void gemm2(const void* __restrict__ Av, const bf16* __restrict__ B,
           const float* __restrict__ bias, const float* __restrict__ Res,
           void* __restrict__ Cv,
           int M, int N, int K, int lda, int ldb, int ldc, int ldres,
           float alpha, int act, long long boff, long long biasoff, int zdiv,
           long long sA1, long long sA2, long long sB1, long long sB2,
           long long sC1, long long sC2, long long sRes,
           const float* __restrict__ gsc, const float* __restrict__ gbs,
           long long gsoff)
{
    __shared__ short As[128][LDSK];
    __shared__ short Bs[128][LDSK];
    int bx = blockIdx.x, by = blockIdx.y, bz = blockIdx.z;
    if (SWZ) {
        long long nwg = (long long)gridDim.x * gridDim.y * gridDim.z;
        long long flat = blockIdx.x + (long long)gridDim.x *
                         (blockIdx.y + (long long)gridDim.y * blockIdx.z);
        long long l = xcd_swz(flat, nwg);
        bx = (int)(l % gridDim.x);
        by = (int)((l / gridDim.x) % gridDim.y);
        bz = (int)(l / ((long long)gridDim.x * gridDim.y));
    }
    int bz1 = bz % zdiv, bz2 = bz / zdiv;
    int tid = threadIdx.x;
    int m0 = by * 128, n0 = bx * 128;
    long long Aoff = bz1 * sA1 + bz2 * sA2;
    long long Boff = boff + bz1 * sB1 + bz2 * sB2;
    long long Coff = bz1 * sC1 + bz2 * sC2;
    long long Roff = bz1 * sRes;

    int lane = tid & 63;
    int w = tid >> 6;
    int wr = w >> 2, wc = w & 3;
    int fr = lane & 15;
    int kg = lane >> 4;

    int srow = tid >> 2;
    int skb  = (tid & 3) * 8;

    short ra[8], rb[8];

    auto loadA = [&](int kk) {
        int gm = m0 + srow;
        if (gm < M) {
            long long base = Aoff + (long long)gm * lda + kk + skb;
            if (ATY == 0) {
                *reinterpret_cast<uint4*>(ra) =
                    *reinterpret_cast<const uint4*>((const bf16*)Av + base);
                if (ASC) {
                    #pragma unroll
                    for (int j = 0; j < 8; ++j) {
                        long long gi = gsoff + kk + skb + j;
                        ra[j] = (short)f2b(b2f((bf16)ra[j]) * gsc[gi] + gbs[gi]);
                    }
                }
            } else {
                float4 f0 = *reinterpret_cast<const float4*>((const float*)Av + base);
                float4 f1 = *reinterpret_cast<const float4*>((const float*)Av + base + 4);
                ra[0]=(short)f2b(f0.x); ra[1]=(short)f2b(f0.y);
                ra[2]=(short)f2b(f0.z); ra[3]=(short)f2b(f0.w);
                ra[4]=(short)f2b(f1.x); ra[5]=(short)f2b(f1.y);
                ra[6]=(short)f2b(f1.z); ra[7]=(short)f2b(f1.w);
            }
        } else {
            #pragma unroll
            for (int j = 0; j < 8; ++j) ra[j] = 0;
        }
    };
    auto loadB = [&](int kk) {
        if (TRANSB) {
            int gn = n0 + srow;
            if (gn < N) {
                long long base = Boff + (long long)gn * ldb + kk + skb;
                *reinterpret_cast<uint4*>(rb) =
                    *reinterpret_cast<const uint4*>(B + base);
            } else {
                #pragma unroll
                for (int j = 0; j < 8; ++j) rb[j] = 0;
            }
        } else {
            int gn = n0 + srow;
            if (gn < N) {
                #pragma unroll
                for (int j = 0; j < 8; ++j) {
                    long long bi = Boff + (long long)(kk + skb + j) * ldb + gn;
                    rb[j] = (short)B[bi];
                }
            } else {
                #pragma unroll
                for (int j = 0; j < 8; ++j) rb[j] = 0;
            }
        }
    };

    f32x4 acc[4][2] = {};

    loadA(0); loadB(0);
    for (int k0 = 0; k0 < K; k0 += 32) {
        *reinterpret_cast<uint4*>(&As[srow][skb]) = *reinterpret_cast<uint4*>(ra);
        *reinterpret_cast<uint4*>(&Bs[srow][skb]) = *reinterpret_cast<uint4*>(rb);
        __syncthreads();
        if (k0 + 32 < K) { loadA(k0 + 32); loadB(k0 + 32); }

        bf16x8 a[4], bq[2];
        #pragma unroll
        for (int m = 0; m < 4; ++m)
            a[m] = *reinterpret_cast<const bf16x8*>(&As[wr * 64 + m * 16 + fr][kg * 8]);
        #pragma unroll
        for (int n = 0; n < 2; ++n)
            bq[n] = *reinterpret_cast<const bf16x8*>(&Bs[wc * 32 + n * 16 + fr][kg * 8]);
        #pragma unroll
        for (int m = 0; m < 4; ++m)
            #pragma unroll
            for (int n = 0; n < 2; ++n)
                acc[m][n] = __builtin_amdgcn_mfma_f32_16x16x32_bf16(a[m], bq[n], acc[m][n], 0, 0, 0);
        __syncthreads();
    }

    #pragma unroll
    for (int m = 0; m < 4; ++m) {
        #pragma unroll
        for (int n = 0; n < 2; ++n) {
            #pragma unroll
            for (int i = 0; i < 4; ++i) {
                int gm = m0 + wr * 64 + m * 16 + kg * 4 + i;
                int gn = n0 + wc * 32 + n * 16 + fr;
                if (gm >= M || gn >= N) continue;
                float v = acc[m][n][i] * alpha;
                if (bias) v += bias[biasoff + gn];
                if (act == 1) v = quick_gelu(v);
                if (RES) v += Res[Roff + (long long)gm * ldres + gn];
                long long ci = Coff + (long long)gm * ldc + gn;
                if (OTY) ((float*)Cv)[ci] = v;
                else     ((bf16*)Cv)[ci] = f2b(v);
            }
        }
    }
}

// ---------------------------------------------------------------------------
// Fused softmax + attn_weight accumulate, 3 heads per block
// ---------------------------------------------------------------------------
__global__ __launch_bounds__(256)
void softmax_aw3_kernel(bf16* __restrict__ T1, float* __restrict__ out, int first)
{
    __shared__ float red4[4];
    __shared__ float srow[SEQ];
    __shared__ float awsh[SEQ];
    long long r = blockIdx.x;
    float* aw = out + (long long)NROWS * CDIM + r * SEQ;
    int tid = threadIdx.x;
    const long long HSTRIDE = (long long)BATCH * SEQ * LDT;
    const float hscale = 1.f / (float)NHEAD;

    for (int k = tid; k < SEQ; k += 256) awsh[k] = 0.f;
    __syncthreads();

    for (int j = 0; j < HG; ++j) {
        bf16* sr = T1 + j * HSTRIDE + r * LDT;
        float lmax = -FLT_MAX;
        for (int k = tid; k < SEQ; k += 256) {
            float v = b2f(sr[k]);
            srow[k] = v;
            lmax = fmaxf(lmax, v);
        }
        __syncthreads();
        float m = brm_fast(lmax, red4, 4);

        float ls = 0.f;
        for (int k = tid; k < SEQ; k += 256) {
            float p = expf(srow[k] - m);
            srow[k] = p; ls += p;
        }
        float Z = brs_fast(ls, red4, 4);
        float inv = 1.f / fmaxf(Z, 1e-30f);
        for (int k = tid; k < SEQ; k += 256) {
            float p = srow[k] * inv;
            sr[k] = f2b(p);
            awsh[k] += p * hscale;
        }
        __syncthreads();
    }
    for (int k = tid; k < SEQ; k += 256)
        aw[k] = (first ? 0.f : aw[k]) + awsh[k];
}

// ---------------------------------------------------------------------------
// Row softmax (view attention), bf16 rows
// ---------------------------------------------------------------------------
__global__ __launch_bounds__(256)
void softmax_rows_bf16(bf16* __restrict__ s)
{
    __shared__ float red4[4];
    __shared__ float srow[GTOK];
    long long row = blockIdx.x;
    bf16* sr = s + row * GTOK;
    int tid = threadIdx.x;
    float lmax = -FLT_MAX;
    #pragma unroll
    for (int i = 0; i < 4; ++i) {
        float v = b2f(sr[tid + i * 256]);
        srow[tid + i * 256] = v;
        lmax = fmaxf(lmax, v);
    }
    __syncthreads();
    float m = brm_fast(lmax, red4, 4);
    float ls = 0.f;
    #pragma unroll
    for (int i = 0; i < 4; ++i) {
        float p = expf(srow[tid + i * 256] - m);
        srow[tid + i * 256] = p; ls += p;
    }
    float Z = brs_fast(ls, red4, 4);
    float inv = 1.f / fmaxf(Z, 1e-30f);
    #pragma unroll
    for (int i = 0; i < 4; ++i) sr[tid + i * 256] = f2b(srow[tid + i * 256] * inv);
}

// ---------------------------------------------------------------------------
// Fused adapter + final residual (coalesced w_down)
// ---------------------------------------------------------------------------
__global__ __launch_bounds__(256)
void adp_final_kernel(const bf16* __restrict__ ffn, const float* __restrict__ w_down,
                      const float* __restrict__ b_down, const float* __restrict__ w_up,
                      const float* __restrict__ b_up, const float* __restrict__ x2,
                      float* __restrict__ out)
{
    __shared__ float rowsh[CDIM];
    __shared__ float red[256];
    __shared__ float a[16];
    long long row = blockIdx.x;
    int tid = threadIdx.x;
    for (int c = tid; c < CDIM; c += 256) rowsh[c] = b2f(ffn[row * CDIM + c]);
    __syncthreads();
    int n = tid & 15;
    int part = tid >> 4;
    float s = 0.f;
    for (int i = part; i < CDIM; i += 16) s += rowsh[i] * w_down[i * 16 + n];
    red[tid] = s; __syncthreads();
    if (tid < 16) {
        float t = 0.f;
        #pragma unroll
        for (int p = 0; p < 16; ++p) t += red[p * 16 + tid];
        a[tid] = gelu_exact(t + b_down[tid]);
    }
    __syncthreads();

    #pragma unroll
    for (int i = 0; i < 3; ++i) {
        int c = tid + i * 256;
        float acc = b_up[c];
        #pragma unroll
        for (int k = 0; k < 16; ++k) acc += a[k] * w_up[k * CDIM + c];
        out[row * CDIM + c] = x2[row * CDIM + c] + rowsh[c] + 0.5f * acc;
    }
}

// ---------------------------------------------------------------------------
// Deterministic segment max+mean, compacted
// ---------------------------------------------------------------------------
__global__ __launch_bounds__(256)
void seg_kernel(const float* __restrict__ feat, const int* __restrict__ idx,
                float* __restrict__ y, int remap)
{
    __shared__ int sidx[NFEAT];
    __shared__ int list[SEGCAP];
    __shared__ int offs[256];
    int seg = blockIdx.x;
    int tid = threadIdx.x;
    for (int j = tid; j < NFEAT; j += 256) sidx[j] = idx[j];
    __syncthreads();

    int base = tid * 32;
    int cnt = 0;
    #pragma unroll
    for (int i = 0; i < 32; ++i) cnt += (sidx[base + i] == seg) ? 1 : 0;
    offs[tid] = cnt;
    __syncthreads();
    for (int st = 1; st < 256; st <<= 1) {
        int v = (tid >= st) ? offs[tid - st] : 0;
        __syncthreads();
        offs[tid] += v;
        __syncthreads();
    }
    int total = offs[255];
    int pos = offs[tid] - cnt;
    __syncthreads();

    float mx0 = -FLT_MAX, mx1 = -FLT_MAX, mx2 = -FLT_MAX;
    float s0 = 0.f, s1 = 0.f, s2 = 0.f;

    if (total <= SEGCAP) {
        #pragma unroll
        for (int i = 0; i < 32; ++i) {
            int j = base + i;
            if (sidx[j] == seg) list[pos++] = j;
        }
        __syncthreads();
        for (int i = 0; i < total; ++i) {
            const float* fr = feat + rmap(list[i], remap) * CDIM;
            float v0 = fr[tid], v1 = fr[tid + 256], v2 = fr[tid + 512];
            s0 += v0; s1 += v1; s2 += v2;
            mx0 = fmaxf(mx0, v0); mx1 = fmaxf(mx1, v1); mx2 = fmaxf(mx2, v2);
        }
    } else {
        for (int j = 0; j < NFEAT; ++j) {
            if (sidx[j] == seg) {
                const float* fr = feat + rmap(j, remap) * CDIM;
                float v0 = fr[tid], v1 = fr[tid + 256], v2 = fr[tid + 512];
                s0 += v0; s1 += v1; s2 += v2;
                mx0 = fmaxf(mx0, v0); mx1 = fmaxf(mx1, v1); mx2 = fmaxf(mx2, v2);
            }
        }
    }

    if (total == 0) { mx0 = mx1 = mx2 = 0.f; }
    float inv = 1.f / (float)(total > 0 ? total : 1);
    float* yr = y + (long long)seg * CDIM;
    yr[tid]       = mx0 + s0 * inv;
    yr[tid + 256] = mx1 + s1 * inv;
    yr[tid + 512] = mx2 + s2 * inv;
}

// ---------------------------------------------------------------------------
// BatchNorm 3-phase (coalesced): partials -> stats -> apply+GELU
// ---------------------------------------------------------------------------
__global__ __launch_bounds__(256)
void bn_part_kernel(const float* __restrict__ y, float* __restrict__ part, int R)
{
    __shared__ float sh[2][4][64];
    int cb = blockIdx.x * 64;
    int ch = blockIdx.y;
    int r0 = (R * ch) / BNCH, r1 = (R * (ch + 1)) / BNCH;
    int tx = threadIdx.x & 63, ty = threadIdx.x >> 6;
    int c = cb + tx;
    float s = 0.f, ss = 0.f;
    for (int r = r0 + ty; r < r1; r += 4) {
        float v = y[(long long)r * CDIM + c];
        s += v; ss += v * v;
    }
    sh[0][ty][tx] = s; sh[1][ty][tx] = ss;
    __syncthreads();
    if (ty == 0) {
        float S  = sh[0][0][tx] + sh[0][1][tx] + sh[0][2][tx] + sh[0][3][tx];
        float SS = sh[1][0][tx] + sh[1][1][tx] + sh[1][2][tx] + sh[1][3][tx];
        part[(long long)ch * CDIM * 2 + c]        = S;
        part[(long long)ch * CDIM * 2 + CDIM + c] = SS;
    }
}

__global__ __launch_bounds__(256)
void bn_stat_kernel(const float* __restrict__ part, float* __restrict__ meanr, int R)
{
    int c = blockIdx.x * 256 + threadIdx.x;
    if (c >= CDIM) return;
    float S = 0.f, SS = 0.f;
    for (int ch = 0; ch < BNCH; ++ch) {
        S  += part[(long long)ch * CDIM * 2 + c];
        SS += part[(long long)ch * CDIM * 2 + CDIM + c];
    }
    float mean = S / (float)R;
    float var = fmaxf(SS / (float)R - mean * mean, 0.f);
    meanr[c] = mean;
    meanr[CDIM + c] = rsqrtf(var + 1e-5f);
}

__global__ __launch_bounds__(256)
void bn_apply_kernel(const float* __restrict__ y, const float* __restrict__ meanr,
                     const float* __restrict__ g, const float* __restrict__ b,
                     long long goff, bf16* __restrict__ out)
{
    long long r = blockIdx.x;
    int tid = threadIdx.x;
    #pragma unroll
    for (int i = 0; i < 3; ++i) {
        int c = tid + i * 256;
        float v = (y[r * CDIM + c] - meanr[c]) * meanr[CDIM + c] * g[goff + c] + b[goff + c];
        out[r * CDIM + c] = f2b(gelu_exact(v));
    }
}

// ---------------------------------------------------------------------------
// Final fusion: LDS-cached p rows, fast reductions, RMW d_out rows
// ---------------------------------------------------------------------------
__global__ __launch_bounds__(256)
void fuse_final_kernel(const bf16* __restrict__ bn3d, const bf16* __restrict__ bn1d,
                       const int* __restrict__ cluster, const int* __restrict__ fgi,
                       float* __restrict__ out)
{
    __shared__ float red4[4];
    __shared__ float x3s[CDIM];
    __shared__ bf16 pc[NVIEW][CDIM];
    __shared__ float simsh[NVIEW];
    int j = blockIdx.x;
    int tid = threadIdx.x;
    int b = j >> 10, g = j & 1023;
    const bf16* x3 = bn3d + (long long)cluster[j] * CDIM;
    float s = 0.f;
    for (int c = tid; c < CDIM; c += 256) {
        float v = b2f(x3[c]);
        x3s[c] = v;
        s += v * v;
    }
    __syncthreads();
    float nx3 = fmaxf(sqrtf(brs_fast(s, red4, 4)), 1e-8f);

    for (int i = 0; i < NVIEW; ++i) {
        const bf16* p = bn1d + ((long long)i * NGRID + fgi[i * NFEAT + j]) * CDIM;
        float d = 0.f, nn = 0.f;
        for (int c = tid; c < CDIM; c += 256) {
            bf16 u = p[c];
            pc[i][c] = u;
            float pv = b2f(u);
            d += pv * x3s[c]; nn += pv * pv;
        }
        float D = brs_fast(d, red4, 4);
        float Np = sqrtf(brs_fast(nn, red4, 4));
        if (tid == 0) {
            float cosv = D / (fmaxf(Np, 1e-8f) * nx3);
            simsh[i] = (cosv + 1.f) * 0.5f;
        }
    }
    __syncthreads();
    float ssum = 0.f;
    #pragma unroll
    for (int i = 0; i < NVIEW; ++i) ssum += simsh[i];
    float invs = 1.f / fmaxf(ssum, 1e-20f);
    long long orow = ((long long)b * SEQ + 1 + g) * CDIM;
    for (int c = tid; c < CDIM; c += 256) {
        float acc = 0.f;
        #pragma unroll
        for (int i = 0; i < NVIEW; ++i) acc += simsh[i] * invs * b2f(pc[i][c]);
        out[orow + c] = out[orow + c] + 0.3f * acc;
    }
}

// ---------------------------------------------------------------------------
// Host side
// ---------------------------------------------------------------------------
extern "C" void kernel_launch(void* const* d_in, const int* in_sizes, int n_in,
                              void* d_out, int out_size, void* d_ws, size_t ws_size,
                              hipStream_t stream)
{
    const float* x      = (const float*)d_in[0];
    const int*  cluster = (const int*)d_in[2];
    const int*  fgi     = (const int*)d_in[3];
    const float* ln1_g = (const float*)d_in[6];
    const float* ln1_b = (const float*)d_in[7];
    const float* w_qkv = (const float*)d_in[8];
    const float* b_qkv = (const float*)d_in[9];
    const float* w_o   = (const float*)d_in[10];
    const float* b_o   = (const float*)d_in[11];
    const float* ln2_g = (const float*)d_in[12];
    const float* ln2_b = (const float*)d_in[13];
    const float* w_fc  = (const float*)d_in[14];
    const float* b_fc  = (const float*)d_in[15];
    const float* w_proj= (const float*)d_in[16];
    const float* b_proj= (const float*)d_in[17];
    const float* w_down= (const float*)d_in[18];
    const float* b_down= (const float*)d_in[19];
    const float* w_up  = (const float*)d_in[20];
    const float* b_up  = (const float*)d_in[21];
    const float* bn3d_g= (const float*)d_in[22];
    const float* bn3d_b= (const float*)d_in[23];
    const float* n3_g  = (const float*)d_in[24];
    const float* n3_b  = (const float*)d_in[25];
    const float* vw_qkv= (const float*)d_in[26];
    const float* vb_qkv= (const float*)d_in[27];
    const float* vw_o  = (const float*)d_in[28];
    const float* vb_o  = (const float*)d_in[29];
    const float* bn1d_g= (const float*)d_in[30];
    const float* bn1d_b= (const float*)d_in[31];
    (void)in_sizes; (void)n_in; (void)out_size; (void)ws_size;

    float* out = (float*)d_out;

    // workspace layout (bytes), total ~205 MB (< proven-safe 209)
    char* w = (char*)d_ws;
    bf16*  QKV    = (bf16*)w;  w += (long long)NROWS * 3 * CDIM * 2;
    bf16*  H      = (bf16*)w;  w += (long long)NROWS * CDIM * 2;
    float* X2     = (float*)w; w += (long long)NROWS * CDIM * 4;
    bf16*  AO     = (bf16*)w;  w += (long long)NROWS * CDIM * 2;
    bf16*  FFN    = (bf16*)w;  w += (long long)NROWS * CDIM * 2;
    float* T1     = (float*)w; w += (long long)HG * BATCH * SEQ * LDT * 2;
    float* Y512   = (float*)w; w += (long long)NCLUST * CDIM * 4;
    bf16*  BN3D   = (bf16*)w;  w += (long long)NCLUST * CDIM * 2;
    float* YG     = (float*)w; w += (long long)NGRID * CDIM * 4;
    bf16*  BN1D   = (bf16*)w;  w += (long long)NVIEW * NGRID * CDIM * 2;
    bf16*  WQKVT  = (bf16*)w;  w += (long long)(3*CDIM) * CDIM * 2;
    bf16*  WOT    = (bf16*)w;  w += (long long)CDIM * CDIM * 2;
    bf16*  WFCT   = (bf16*)w;  w += (long long)(4*CDIM) * CDIM * 2;
    bf16*  WPROJT = (bf16*)w;  w += (long long)CDIM * (4*CDIM) * 2;
    bf16*  VWQKVT = (bf16*)w;  w += (long long)(3*CDIM) * CDIM * 2;
    bf16*  VWOT   = (bf16*)w;  w += (long long)CDIM * CDIM * 2;
    bf16*  VT     = (bf16*)w;  w += (long long)BATCH * CDIM * LDT * 2;
    float* BPART  = (float*)w; w += (long long)BNCH * CDIM * 2 * 4;
    float* BSTAT  = (float*)w; w += (long long)CDIM * 2 * 4;
    bf16*  T1b    = (bf16*)T1;

    dim3 blk(256), blk512(512);

    // ---- weight transposes (f32 -> bf16, N x K) ----
    transpose_kernel<<<dim3(72, 24), blk, 0, stream>>>(w_qkv, WQKVT, CDIM, 3*CDIM);
    transpose_kernel<<<dim3(24, 24), blk, 0, stream>>>(w_o, WOT, CDIM, CDIM);
    transpose_kernel<<<dim3(96, 24), blk, 0, stream>>>(w_fc, WFCT, CDIM, 4*CDIM);
    transpose_kernel<<<dim3(24, 96), blk, 0, stream>>>(w_proj, WPROJT, 4*CDIM, CDIM);

    // ---- stage A ----
    ln_kernel<<<NROWS, blk, 0, stream>>>(x, ln1_g, ln1_b, 0LL, H, 0);

    gemm2<1,0,0,0,0,1><<<dim3(18, 65, 1), blk512, 0, stream>>>(
        H, WQKVT, b_qkv, nullptr, QKV,
        NROWS, 3*CDIM, CDIM, CDIM, CDIM, 3*CDIM, 0, 1.f, 0, 0LL, 0LL,
        1, 0, 0, 0, 0, 0, 0, 0, nullptr, nullptr, 0);

    transpose_bf16_kernel<<<dim3(24, 33, BATCH), blk, 0, stream>>>(
        QKV + 2*CDIM, VT, SEQ, CDIM, 3*CDIM, LDT,
        (long long)SEQ * 3*CDIM, (long long)CDIM * LDT);

    const long long HSTR = (long long)BATCH * SEQ * LDT;
    for (int g = 0; g < NHEAD / HG; ++g) {
        int hb = g * HG;
        gemm2<1,0,0,0,0,1><<<dim3(9, 9, BATCH * HG), blk512, 0, stream>>>(
            QKV + hb * DHEAD, QKV + CDIM + hb * DHEAD, nullptr, nullptr, T1b,
            SEQ, SEQ, DHEAD, 3*CDIM, 3*CDIM, LDT, 0, 0.125f, 0, 0LL, 0LL,
            BATCH, (long long)SEQ * 3*CDIM, DHEAD,
            (long long)SEQ * 3*CDIM, DHEAD,
            (long long)SEQ * LDT, HSTR, 0, nullptr, nullptr, 0);

        softmax_aw3_kernel<<<NROWS, blk, 0, stream>>>(T1b, out, g == 0 ? 1 : 0);

        gemm_k<1,0,0,0,1><<<dim3(1, 17, BATCH * HG), blk, 0, stream>>>(
            T1b, VT + (long long)hb * DHEAD * LDT, nullptr, nullptr, AO + hb * DHEAD,
            SEQ, DHEAD, SEQ, LDT, LDT, CDIM, 0, 1.f, 0, 0LL, 0LL,
            BATCH, (long long)SEQ * LDT, HSTR,
            (long long)CDIM * LDT, (long long)DHEAD * LDT,
            (long long)SEQ * CDIM, DHEAD, 0);
    }

    gemm2<1,0,1,1,0,1><<<dim3(6, 65, 1), blk512, 0, stream>>>(
        AO, WOT, b_o, x, X2,
        NROWS, CDIM, CDIM, CDIM, CDIM, CDIM, CDIM, 1.f, 0, 0LL, 0LL,
        1, 0, 0, 0, 0, 0, 0, 0, nullptr, nullptr, 0);

    ln_kernel<<<NROWS, blk, 0, stream>>>(X2, ln2_g, ln2_b, 0LL, H, 0);

    // FC + proj unchunked
    {
        bf16* MID = (bf16*)T1;
        gemm2<1,0,0,0,0,1><<<dim3(24, 65, 1), blk512, 0, stream>>>(
            H, WFCT, b_fc, nullptr, MID,
            NROWS, 4*CDIM, CDIM, CDIM, CDIM, 4*CDIM, 0, 1.f, 1, 0LL, 0LL,
            1, 0, 0, 0, 0, 0, 0, 0, nullptr, nullptr, 0);
        gemm2<1,0,0,0,0,1><<<dim3(6, 65, 1), blk512, 0, stream>>>(
            MID, WPROJT, b_proj, nullptr, FFN,
            NROWS, CDIM, 4*CDIM, 4*CDIM, 4*CDIM, CDIM, 0, 1.f, 0, 0LL, 0LL,
            1, 0, 0, 0, 0, 0, 0, 0, nullptr, nullptr, 0);
    }

    adp_final_kernel<<<NROWS, blk, 0, stream>>>(FFN, w_down, b_down, w_up, b_up,
                                                X2, out);

    // shared norm for all views
    norm_kernel<<<NFEAT, blk, 0, stream>>>(out, H);

    // ---- stage B ----
    seg_kernel<<<NCLUST, blk, 0, stream>>>(out, cluster, Y512, 1);
    bn_part_kernel<<<dim3(12, BNCH), blk, 0, stream>>>(Y512, BPART, NCLUST);
    bn_stat_kernel<<<dim3(3), blk, 0, stream>>>(BPART, BSTAT, NCLUST);
    bn_apply_kernel<<<NCLUST, blk, 0, stream>>>(Y512, BSTAT, bn3d_g, bn3d_b, 0LL, BN3D);

    // ---- stage C: 6 views ----
    const float inv_sqrt_c = 0.03608439182435161f;
    for (int i = 0; i < NVIEW; ++i) {
        transpose_kernel<<<dim3(72, 24), blk, 0, stream>>>(
            vw_qkv + (long long)i * CDIM * 3*CDIM, VWQKVT, CDIM, 3*CDIM);
        transpose_kernel<<<dim3(24, 24), blk, 0, stream>>>(
            vw_o + (long long)i * CDIM * CDIM, VWOT, CDIM, CDIM);

        gemm2<1,0,0,0,1,1><<<dim3(18, 64, 1), blk512, 0, stream>>>(
            H, VWQKVT, vb_qkv, nullptr, QKV,
            NFEAT, 3*CDIM, CDIM, CDIM, CDIM, 3*CDIM, 0, 1.f, 0,
            0LL, (long long)i * 3*CDIM, 1, 0, 0, 0, 0, 0, 0, 0,
            n3_g, n3_b, (long long)i * CDIM);

        transpose_bf16_kernel<<<dim3(24, 32, BATCH), blk, 0, stream>>>(
            QKV + 2*CDIM, VT, GTOK, CDIM, 3*CDIM, GTOK,
            (long long)GTOK * 3*CDIM, (long long)CDIM * GTOK);

        gemm2<1,0,0,0,0,1><<<dim3(8, 8, BATCH), blk512, 0, stream>>>(
            QKV, QKV + CDIM, nullptr, nullptr, T1b,
            GTOK, GTOK, CDIM, 3*CDIM, 3*CDIM, GTOK, 0, inv_sqrt_c, 0, 0LL, 0LL,
            BATCH, (long long)GTOK * 3*CDIM, 0,
            (long long)GTOK * 3*CDIM, 0,
            (long long)GTOK * GTOK, 0, 0, nullptr, nullptr, 0);

        softmax_rows_bf16<<<BATCH * GTOK, blk, 0, stream>>>(T1b);

        gemm2<1,0,0,0,0,1><<<dim3(6, 8, BATCH), blk512, 0, stream>>>(
            T1b, VT, nullptr, nullptr, AO,
            GTOK, CDIM, GTOK, GTOK, GTOK, CDIM, 0, 1.f, 0, 0LL, 0LL,
            BATCH, (long long)GTOK * GTOK, 0,
            (long long)CDIM * GTOK, 0,
            (long long)GTOK * CDIM, 0, 0, nullptr, nullptr, 0);

        gemm2<1,0,1,1,0,1><<<dim3(6, 8, BATCH), blk512, 0, stream>>>(
            AO, VWOT, vb_o, out + CDIM, X2,
            GTOK, CDIM, CDIM, CDIM, CDIM, CDIM, CDIM, 1.f, 0,
            0LL, (long long)i * CDIM,
            BATCH, (long long)GTOK * CDIM, 0, 0, 0,
            (long long)GTOK * CDIM, 0, (long long)SEQ * CDIM, nullptr, nullptr, 0);

        seg_kernel<<<NGRID, blk, 0, stream>>>(X2, fgi + i * NFEAT, YG, 0);
        bn_part_kernel<<<dim3(12, BNCH), blk, 0, stream>>>(YG, BPART, NGRID);
        bn_stat_kernel<<<dim3(3), blk, 0, stream>>>(BPART, BSTAT, NGRID);
        bn_apply_kernel<<<NGRID, blk, 0, stream>>>(YG, BSTAT, bn1d_g, bn1d_b,
                                                   (long long)i * CDIM,
                                                   BN1D + (long long)i * NGRID * CDIM);
    }

    // ---- final fusion ----
    fuse_final_kernel<<<NFEAT, blk, 0, stream>>>(BN3D, BN1D, cluster, fgi, out);
}